// Round 2
// baseline (1212.219 us; speedup 1.0000x reference)
//
#include <hip/hip_runtime.h>

typedef unsigned short ushort_t;
typedef unsigned int uint32;
typedef __attribute__((ext_vector_type(8))) unsigned short ushort8;
typedef __attribute__((ext_vector_type(8))) __bf16 bf16x8;
typedef __attribute__((ext_vector_type(4))) float f32x4;

__device__ __forceinline__ ushort_t f2b(float f) {
    union { float f; uint32 u; } v; v.f = f;
    uint32 r = v.u + 0x7fffu + ((v.u >> 16) & 1u);
    return (ushort_t)(r >> 16);
}
__device__ __forceinline__ float b2f(ushort_t b) {
    union { uint32 u; float f; } v; v.u = ((uint32)b) << 16;
    return v.f;
}
__device__ __forceinline__ float sigm(float x) { return 1.f / (1.f + __expf(-x)); }

// epilogues
constexpr int EPI_BIAS = 0;  // bf16 (acc+bias) -> obf[row*ldo+col]
constexpr int EPI_RELU = 1;  // bf16 relu(acc+bias) -> obf[row*ldo+col]
constexpr int EPI_FEAT = 2;  // bf16 acc+bias+res[row*ldres+col] -> obf[row*ldo+col]
constexpr int EPI_SIG  = 3;  // rowsum of sigmoid(acc) -> atomicAdd dsum[z*256+row]
constexpr int EPI_PTX  = 4;  // bf16 cw[z*128+row]*acc -> obf[z*oBatch + col*128 + row]
constexpr int EPI_LX   = 5;  // bf16 res - acc -> obf
constexpr int EPI_Y    = 6;  // bf16 res + acc -> obf
constexpr int EPI_OUT0 = 7;  // fp32 acc+bias -> out NCHW (write)
constexpr int EPI_OUTA = 8;  // fp32 out += acc (accumulate) NCHW

struct GemmP {
    const ushort_t* A; const ushort_t* B;
    long long aBatch, bBatch;
    int lda, ldb;
    int Ksub, dil;
    const float* bias;
    const ushort_t* res; long long resBatch; int ldres;
    ushort_t* obf; long long oBatch; int ldo;
    float* of32;
    const float* cw;
    float* dsum;
};

// Generic 4-wave MFMA GEMM: C[M,N] = A[M,K] . B[N,K]^T, bf16 in, fp32 acc.
// AMODE==1: A is implicit 10-tap dilated-conv im2col over unpadded
//           [B][16][16][1024] bf16 (taps 0..8 = 3x3 conv with dilation p.dil,
//           tap 9 = identity), K = 10240, zero-fill out of bounds.
// Fragment layout (m89/m91-verified): A/B row|col = lane&15, k=(lane>>4)*8+j;
// C/D col = lane&15, row = (lane>>4)*4 + reg.
template<int BM, int BN, int AMODE, int EPI>
__global__ __launch_bounds__(256) void gemm_k(GemmP p) {
    __shared__ __align__(16) ushort_t aT[BM * 64];
    __shared__ __align__(16) ushort_t bT[BN * 64];
    constexpr int APASS = BM / 32, BPASS = BN / 32;
    constexpr int MFRAG = BM / 32, NFRAG = BN / 32;  // per-wave fragment counts
    const int tid = threadIdx.x;
    const int z = blockIdx.z;
    const int m0 = blockIdx.x * BM, n0 = blockIdx.y * BN;
    const int lane = tid & 63, wid = tid >> 6;
    const int l15 = lane & 15, l16 = lane >> 4;
    const int wr = wid >> 1, wc = wid & 1;
    const int srow = tid >> 3, scol = (tid & 7) * 8;

    const ushort_t* aptr[APASS];
    int ayy[APASS], axx[APASS];
    if constexpr (AMODE == 1) {
#pragma unroll
        for (int pi = 0; pi < APASS; ++pi) {
            int m = m0 + pi * 32 + srow;
            int bb = m >> 8;
            ayy[pi] = (m >> 4) & 15; axx[pi] = m & 15;
            aptr[pi] = p.A + (long long)bb * 262144 + scol;
        }
    } else {
#pragma unroll
        for (int pi = 0; pi < APASS; ++pi)
            aptr[pi] = p.A + (long long)z * p.aBatch +
                       (long long)(m0 + pi * 32 + srow) * p.lda + scol;
    }
    const ushort_t* bptr[BPASS];
#pragma unroll
    for (int pi = 0; pi < BPASS; ++pi)
        bptr[pi] = p.B + (long long)z * p.bBatch +
                   (long long)(n0 + pi * 32 + srow) * p.ldb + scol;

    f32x4 acc[MFRAG][NFRAG];
#pragma unroll
    for (int i = 0; i < MFRAG; ++i)
#pragma unroll
        for (int j = 0; j < NFRAG; ++j) acc[i][j] = (f32x4){0.f, 0.f, 0.f, 0.f};

    ushort8 ar[APASS], br[BPASS];
    auto ldg = [&](int gk) {
        if constexpr (AMODE == 1) {
            int tap = gk >> 10, kin = gk & 1023;
            int dy = 0, dx = 0;
            if (tap < 9) { int ky = tap / 3; dy = (ky - 1) * p.dil; dx = (tap - ky * 3 - 1) * p.dil; }
#pragma unroll
            for (int pi = 0; pi < APASS; ++pi) {
                int iy = ayy[pi] + dy, ix = axx[pi] + dx;
                if (((unsigned)iy < 16u) && ((unsigned)ix < 16u))
                    ar[pi] = *(const ushort8*)(aptr[pi] + ((iy << 4) + ix) * 1024 + kin);
                else {
                    ushort8 zz = {};
                    ar[pi] = zz;
                }
            }
        } else {
#pragma unroll
            for (int pi = 0; pi < APASS; ++pi)
                ar[pi] = *(const ushort8*)(aptr[pi] + gk);
        }
#pragma unroll
        for (int pi = 0; pi < BPASS; ++pi)
            br[pi] = *(const ushort8*)(bptr[pi] + gk);
    };

    ldg(0);
    const int iters = p.Ksub >> 6;
    for (int it = 0; it < iters; ++it) {
#pragma unroll
        for (int pi = 0; pi < APASS; ++pi)
            *(ushort8*)&aT[(pi * 32 + srow) * 64 + scol] = ar[pi];
#pragma unroll
        for (int pi = 0; pi < BPASS; ++pi)
            *(ushort8*)&bT[(pi * 32 + srow) * 64 + scol] = br[pi];
        __syncthreads();
        if (it + 1 < iters) ldg((it + 1) * 64);
#pragma unroll
        for (int ks = 0; ks < 2; ++ks) {
            bf16x8 af[MFRAG], bfr[NFRAG];
#pragma unroll
            for (int mi = 0; mi < MFRAG; ++mi)
                af[mi] = __builtin_bit_cast(bf16x8,
                    *(const ushort8*)&aT[(wr * (BM / 2) + mi * 16 + l15) * 64 + ks * 32 + l16 * 8]);
#pragma unroll
            for (int ni = 0; ni < NFRAG; ++ni)
                bfr[ni] = __builtin_bit_cast(bf16x8,
                    *(const ushort8*)&bT[(wc * (BN / 2) + ni * 16 + l15) * 64 + ks * 32 + l16 * 8]);
#pragma unroll
            for (int mi = 0; mi < MFRAG; ++mi)
#pragma unroll
                for (int ni = 0; ni < NFRAG; ++ni)
                    acc[mi][ni] = __builtin_amdgcn_mfma_f32_16x16x32_bf16(af[mi], bfr[ni], acc[mi][ni], 0, 0, 0);
        }
        __syncthreads();
    }

    // ---------------- epilogue ----------------
#pragma unroll
    for (int mi = 0; mi < MFRAG; ++mi) {
        if constexpr (EPI == EPI_SIG) {
#pragma unroll
            for (int r = 0; r < 4; ++r) {
                float sv = 0.f;
#pragma unroll
                for (int ni = 0; ni < NFRAG; ++ni) sv += sigm(acc[mi][ni][r]);
                sv += __shfl_xor(sv, 1); sv += __shfl_xor(sv, 2);
                sv += __shfl_xor(sv, 4); sv += __shfl_xor(sv, 8);
                if (l15 == 0) {
                    int grow = m0 + wr * (BM / 2) + mi * 16 + l16 * 4 + r;
                    atomicAdd(&p.dsum[z * 256 + grow], sv);
                }
            }
        } else {
#pragma unroll
            for (int ni = 0; ni < NFRAG; ++ni) {
                int gcol = n0 + wc * (BN / 2) + ni * 16 + l15;
                int growb = m0 + wr * (BM / 2) + mi * 16 + l16 * 4;
#pragma unroll
                for (int r = 0; r < 4; ++r) {
                    int grow = growb + r;
                    float v = acc[mi][ni][r];
                    if constexpr (EPI == EPI_BIAS) {
                        v += p.bias[gcol];
                        p.obf[(long long)grow * p.ldo + gcol] = f2b(v);
                    } else if constexpr (EPI == EPI_RELU) {
                        v += p.bias[gcol]; v = fmaxf(v, 0.f);
                        p.obf[(long long)grow * p.ldo + gcol] = f2b(v);
                    } else if constexpr (EPI == EPI_FEAT) {
                        v += p.bias[gcol] + b2f(p.res[(long long)grow * p.ldres + gcol]);
                        p.obf[(long long)grow * p.ldo + gcol] = f2b(v);
                    } else if constexpr (EPI == EPI_PTX) {
                        v *= p.cw[z * 128 + grow];
                        p.obf[(long long)z * p.oBatch + (long long)gcol * 128 + grow] = f2b(v);
                    } else if constexpr (EPI == EPI_LX) {
                        v = b2f(p.res[(long long)z * p.resBatch + (long long)grow * p.ldres + gcol]) - v;
                        p.obf[(long long)z * p.oBatch + (long long)grow * p.ldo + gcol] = f2b(v);
                    } else if constexpr (EPI == EPI_Y) {
                        v = b2f(p.res[(long long)z * p.resBatch + (long long)grow * p.ldres + gcol]) + v;
                        p.obf[(long long)z * p.oBatch + (long long)grow * p.ldo + gcol] = f2b(v);
                    } else if constexpr (EPI == EPI_OUT0) {
                        v += p.bias[gcol];
                        int bb = grow >> 8, px = grow & 255;
                        p.of32[((long long)bb * 1024 + gcol) * 256 + px] = v;
                    } else if constexpr (EPI == EPI_OUTA) {
                        int bb = grow >> 8, px = grow & 255;
                        long long o = ((long long)bb * 1024 + gcol) * 256 + px;
                        p.of32[o] = p.of32[o] + v;
                    }
                }
            }
        }
    }
}

// ---------------- small kernels ----------------

// x_sum = x_cur * (1 + bilinear_up2x_align_corners(x_lat)); bf16 [B*256][1024]
__global__ void k_upsum(const float* __restrict__ xc, const float* __restrict__ xl,
                        ushort_t* __restrict__ xs) {
    __shared__ float lat[64 * 64];
    __shared__ ushort_t tile[64 * 258];
    int b = blockIdx.x, c0 = blockIdx.y * 64;
    int t = threadIdx.x;
    for (int i = t; i < 4096; i += 256)
        lat[i] = xl[((long long)(b * 1024 + c0 + (i >> 6))) * 64 + (i & 63)];
    __syncthreads();
    int y = t >> 4, x = t & 15;
    float fy = y * (7.f / 15.f); int y0 = (int)fy; float wy = fy - y0; int y1 = y0 + 1 > 7 ? 7 : y0 + 1;
    float fx = x * (7.f / 15.f); int x0 = (int)fx; float wx = fx - x0; int x1 = x0 + 1 > 7 ? 7 : x0 + 1;
    for (int cc = 0; cc < 64; ++cc) {
        float cur = xc[((long long)(b * 1024 + c0 + cc)) * 256 + t];
        const float* L = &lat[cc * 64];
        float tv = L[y0 * 8 + x0] * (1.f - wx) + L[y0 * 8 + x1] * wx;
        float bv = L[y1 * 8 + x0] * (1.f - wx) + L[y1 * 8 + x1] * wx;
        float up = tv + (bv - tv) * wy;
        tile[cc * 258 + t] = f2b(cur * (1.f + up));
    }
    __syncthreads();
    for (int i = t; i < 16384; i += 256) {
        int px = i >> 6, cc = i & 63;
        xs[((long long)(b * 256 + px)) * 1024 + c0 + cc] = tile[cc * 258 + px];
    }
}

__global__ void k_pool(const ushort_t* __restrict__ f, float* __restrict__ avg, float* __restrict__ mx) {
    int b = blockIdx.x, c = threadIdx.x;
    float s = 0.f, m = -3.4e38f;
    const ushort_t* base = f + (long long)b * 65536 + c;
    for (int px = 0; px < 256; ++px) { float v = b2f(base[px * 256]); s += v; m = fmaxf(m, v); }
    avg[b * 256 + c] = s * (1.f / 256.f);
    mx[b * 256 + c] = m;
}

__global__ void k_cw(const float* __restrict__ avg, const float* __restrict__ mx,
                     const float* __restrict__ aw, const float* __restrict__ mw,
                     float* __restrict__ cw) {
    __shared__ float sa[256], sm[256];
    int b = blockIdx.x, t = threadIdx.x; // 128 threads
    sa[t] = avg[b * 256 + t]; sa[t + 128] = avg[b * 256 + t + 128];
    sm[t] = mx[b * 256 + t];  sm[t + 128] = mx[b * 256 + t + 128];
    __syncthreads();
    float s1 = 0.f, s2 = 0.f;
    const float* a = aw + t * 256; const float* w = mw + t * 256;
    for (int c = 0; c < 256; ++c) { s1 += sa[c] * a[c]; s2 += sm[c] * w[c]; }
    s1 = fmaxf(s1, 0.f); s2 = fmaxf(s2, 0.f);
    cw[b * 128 + t] = sigm(s1 + s2);
}

__global__ void k_qc(const ushort_t* __restrict__ q, const float* __restrict__ cw,
                     ushort_t* __restrict__ qc) {
    int idx = blockIdx.x * 256 + threadIdx.x;
    int m = idx & 127; int b = idx >> 15;
    qc[idx] = f2b(b2f(q[idx]) * cw[(b << 7) + m]);
}

__global__ void k_pscale(const ushort_t* __restrict__ q, const float* __restrict__ dsum,
                         ushort_t* __restrict__ P, ushort_t* __restrict__ Pt) {
    int idx = blockIdx.x * 256 + threadIdx.x; // 2,097,152
    int m = idx & 127; int pix = idx >> 7;
    int b = pix >> 8, j = pix & 255;
    float d = rsqrtf(dsum[pix]);
    ushort_t v = f2b(d * b2f(q[idx]));
    P[idx] = v;
    Pt[((long long)b << 15) + (m << 8) + j] = v;
}

__global__ void k_ft(const ushort_t* __restrict__ f, ushort_t* __restrict__ ft) {
    long long idx = (long long)blockIdx.x * 256 + threadIdx.x; // 64*65536
    int r = (int)(idx & 65535); int b = (int)(idx >> 16);
    int c = r >> 8, j = r & 255;
    ft[idx] = f[((long long)(b * 256 + j)) * 256 + c];
}

// pack stage-s big-GEMM weight: [o<256][tap<10 * 1024]; taps 0..8 = rate(3x3), 9 = conv1x1
__global__ void k_wbig(const float* __restrict__ rate, const float* __restrict__ convw,
                       ushort_t* __restrict__ dst) {
    int gk = blockIdx.x * 256 + threadIdx.x; // 10240
    int o = blockIdx.y;
    int tap = gk >> 10, ci = gk & 1023;
    float v = (tap < 9) ? rate[(long long)o * 9216 + ci * 9 + tap] : convw[(long long)o * 1024 + ci];
    dst[(long long)o * 10240 + gk] = f2b(v);
}

__global__ void k_w3s(const float* __restrict__ w3, ushort_t* __restrict__ dst, int s) {
    int o = blockIdx.x, c = threadIdx.x;
    dst[o * 256 + c] = f2b(w3[o * 768 + s * 256 + c]);
}

__global__ void k_cast(const float* __restrict__ s, ushort_t* __restrict__ d) {
    int i = blockIdx.x * 256 + threadIdx.x; d[i] = f2b(s[i]);
}
__global__ void k_castT256(const float* __restrict__ s, ushort_t* __restrict__ d) {
    int c1 = threadIdx.x, c2 = blockIdx.x;
    d[c2 * 256 + c1] = f2b(s[c1 * 256 + c2]);
}
__global__ void k_bias2(const float* a0, const float* a1, const float* a2,
                        const float* cb, float* dst) {
    int t = threadIdx.x; int s = blockIdx.x;
    const float* a = s == 0 ? a0 : (s == 1 ? a1 : a2);
    dst[s * 256 + t] = a[t] + cb[t];
}
__global__ void k_sentinel(float* o, int n, float v) {
    int i = blockIdx.x * 256 + threadIdx.x; if (i < n) o[i] = v;
}

// ---------------- launch ----------------
extern "C" void kernel_launch(void* const* d_in, const int* in_sizes, int n_in,
                              void* d_out, int out_size, void* d_ws, size_t ws_size,
                              hipStream_t stream) {
    const float* x_cur  = (const float*)d_in[0];
    const float* x_lat  = (const float*)d_in[1];
    const float* conv_w = (const float*)d_in[2];
    const float* conv_b = (const float*)d_in[3];
    const float* conv1_w = (const float*)d_in[4];
    const float* conv1_b = (const float*)d_in[5];
    const float* conv3_w = (const float*)d_in[6];
    const float* conv3_b = (const float*)d_in[7];
    const float* rate_w[3] = {(const float*)d_in[8], (const float*)d_in[10], (const float*)d_in[12]};
    const float* rate_b[3] = {(const float*)d_in[9], (const float*)d_in[11], (const float*)d_in[13]};
    const float* ck_w  = (const float*)d_in[14];
    const float* ck_b  = (const float*)d_in[15];
    const float* avg_w = (const float*)d_in[16];
    const float* max_w = (const float*)d_in[17];
    const float* gcn_w = (const float*)d_in[18];
    float* out = (float*)d_out;

    char* w = (char*)d_ws;
    auto take = [&](size_t bytes) { void* p = (void*)w; w += (bytes + 255) & ~(size_t)255; return p; };
    ushort_t* xsum = (ushort_t*)take(16384ll * 1024 * 2);   // 33.55MB
    ushort_t* feat = (ushort_t*)take(16384ll * 1024 * 2);   // 33.55MB
    ushort_t* fbuf = (ushort_t*)take(16384ll * 256 * 2);    // 8.39MB
    ushort_t* ftb  = (ushort_t*)take(64ll * 256 * 256 * 2); // 8.39MB (reused as ybuf)
    ushort_t* ybuf = ftb;
    ushort_t* qbuf = (ushort_t*)take(16384ll * 128 * 2);    // 4.19MB
    ushort_t* qc   = (ushort_t*)take(16384ll * 128 * 2);    // 4.19MB \ lx aliases
    ushort_t* Pt   = (ushort_t*)take(64ll * 128 * 256 * 2); // 4.19MB /  [qc|Pt]
    ushort_t* lx   = qc;
    ushort_t* Pb   = (ushort_t*)take(16384ll * 128 * 2);    // 4.19MB
    ushort_t* St   = (ushort_t*)take(64ll * 256 * 128 * 2); // 4.19MB
    ushort_t* wbig = (ushort_t*)take(256ll * 10240 * 2);    // 5.24MB
    ushort_t* w1b  = (ushort_t*)take(1024ll * 256 * 2);
    ushort_t* w3b  = (ushort_t*)take(1024ll * 256 * 2);
    ushort_t* ckb  = (ushort_t*)take(128ll * 256 * 2);
    ushort_t* gcnT = (ushort_t*)take(256ll * 256 * 2);
    float*    fbias = (float*)take(3 * 256 * 4);
    float*    avg   = (float*)take(64 * 256 * 4);
    float*    mxp   = (float*)take(64 * 256 * 4);
    float*    cwb   = (float*)take(64 * 128 * 4);
    float*    dsum  = (float*)take(64 * 256 * 4);

    size_t need = (size_t)(w - (char*)d_ws);
    if (need > ws_size) {
        // sentinel: encode ws budget (MB) so the failing absmax reveals it
        float v = 1.0e6f + (float)(ws_size >> 20);
        k_sentinel<<<(out_size + 255) / 256, 256, 0, stream>>>(out, out_size, v);
        return;
    }

    k_upsum<<<dim3(64, 16), 256, 0, stream>>>(x_cur, x_lat, xsum);
    k_cast<<<1024, 256, 0, stream>>>(conv1_w, w1b);
    k_cast<<<128, 256, 0, stream>>>(ck_w, ckb);
    k_castT256<<<256, 256, 0, stream>>>(gcn_w, gcnT);
    k_bias2<<<3, 256, 0, stream>>>(rate_b[0], rate_b[1], rate_b[2], conv_b, fbias);

    for (int s = 0; s < 3; ++s) {
        k_wbig<<<dim3(40, 256), 256, 0, stream>>>(rate_w[s], conv_w, wbig);
        k_w3s<<<1024, 256, 0, stream>>>(conv3_w, w3b, s);

        { // BIG: f_s = conv3x3(dil=2^s) + rate_b + conv1x1 + conv_b, bf16 -> fbuf
            GemmP p{};
            p.A = (s == 0) ? xsum : feat;
            p.B = wbig; p.ldb = 10240;
            p.Ksub = 10240; p.dil = 1 << s;
            p.bias = fbias + s * 256;
            p.obf = fbuf; p.ldo = 256;
            gemm_k<64, 128, 1, EPI_BIAS><<<dim3(256, 2, 1), 256, 0, stream>>>(p);
        }
        k_pool<<<64, 256, 0, stream>>>(fbuf, avg, mxp);
        k_cw<<<64, 128, 0, stream>>>(avg, mxp, avg_w, max_w, cwb);
        { // q = relu(f @ ck_w^T + ck_b)  [16384][128]
            GemmP p{};
            p.A = fbuf; p.lda = 256; p.B = ckb; p.ldb = 256;
            p.Ksub = 256;
            p.bias = ck_b; p.obf = qbuf; p.ldo = 128;
            gemm_k<128, 128, 0, EPI_RELU><<<dim3(128, 1, 1), 256, 0, stream>>>(p);
        }
        k_qc<<<8192, 256, 0, stream>>>(qbuf, cwb, qc);
        hipMemsetAsync(dsum, 0, 64 * 256 * 4, stream);
        { // dsum[b][i] = sum_j sigmoid( (q*cw)[i,:] . q[j,:] )
            GemmP p{};
            p.A = qc;   p.aBatch = 32768; p.lda = 128;
            p.B = qbuf; p.bBatch = 32768; p.ldb = 128;
            p.Ksub = 128; p.dsum = dsum;
            gemm_k<128, 128, 0, EPI_SIG><<<dim3(2, 2, 64), 256, 0, stream>>>(p);
        }
        k_pscale<<<8192, 256, 0, stream>>>(qbuf, dsum, Pb, Pt);
        k_ft<<<16384, 256, 0, stream>>>(fbuf, ftb);
        { // St[b][c][m] = cw[m] * (P^T X)[m][c]
            GemmP p{};
            p.A = Pt;  p.aBatch = 32768; p.lda = 256;
            p.B = ftb; p.bBatch = 65536; p.ldb = 256;
            p.Ksub = 256; p.cw = cwb;
            p.obf = St; p.oBatch = 32768;
            gemm_k<128, 128, 0, EPI_PTX><<<dim3(1, 2, 64), 256, 0, stream>>>(p);
        }
        { // LX = X - P @ St^T
            GemmP p{};
            p.A = Pb; p.aBatch = 32768; p.lda = 128;
            p.B = St; p.bBatch = 32768; p.ldb = 128;
            p.Ksub = 128;
            p.res = fbuf; p.resBatch = 65536; p.ldres = 256;
            p.obf = lx; p.oBatch = 65536; p.ldo = 256;
            gemm_k<128, 128, 0, EPI_LX><<<dim3(2, 2, 64), 256, 0, stream>>>(p);
        }
        { // Y = X + LX @ gcn_w -> ybuf [16384][256]
            GemmP p{};
            p.A = lx;   p.aBatch = 65536; p.lda = 256;
            p.B = gcnT; p.bBatch = 0;     p.ldb = 256;
            p.Ksub = 256;
            p.res = fbuf; p.resBatch = 65536; p.ldres = 256;
            p.obf = ybuf; p.oBatch = 65536; p.ldo = 256;
            gemm_k<128, 128, 0, EPI_Y><<<dim3(2, 2, 64), 256, 0, stream>>>(p);
        }
        { // out (+)= ybuf @ w3_slice^T (+ conv3_b at s==0), fp32 NCHW
            GemmP p{};
            p.A = ybuf; p.lda = 256; p.B = w3b; p.ldb = 256;
            p.Ksub = 256; p.bias = conv3_b; p.of32 = out;
            if (s == 0)
                gemm_k<128, 128, 0, EPI_OUT0><<<dim3(128, 8, 1), 256, 0, stream>>>(p);
            else
                gemm_k<128, 128, 0, EPI_OUTA><<<dim3(128, 8, 1), 256, 0, stream>>>(p);
        }
        if (s < 2) { // feature = conv1(f) + conv1_b + x_sum -> feat [16384][1024]
            GemmP p{};
            p.A = fbuf; p.lda = 256; p.B = w1b; p.ldb = 256;
            p.Ksub = 256; p.bias = conv1_b;
            p.res = xsum; p.ldres = 1024;
            p.obf = feat; p.ldo = 1024;
            gemm_k<128, 128, 0, EPI_FEAT><<<dim3(128, 8, 1), 256, 0, stream>>>(p);
        }
    }
}

// Round 3
// 1028.323 us; speedup vs baseline: 1.1788x; 1.1788x over previous
//
#include <hip/hip_runtime.h>

typedef unsigned short ushort_t;
typedef unsigned int uint32;
typedef __attribute__((ext_vector_type(8))) unsigned short ushort8;
typedef __attribute__((ext_vector_type(8))) __bf16 bf16x8;
typedef __attribute__((ext_vector_type(4))) float f32x4;

__device__ __forceinline__ ushort_t f2b(float f) {
    union { float f; uint32 u; } v; v.f = f;
    uint32 r = v.u + 0x7fffu + ((v.u >> 16) & 1u);
    return (ushort_t)(r >> 16);
}
__device__ __forceinline__ float b2f(ushort_t b) {
    union { uint32 u; float f; } v; v.u = ((uint32)b) << 16;
    return v.f;
}
__device__ __forceinline__ float sigm(float x) { return 1.f / (1.f + __expf(-x)); }

// epilogues
constexpr int EPI_BIAS = 0;  // bf16 (acc+bias) -> obf[row*ldo+col]
constexpr int EPI_RELU = 1;  // bf16 relu(acc+bias) -> obf[row*ldo+col]
constexpr int EPI_FEAT = 2;  // bf16 acc+bias+res[row*ldres+col] -> obf[row*ldo+col]
constexpr int EPI_SIG  = 3;  // rowsum of sigmoid(acc) -> atomicAdd dsum[z*256+row]
constexpr int EPI_PTX  = 4;  // bf16 cw[z*128+row]*acc -> obf[z*oBatch + col*128 + row]
constexpr int EPI_LX   = 5;  // bf16 res - acc -> obf
constexpr int EPI_Y    = 6;  // bf16 res + acc -> obf
constexpr int EPI_OUT0 = 7;  // fp32 acc+bias -> out NCHW (write)
constexpr int EPI_OUTA = 8;  // fp32 out += acc (accumulate) NCHW

struct GemmP {
    const ushort_t* A; const ushort_t* B;
    long long aBatch, bBatch;
    int lda, ldb;
    int Ksub, dil;
    const float* bias;
    const ushort_t* res; long long resBatch; int ldres;
    ushort_t* obf; long long oBatch; int ldo;
    float* of32;
    const float* cw;
    float* dsum;
};

// Generic 4-wave MFMA GEMM: C[M,N] = A[M,K] . B[N,K]^T, bf16 in, fp32 acc.
// AMODE==1: A is implicit 10-tap dilated-conv im2col over unpadded
//           [B][16][16][1024] bf16 (taps 0..8 = 3x3 conv with dilation p.dil,
//           tap 9 = identity), K = 10240, zero-fill out of bounds.
// Fragment layout (m89/m91-verified): A/B row|col = lane&15, k=(lane>>4)*8+j;
// C/D col = lane&15, row = (lane>>4)*4 + reg.
// LDS tiles are [rows][64] bf16 (128B rows) with a T2-style XOR swizzle:
// column (8-elem granules) ^= (row&7)<<3, applied on BOTH ds_write and
// ds_read (reg-staged, so both sides controllable — rule #21). Without it,
// fragment reads are a 16-way bank conflict (lanes 0-15 = 16 rows at one
// 16B column, 128B row stride -> same bank group; measured 4.7e7 conflict
// cycles = ~37% of wall time in round 2).
template<int BM, int BN, int AMODE, int EPI>
__global__ __launch_bounds__(256) void gemm_k(GemmP p) {
    __shared__ __align__(16) ushort_t aT[BM * 64];
    __shared__ __align__(16) ushort_t bT[BN * 64];
    constexpr int APASS = BM / 32, BPASS = BN / 32;
    constexpr int MFRAG = BM / 32, NFRAG = BN / 32;  // per-wave fragment counts
    const int tid = threadIdx.x;
    const int z = blockIdx.z;
    const int m0 = blockIdx.x * BM, n0 = blockIdx.y * BN;
    const int lane = tid & 63, wid = tid >> 6;
    const int l15 = lane & 15, l16 = lane >> 4;
    const int wr = wid >> 1, wc = wid & 1;
    const int srow = tid >> 3, scol = (tid & 7) * 8;
    const int swcol = scol ^ ((srow & 7) << 3);  // swizzled store column

    const ushort_t* aptr[APASS];
    int ayy[APASS], axx[APASS];
    if constexpr (AMODE == 1) {
#pragma unroll
        for (int pi = 0; pi < APASS; ++pi) {
            int m = m0 + pi * 32 + srow;
            int bb = m >> 8;
            ayy[pi] = (m >> 4) & 15; axx[pi] = m & 15;
            aptr[pi] = p.A + (long long)bb * 262144 + scol;
        }
    } else {
#pragma unroll
        for (int pi = 0; pi < APASS; ++pi)
            aptr[pi] = p.A + (long long)z * p.aBatch +
                       (long long)(m0 + pi * 32 + srow) * p.lda + scol;
    }
    const ushort_t* bptr[BPASS];
#pragma unroll
    for (int pi = 0; pi < BPASS; ++pi)
        bptr[pi] = p.B + (long long)z * p.bBatch +
                   (long long)(n0 + pi * 32 + srow) * p.ldb + scol;

    f32x4 acc[MFRAG][NFRAG];
#pragma unroll
    for (int i = 0; i < MFRAG; ++i)
#pragma unroll
        for (int j = 0; j < NFRAG; ++j) acc[i][j] = (f32x4){0.f, 0.f, 0.f, 0.f};

    ushort8 ar[APASS], br[BPASS];
    auto ldg = [&](int gk) {
        if constexpr (AMODE == 1) {
            int tap = gk >> 10, kin = gk & 1023;
            int dy = 0, dx = 0;
            if (tap < 9) { int ky = tap / 3; dy = (ky - 1) * p.dil; dx = (tap - ky * 3 - 1) * p.dil; }
#pragma unroll
            for (int pi = 0; pi < APASS; ++pi) {
                int iy = ayy[pi] + dy, ix = axx[pi] + dx;
                if (((unsigned)iy < 16u) && ((unsigned)ix < 16u))
                    ar[pi] = *(const ushort8*)(aptr[pi] + ((iy << 4) + ix) * 1024 + kin);
                else {
                    ushort8 zz = {};
                    ar[pi] = zz;
                }
            }
        } else {
#pragma unroll
            for (int pi = 0; pi < APASS; ++pi)
                ar[pi] = *(const ushort8*)(aptr[pi] + gk);
        }
#pragma unroll
        for (int pi = 0; pi < BPASS; ++pi)
            br[pi] = *(const ushort8*)(bptr[pi] + gk);
    };

    ldg(0);
    const int iters = p.Ksub >> 6;
    for (int it = 0; it < iters; ++it) {
#pragma unroll
        for (int pi = 0; pi < APASS; ++pi)
            *(ushort8*)&aT[(pi * 32 + srow) * 64 + swcol] = ar[pi];
#pragma unroll
        for (int pi = 0; pi < BPASS; ++pi)
            *(ushort8*)&bT[(pi * 32 + srow) * 64 + swcol] = br[pi];
        __syncthreads();
        if (it + 1 < iters) ldg((it + 1) * 64);
#pragma unroll
        for (int ks = 0; ks < 2; ++ks) {
            bf16x8 af[MFRAG], bfr[NFRAG];
#pragma unroll
            for (int mi = 0; mi < MFRAG; ++mi) {
                int rr = wr * (BM / 2) + mi * 16 + l15;
                int cc = (ks * 32 + l16 * 8) ^ ((rr & 7) << 3);
                af[mi] = __builtin_bit_cast(bf16x8, *(const ushort8*)&aT[rr * 64 + cc]);
            }
#pragma unroll
            for (int ni = 0; ni < NFRAG; ++ni) {
                int rr = wc * (BN / 2) + ni * 16 + l15;
                int cc = (ks * 32 + l16 * 8) ^ ((rr & 7) << 3);
                bfr[ni] = __builtin_bit_cast(bf16x8, *(const ushort8*)&bT[rr * 64 + cc]);
            }
#pragma unroll
            for (int mi = 0; mi < MFRAG; ++mi)
#pragma unroll
                for (int ni = 0; ni < NFRAG; ++ni)
                    acc[mi][ni] = __builtin_amdgcn_mfma_f32_16x16x32_bf16(af[mi], bfr[ni], acc[mi][ni], 0, 0, 0);
        }
        __syncthreads();
    }

    // ---------------- epilogue ----------------
#pragma unroll
    for (int mi = 0; mi < MFRAG; ++mi) {
        if constexpr (EPI == EPI_SIG) {
#pragma unroll
            for (int r = 0; r < 4; ++r) {
                float sv = 0.f;
#pragma unroll
                for (int ni = 0; ni < NFRAG; ++ni) sv += sigm(acc[mi][ni][r]);
                sv += __shfl_xor(sv, 1); sv += __shfl_xor(sv, 2);
                sv += __shfl_xor(sv, 4); sv += __shfl_xor(sv, 8);
                if (l15 == 0) {
                    int grow = m0 + wr * (BM / 2) + mi * 16 + l16 * 4 + r;
                    atomicAdd(&p.dsum[z * 256 + grow], sv);
                }
            }
        } else {
#pragma unroll
            for (int ni = 0; ni < NFRAG; ++ni) {
                int gcol = n0 + wc * (BN / 2) + ni * 16 + l15;
                int growb = m0 + wr * (BM / 2) + mi * 16 + l16 * 4;
#pragma unroll
                for (int r = 0; r < 4; ++r) {
                    int grow = growb + r;
                    float v = acc[mi][ni][r];
                    if constexpr (EPI == EPI_BIAS) {
                        v += p.bias[gcol];
                        p.obf[(long long)grow * p.ldo + gcol] = f2b(v);
                    } else if constexpr (EPI == EPI_RELU) {
                        v += p.bias[gcol]; v = fmaxf(v, 0.f);
                        p.obf[(long long)grow * p.ldo + gcol] = f2b(v);
                    } else if constexpr (EPI == EPI_FEAT) {
                        v += p.bias[gcol] + b2f(p.res[(long long)grow * p.ldres + gcol]);
                        p.obf[(long long)grow * p.ldo + gcol] = f2b(v);
                    } else if constexpr (EPI == EPI_PTX) {
                        v *= p.cw[z * 128 + grow];
                        p.obf[(long long)z * p.oBatch + (long long)gcol * 128 + grow] = f2b(v);
                    } else if constexpr (EPI == EPI_LX) {
                        v = b2f(p.res[(long long)z * p.resBatch + (long long)grow * p.ldres + gcol]) - v;
                        p.obf[(long long)z * p.oBatch + (long long)grow * p.ldo + gcol] = f2b(v);
                    } else if constexpr (EPI == EPI_Y) {
                        v = b2f(p.res[(long long)z * p.resBatch + (long long)grow * p.ldres + gcol]) + v;
                        p.obf[(long long)z * p.oBatch + (long long)grow * p.ldo + gcol] = f2b(v);
                    } else if constexpr (EPI == EPI_OUT0) {
                        v += p.bias[gcol];
                        int bb = grow >> 8, px = grow & 255;
                        p.of32[((long long)bb * 1024 + gcol) * 256 + px] = v;
                    } else if constexpr (EPI == EPI_OUTA) {
                        int bb = grow >> 8, px = grow & 255;
                        long long o = ((long long)bb * 1024 + gcol) * 256 + px;
                        p.of32[o] = p.of32[o] + v;
                    }
                }
            }
        }
    }
}

// ---------------- small kernels ----------------

// x_sum = x_cur * (1 + bilinear_up2x_align_corners(x_lat)); bf16 [B*256][1024]
__global__ void k_upsum(const float* __restrict__ xc, const float* __restrict__ xl,
                        ushort_t* __restrict__ xs) {
    __shared__ float lat[64 * 64];
    __shared__ ushort_t tile[64 * 258];
    int b = blockIdx.x, c0 = blockIdx.y * 64;
    int t = threadIdx.x;
    for (int i = t; i < 4096; i += 256)
        lat[i] = xl[((long long)(b * 1024 + c0 + (i >> 6))) * 64 + (i & 63)];
    __syncthreads();
    int y = t >> 4, x = t & 15;
    float fy = y * (7.f / 15.f); int y0 = (int)fy; float wy = fy - y0; int y1 = y0 + 1 > 7 ? 7 : y0 + 1;
    float fx = x * (7.f / 15.f); int x0 = (int)fx; float wx = fx - x0; int x1 = x0 + 1 > 7 ? 7 : x0 + 1;
    for (int cc = 0; cc < 64; ++cc) {
        float cur = xc[((long long)(b * 1024 + c0 + cc)) * 256 + t];
        const float* L = &lat[cc * 64];
        float tv = L[y0 * 8 + x0] * (1.f - wx) + L[y0 * 8 + x1] * wx;
        float bv = L[y1 * 8 + x0] * (1.f - wx) + L[y1 * 8 + x1] * wx;
        float up = tv + (bv - tv) * wy;
        tile[cc * 258 + t] = f2b(cur * (1.f + up));
    }
    __syncthreads();
    for (int i = t; i < 16384; i += 256) {
        int px = i >> 6, cc = i & 63;
        xs[((long long)(b * 256 + px)) * 1024 + c0 + cc] = tile[cc * 258 + px];
    }
}

__global__ void k_pool(const ushort_t* __restrict__ f, float* __restrict__ avg, float* __restrict__ mx) {
    int b = blockIdx.x, c = threadIdx.x;
    float s = 0.f, m = -3.4e38f;
    const ushort_t* base = f + (long long)b * 65536 + c;
    for (int px = 0; px < 256; ++px) { float v = b2f(base[px * 256]); s += v; m = fmaxf(m, v); }
    avg[b * 256 + c] = s * (1.f / 256.f);
    mx[b * 256 + c] = m;
}

__global__ void k_cw(const float* __restrict__ avg, const float* __restrict__ mx,
                     const float* __restrict__ aw, const float* __restrict__ mw,
                     float* __restrict__ cw) {
    __shared__ float sa[256], sm[256];
    int b = blockIdx.x, t = threadIdx.x; // 128 threads
    sa[t] = avg[b * 256 + t]; sa[t + 128] = avg[b * 256 + t + 128];
    sm[t] = mx[b * 256 + t];  sm[t + 128] = mx[b * 256 + t + 128];
    __syncthreads();
    float s1 = 0.f, s2 = 0.f;
    const float* a = aw + t * 256; const float* w = mw + t * 256;
    for (int c = 0; c < 256; ++c) { s1 += sa[c] * a[c]; s2 += sm[c] * w[c]; }
    s1 = fmaxf(s1, 0.f); s2 = fmaxf(s2, 0.f);
    cw[b * 128 + t] = sigm(s1 + s2);
}

__global__ void k_qc(const ushort_t* __restrict__ q, const float* __restrict__ cw,
                     ushort_t* __restrict__ qc) {
    int idx = blockIdx.x * 256 + threadIdx.x;
    int m = idx & 127; int b = idx >> 15;
    qc[idx] = f2b(b2f(q[idx]) * cw[(b << 7) + m]);
}

__global__ void k_pscale(const ushort_t* __restrict__ q, const float* __restrict__ dsum,
                         ushort_t* __restrict__ P, ushort_t* __restrict__ Pt) {
    int idx = blockIdx.x * 256 + threadIdx.x; // 2,097,152
    int m = idx & 127; int pix = idx >> 7;
    int b = pix >> 8, j = pix & 255;
    float d = rsqrtf(dsum[pix]);
    ushort_t v = f2b(d * b2f(q[idx]));
    P[idx] = v;
    Pt[((long long)b << 15) + (m << 8) + j] = v;
}

__global__ void k_ft(const ushort_t* __restrict__ f, ushort_t* __restrict__ ft) {
    long long idx = (long long)blockIdx.x * 256 + threadIdx.x; // 64*65536
    int r = (int)(idx & 65535); int b = (int)(idx >> 16);
    int c = r >> 8, j = r & 255;
    ft[idx] = f[((long long)(b * 256 + j)) * 256 + c];
}

// pack stage-s big-GEMM weight: [o<256][tap<10 * 1024]; taps 0..8 = rate(3x3), 9 = conv1x1
__global__ void k_wbig(const float* __restrict__ rate, const float* __restrict__ convw,
                       ushort_t* __restrict__ dst) {
    int gk = blockIdx.x * 256 + threadIdx.x; // 10240
    int o = blockIdx.y;
    int tap = gk >> 10, ci = gk & 1023;
    float v = (tap < 9) ? rate[(long long)o * 9216 + ci * 9 + tap] : convw[(long long)o * 1024 + ci];
    dst[(long long)o * 10240 + gk] = f2b(v);
}

__global__ void k_w3s(const float* __restrict__ w3, ushort_t* __restrict__ dst, int s) {
    int o = blockIdx.x, c = threadIdx.x;
    dst[o * 256 + c] = f2b(w3[o * 768 + s * 256 + c]);
}

__global__ void k_cast(const float* __restrict__ s, ushort_t* __restrict__ d) {
    int i = blockIdx.x * 256 + threadIdx.x; d[i] = f2b(s[i]);
}
__global__ void k_castT256(const float* __restrict__ s, ushort_t* __restrict__ d) {
    int c1 = threadIdx.x, c2 = blockIdx.x;
    d[c2 * 256 + c1] = f2b(s[c1 * 256 + c2]);
}
__global__ void k_bias2(const float* a0, const float* a1, const float* a2,
                        const float* cb, float* dst) {
    int t = threadIdx.x; int s = blockIdx.x;
    const float* a = s == 0 ? a0 : (s == 1 ? a1 : a2);
    dst[s * 256 + t] = a[t] + cb[t];
}
__global__ void k_sentinel(float* o, int n, float v) {
    int i = blockIdx.x * 256 + threadIdx.x; if (i < n) o[i] = v;
}

// ---------------- launch ----------------
extern "C" void kernel_launch(void* const* d_in, const int* in_sizes, int n_in,
                              void* d_out, int out_size, void* d_ws, size_t ws_size,
                              hipStream_t stream) {
    const float* x_cur  = (const float*)d_in[0];
    const float* x_lat  = (const float*)d_in[1];
    const float* conv_w = (const float*)d_in[2];
    const float* conv_b = (const float*)d_in[3];
    const float* conv1_w = (const float*)d_in[4];
    const float* conv1_b = (const float*)d_in[5];
    const float* conv3_w = (const float*)d_in[6];
    const float* conv3_b = (const float*)d_in[7];
    const float* rate_w[3] = {(const float*)d_in[8], (const float*)d_in[10], (const float*)d_in[12]};
    const float* rate_b[3] = {(const float*)d_in[9], (const float*)d_in[11], (const float*)d_in[13]};
    const float* ck_w  = (const float*)d_in[14];
    const float* ck_b  = (const float*)d_in[15];
    const float* avg_w = (const float*)d_in[16];
    const float* max_w = (const float*)d_in[17];
    const float* gcn_w = (const float*)d_in[18];
    float* out = (float*)d_out;

    char* w = (char*)d_ws;
    auto take = [&](size_t bytes) { void* p = (void*)w; w += (bytes + 255) & ~(size_t)255; return p; };
    ushort_t* xsum = (ushort_t*)take(16384ll * 1024 * 2);   // 33.55MB
    ushort_t* feat = (ushort_t*)take(16384ll * 1024 * 2);   // 33.55MB
    ushort_t* fbuf = (ushort_t*)take(16384ll * 256 * 2);    // 8.39MB
    ushort_t* ftb  = (ushort_t*)take(64ll * 256 * 256 * 2); // 8.39MB (reused as ybuf)
    ushort_t* ybuf = ftb;
    ushort_t* qbuf = (ushort_t*)take(16384ll * 128 * 2);    // 4.19MB
    ushort_t* qc   = (ushort_t*)take(16384ll * 128 * 2);    // 4.19MB \ lx aliases
    ushort_t* Pt   = (ushort_t*)take(64ll * 128 * 256 * 2); // 4.19MB /  [qc|Pt]
    ushort_t* lx   = qc;
    ushort_t* Pb   = (ushort_t*)take(16384ll * 128 * 2);    // 4.19MB
    ushort_t* St   = (ushort_t*)take(64ll * 256 * 128 * 2); // 4.19MB
    ushort_t* wbig = (ushort_t*)take(256ll * 10240 * 2);    // 5.24MB
    ushort_t* w1b  = (ushort_t*)take(1024ll * 256 * 2);
    ushort_t* w3b  = (ushort_t*)take(1024ll * 256 * 2);
    ushort_t* ckb  = (ushort_t*)take(128ll * 256 * 2);
    ushort_t* gcnT = (ushort_t*)take(256ll * 256 * 2);
    float*    fbias = (float*)take(3 * 256 * 4);
    float*    avg   = (float*)take(64 * 256 * 4);
    float*    mxp   = (float*)take(64 * 256 * 4);
    float*    cwb   = (float*)take(64 * 128 * 4);
    float*    dsum  = (float*)take(64 * 256 * 4);

    size_t need = (size_t)(w - (char*)d_ws);
    if (need > ws_size) {
        // sentinel: encode ws budget (MB) so the failing absmax reveals it
        float v = 1.0e6f + (float)(ws_size >> 20);
        k_sentinel<<<(out_size + 255) / 256, 256, 0, stream>>>(out, out_size, v);
        return;
    }

    k_upsum<<<dim3(64, 16), 256, 0, stream>>>(x_cur, x_lat, xsum);
    k_cast<<<1024, 256, 0, stream>>>(conv1_w, w1b);
    k_cast<<<128, 256, 0, stream>>>(ck_w, ckb);
    k_castT256<<<256, 256, 0, stream>>>(gcn_w, gcnT);
    k_bias2<<<3, 256, 0, stream>>>(rate_b[0], rate_b[1], rate_b[2], conv_b, fbias);

    for (int s = 0; s < 3; ++s) {
        k_wbig<<<dim3(40, 256), 256, 0, stream>>>(rate_w[s], conv_w, wbig);
        k_w3s<<<1024, 256, 0, stream>>>(conv3_w, w3b, s);

        { // BIG: f_s = conv3x3(dil=2^s) + rate_b + conv1x1 + conv_b, bf16 -> fbuf
            GemmP p{};
            p.A = (s == 0) ? xsum : feat;
            p.B = wbig; p.ldb = 10240;
            p.Ksub = 10240; p.dil = 1 << s;
            p.bias = fbias + s * 256;
            p.obf = fbuf; p.ldo = 256;
            gemm_k<64, 128, 1, EPI_BIAS><<<dim3(256, 2, 1), 256, 0, stream>>>(p);
        }
        k_pool<<<64, 256, 0, stream>>>(fbuf, avg, mxp);
        k_cw<<<64, 128, 0, stream>>>(avg, mxp, avg_w, max_w, cwb);
        { // q = relu(f @ ck_w^T + ck_b)  [16384][128]
            GemmP p{};
            p.A = fbuf; p.lda = 256; p.B = ckb; p.ldb = 256;
            p.Ksub = 256;
            p.bias = ck_b; p.obf = qbuf; p.ldo = 128;
            gemm_k<128, 128, 0, EPI_RELU><<<dim3(128, 1, 1), 256, 0, stream>>>(p);
        }
        k_qc<<<8192, 256, 0, stream>>>(qbuf, cwb, qc);
        hipMemsetAsync(dsum, 0, 64 * 256 * 4, stream);
        { // dsum[b][i] = sum_j sigmoid( (q*cw)[i,:] . q[j,:] )
            GemmP p{};
            p.A = qc;   p.aBatch = 32768; p.lda = 128;
            p.B = qbuf; p.bBatch = 32768; p.ldb = 128;
            p.Ksub = 128; p.dsum = dsum;
            gemm_k<128, 128, 0, EPI_SIG><<<dim3(2, 2, 64), 256, 0, stream>>>(p);
        }
        k_pscale<<<8192, 256, 0, stream>>>(qbuf, dsum, Pb, Pt);
        k_ft<<<16384, 256, 0, stream>>>(fbuf, ftb);
        { // St[b][c][m] = cw[m] * (P^T X)[m][c]
            GemmP p{};
            p.A = Pt;  p.aBatch = 32768; p.lda = 256;
            p.B = ftb; p.bBatch = 65536; p.ldb = 256;
            p.Ksub = 256; p.cw = cwb;
            p.obf = St; p.oBatch = 32768;
            gemm_k<128, 128, 0, EPI_PTX><<<dim3(1, 2, 64), 256, 0, stream>>>(p);
        }
        { // LX = X - P @ St^T
            GemmP p{};
            p.A = Pb; p.aBatch = 32768; p.lda = 128;
            p.B = St; p.bBatch = 32768; p.ldb = 128;
            p.Ksub = 128;
            p.res = fbuf; p.resBatch = 65536; p.ldres = 256;
            p.obf = lx; p.oBatch = 65536; p.ldo = 256;
            gemm_k<128, 128, 0, EPI_LX><<<dim3(2, 2, 64), 256, 0, stream>>>(p);
        }
        { // Y = X + LX @ gcn_w -> ybuf [16384][256]
            GemmP p{};
            p.A = lx;   p.aBatch = 65536; p.lda = 256;
            p.B = gcnT; p.bBatch = 0;     p.ldb = 256;
            p.Ksub = 256;
            p.res = fbuf; p.resBatch = 65536; p.ldres = 256;
            p.obf = ybuf; p.oBatch = 65536; p.ldo = 256;
            gemm_k<128, 128, 0, EPI_Y><<<dim3(2, 2, 64), 256, 0, stream>>>(p);
        }
        { // out (+)= ybuf @ w3_slice^T (+ conv3_b at s==0), fp32 NCHW
            GemmP p{};
            p.A = ybuf; p.lda = 256; p.B = w3b; p.ldb = 256;
            p.Ksub = 256; p.bias = conv3_b; p.of32 = out;
            if (s == 0)
                gemm_k<128, 128, 0, EPI_OUT0><<<dim3(128, 8, 1), 256, 0, stream>>>(p);
            else
                gemm_k<128, 128, 0, EPI_OUTA><<<dim3(128, 8, 1), 256, 0, stream>>>(p);
        }
        if (s < 2) { // feature = conv1(f) + conv1_b + x_sum -> feat [16384][1024]
            GemmP p{};
            p.A = fbuf; p.lda = 256; p.B = w1b; p.ldb = 256;
            p.Ksub = 256; p.bias = conv1_b;
            p.res = xsum; p.ldres = 1024;
            p.obf = feat; p.ldo = 1024;
            gemm_k<128, 128, 0, EPI_FEAT><<<dim3(128, 8, 1), 256, 0, stream>>>(p);
        }
    }
}

// Round 4
// 926.275 us; speedup vs baseline: 1.3087x; 1.1102x over previous
//
#include <hip/hip_runtime.h>

typedef unsigned short ushort_t;
typedef unsigned int uint32;
typedef __attribute__((ext_vector_type(8))) unsigned short ushort8;
typedef __attribute__((ext_vector_type(4))) unsigned short ushort4v;
typedef __attribute__((ext_vector_type(8))) __bf16 bf16x8;
typedef __attribute__((ext_vector_type(4))) float f32x4;

__device__ __forceinline__ ushort_t f2b(float f) {
    union { float f; uint32 u; } v; v.f = f;
    uint32 r = v.u + 0x7fffu + ((v.u >> 16) & 1u);
    return (ushort_t)(r >> 16);
}
__device__ __forceinline__ float b2f(ushort_t b) {
    union { uint32 u; float f; } v; v.u = ((uint32)b) << 16;
    return v.f;
}
__device__ __forceinline__ float sigm(float x) { return 1.f / (1.f + __expf(-x)); }

// epilogues
constexpr int EPI_BIAS = 0;  // bf16 (acc+bias) -> obf[row*ldo+col]
constexpr int EPI_RELU = 1;  // bf16 relu(acc+bias) -> obf[row*ldo+col]
constexpr int EPI_FEAT = 2;  // bf16 acc+bias+res[row*ldres+col] -> obf[row*ldo+col]
constexpr int EPI_SIG  = 3;  // rowsum of sigmoid(acc) -> atomicAdd dsum[z*256+row]
constexpr int EPI_PTX  = 4;  // bf16 cw[z*128+row]*acc -> obf[z*oBatch + col*128 + row]
constexpr int EPI_LX   = 5;  // bf16 res - acc -> obf
constexpr int EPI_Y    = 6;  // bf16 res + acc -> obf
constexpr int EPI_OUT0 = 7;  // fp32 acc+bias -> out NCHW (write)
constexpr int EPI_OUTA = 8;  // fp32 out += acc (accumulate) NCHW
constexpr int EPI_TMP  = 9;  // fp32 acc -> of32[z*oBatch + row*256 + col] (split-K partial)

struct GemmP {
    const ushort_t* A; const ushort_t* B;
    long long aBatch, bBatch;
    int lda, ldb;
    int Ksub, kSplit, dil;
    const float* bias;
    const ushort_t* res; long long resBatch; int ldres;
    ushort_t* obf; long long oBatch; int ldo;
    float* of32;
    const float* cw;
    float* dsum;
};

// Generic 4-wave MFMA GEMM: C[M,N] = A[M,K] . B[N,K]^T, bf16 in, fp32 acc.
// AMODE==1: A is implicit 10-tap dilated-conv im2col over unpadded
//           [B][16][16][1024] bf16 (taps 0..8 = 3x3 conv with dilation p.dil,
//           tap 9 = identity), K = 10240, zero-fill out of bounds.
// Split-K: block z handles global K range [z*kSplit, z*kSplit+Ksub) (kSplit=0
//          for batched GEMMs where z = batch index via aBatch/bBatch).
// Fragment layout (m89/m91-verified): A/B row|col = lane&15, k=(lane>>4)*8+j;
// C/D col = lane&15, row = (lane>>4)*4 + reg.
// LDS tiles [rows][64] bf16 with T2 XOR swizzle (granule ^= (row&7)<<3) on
// BOTH ds_write and ds_read — r2->r3 this took bank conflicts 4.7e7 -> 0.
template<int BM, int BN, int AMODE, int EPI>
__global__ __launch_bounds__(256) void gemm_k(GemmP p) {
    __shared__ __align__(16) ushort_t aT[BM * 64];
    __shared__ __align__(16) ushort_t bT[BN * 64];
    constexpr int APASS = BM / 32, BPASS = BN / 32;
    constexpr int MFRAG = BM / 32, NFRAG = BN / 32;  // per-wave fragment counts
    const int tid = threadIdx.x;
    const int z = blockIdx.z;
    const int m0 = blockIdx.x * BM, n0 = blockIdx.y * BN;
    const int lane = tid & 63, wid = tid >> 6;
    const int l15 = lane & 15, l16 = lane >> 4;
    const int wr = wid >> 1, wc = wid & 1;
    const int srow = tid >> 3, scol = (tid & 7) * 8;
    const int swcol = scol ^ ((srow & 7) << 3);  // swizzled store column

    const ushort_t* aptr[APASS];
    int ayy[APASS], axx[APASS];
    if constexpr (AMODE == 1) {
#pragma unroll
        for (int pi = 0; pi < APASS; ++pi) {
            int m = m0 + pi * 32 + srow;
            int bb = m >> 8;
            ayy[pi] = (m >> 4) & 15; axx[pi] = m & 15;
            aptr[pi] = p.A + (long long)bb * 262144 + scol;
        }
    } else {
#pragma unroll
        for (int pi = 0; pi < APASS; ++pi)
            aptr[pi] = p.A + (long long)z * p.aBatch +
                       (long long)(m0 + pi * 32 + srow) * p.lda + scol;
    }
    const ushort_t* bptr[BPASS];
#pragma unroll
    for (int pi = 0; pi < BPASS; ++pi)
        bptr[pi] = p.B + (long long)z * p.bBatch +
                   (long long)(n0 + pi * 32 + srow) * p.ldb + scol;

    f32x4 acc[MFRAG][NFRAG];
#pragma unroll
    for (int i = 0; i < MFRAG; ++i)
#pragma unroll
        for (int j = 0; j < NFRAG; ++j) acc[i][j] = (f32x4){0.f, 0.f, 0.f, 0.f};

    ushort8 ar[APASS], br[BPASS];
    auto ldg = [&](int gk) {
        if constexpr (AMODE == 1) {
            int tap = gk >> 10, kin = gk & 1023;
            int dy = 0, dx = 0;
            if (tap < 9) { int ky = tap / 3; dy = (ky - 1) * p.dil; dx = (tap - ky * 3 - 1) * p.dil; }
#pragma unroll
            for (int pi = 0; pi < APASS; ++pi) {
                int iy = ayy[pi] + dy, ix = axx[pi] + dx;
                if (((unsigned)iy < 16u) && ((unsigned)ix < 16u))
                    ar[pi] = *(const ushort8*)(aptr[pi] + ((iy << 4) + ix) * 1024 + kin);
                else {
                    ushort8 zz = {};
                    ar[pi] = zz;
                }
            }
        } else {
#pragma unroll
            for (int pi = 0; pi < APASS; ++pi)
                ar[pi] = *(const ushort8*)(aptr[pi] + gk);
        }
#pragma unroll
        for (int pi = 0; pi < BPASS; ++pi)
            br[pi] = *(const ushort8*)(bptr[pi] + gk);
    };

    const int gk0 = z * p.kSplit;
    ldg(gk0);
    const int iters = p.Ksub >> 6;
    for (int it = 0; it < iters; ++it) {
#pragma unroll
        for (int pi = 0; pi < APASS; ++pi)
            *(ushort8*)&aT[(pi * 32 + srow) * 64 + swcol] = ar[pi];
#pragma unroll
        for (int pi = 0; pi < BPASS; ++pi)
            *(ushort8*)&bT[(pi * 32 + srow) * 64 + swcol] = br[pi];
        __syncthreads();
        if (it + 1 < iters) ldg(gk0 + (it + 1) * 64);
#pragma unroll
        for (int ks = 0; ks < 2; ++ks) {
            bf16x8 af[MFRAG], bfr[NFRAG];
#pragma unroll
            for (int mi = 0; mi < MFRAG; ++mi) {
                int rr = wr * (BM / 2) + mi * 16 + l15;
                int cc = (ks * 32 + l16 * 8) ^ ((rr & 7) << 3);
                af[mi] = __builtin_bit_cast(bf16x8, *(const ushort8*)&aT[rr * 64 + cc]);
            }
#pragma unroll
            for (int ni = 0; ni < NFRAG; ++ni) {
                int rr = wc * (BN / 2) + ni * 16 + l15;
                int cc = (ks * 32 + l16 * 8) ^ ((rr & 7) << 3);
                bfr[ni] = __builtin_bit_cast(bf16x8, *(const ushort8*)&bT[rr * 64 + cc]);
            }
#pragma unroll
            for (int mi = 0; mi < MFRAG; ++mi)
#pragma unroll
                for (int ni = 0; ni < NFRAG; ++ni)
                    acc[mi][ni] = __builtin_amdgcn_mfma_f32_16x16x32_bf16(af[mi], bfr[ni], acc[mi][ni], 0, 0, 0);
        }
        __syncthreads();
    }

    // ---------------- epilogue ----------------
#pragma unroll
    for (int mi = 0; mi < MFRAG; ++mi) {
        if constexpr (EPI == EPI_SIG) {
#pragma unroll
            for (int r = 0; r < 4; ++r) {
                float sv = 0.f;
#pragma unroll
                for (int ni = 0; ni < NFRAG; ++ni) sv += sigm(acc[mi][ni][r]);
                sv += __shfl_xor(sv, 1); sv += __shfl_xor(sv, 2);
                sv += __shfl_xor(sv, 4); sv += __shfl_xor(sv, 8);
                if (l15 == 0) {
                    int grow = m0 + wr * (BM / 2) + mi * 16 + l16 * 4 + r;
                    atomicAdd(&p.dsum[z * 256 + grow], sv);
                }
            }
        } else {
#pragma unroll
            for (int ni = 0; ni < NFRAG; ++ni) {
                int gcol = n0 + wc * (BN / 2) + ni * 16 + l15;
                int growb = m0 + wr * (BM / 2) + mi * 16 + l16 * 4;
#pragma unroll
                for (int r = 0; r < 4; ++r) {
                    int grow = growb + r;
                    float v = acc[mi][ni][r];
                    if constexpr (EPI == EPI_BIAS) {
                        v += p.bias[gcol];
                        p.obf[(long long)grow * p.ldo + gcol] = f2b(v);
                    } else if constexpr (EPI == EPI_RELU) {
                        v += p.bias[gcol]; v = fmaxf(v, 0.f);
                        p.obf[(long long)grow * p.ldo + gcol] = f2b(v);
                    } else if constexpr (EPI == EPI_FEAT) {
                        v += p.bias[gcol] + b2f(p.res[(long long)grow * p.ldres + gcol]);
                        p.obf[(long long)grow * p.ldo + gcol] = f2b(v);
                    } else if constexpr (EPI == EPI_PTX) {
                        v *= p.cw[z * 128 + grow];
                        p.obf[(long long)z * p.oBatch + (long long)gcol * 128 + grow] = f2b(v);
                    } else if constexpr (EPI == EPI_LX) {
                        v = b2f(p.res[(long long)z * p.resBatch + (long long)grow * p.ldres + gcol]) - v;
                        p.obf[(long long)z * p.oBatch + (long long)grow * p.ldo + gcol] = f2b(v);
                    } else if constexpr (EPI == EPI_Y) {
                        v = b2f(p.res[(long long)z * p.resBatch + (long long)grow * p.ldres + gcol]) + v;
                        p.obf[(long long)z * p.oBatch + (long long)grow * p.ldo + gcol] = f2b(v);
                    } else if constexpr (EPI == EPI_OUT0) {
                        v += p.bias[gcol];
                        int bb = grow >> 8, px = grow & 255;
                        p.of32[((long long)bb * 1024 + gcol) * 256 + px] = v;
                    } else if constexpr (EPI == EPI_OUTA) {
                        int bb = grow >> 8, px = grow & 255;
                        long long o = ((long long)bb * 1024 + gcol) * 256 + px;
                        p.of32[o] = p.of32[o] + v;
                    } else if constexpr (EPI == EPI_TMP) {
                        p.of32[(long long)z * p.oBatch + (long long)grow * 256 + gcol] = v;
                    }
                }
            }
        }
    }
}

// ---------------- small kernels ----------------

// combine 4 split-K fp32 partials + bias -> bf16 fbuf; float4-vectorized
__global__ void k_combine(const float* __restrict__ t, const float* __restrict__ fbias_s,
                          ushort_t* __restrict__ f) {
    int idx = blockIdx.x * 256 + threadIdx.x;  // over 16384*256/4
    const long long N = 16384ll * 256 / 4;
    const float4* t4 = (const float4*)t;
    float4 a = t4[idx], b = t4[idx + N], c = t4[idx + 2 * N], d = t4[idx + 3 * N];
    int cb = (idx * 4) & 255;
    ushort4v o;
    o.x = f2b(a.x + b.x + c.x + d.x + fbias_s[cb]);
    o.y = f2b(a.y + b.y + c.y + d.y + fbias_s[cb + 1]);
    o.z = f2b(a.z + b.z + c.z + d.z + fbias_s[cb + 2]);
    o.w = f2b(a.w + b.w + c.w + d.w + fbias_s[cb + 3]);
    *(ushort4v*)&f[idx * 4] = o;
}

// x_sum = x_cur * (1 + bilinear_up2x_align_corners(x_lat)); bf16 [B*256][1024]
__global__ void k_upsum(const float* __restrict__ xc, const float* __restrict__ xl,
                        ushort_t* __restrict__ xs) {
    __shared__ float lat[64 * 64];
    __shared__ ushort_t tile[64 * 258];
    int b = blockIdx.x, c0 = blockIdx.y * 64;
    int t = threadIdx.x;
    for (int i = t; i < 4096; i += 256)
        lat[i] = xl[((long long)(b * 1024 + c0 + (i >> 6))) * 64 + (i & 63)];
    __syncthreads();
    int y = t >> 4, x = t & 15;
    float fy = y * (7.f / 15.f); int y0 = (int)fy; float wy = fy - y0; int y1 = y0 + 1 > 7 ? 7 : y0 + 1;
    float fx = x * (7.f / 15.f); int x0 = (int)fx; float wx = fx - x0; int x1 = x0 + 1 > 7 ? 7 : x0 + 1;
    for (int cc = 0; cc < 64; ++cc) {
        float cur = xc[((long long)(b * 1024 + c0 + cc)) * 256 + t];
        const float* L = &lat[cc * 64];
        float tv = L[y0 * 8 + x0] * (1.f - wx) + L[y0 * 8 + x1] * wx;
        float bv = L[y1 * 8 + x0] * (1.f - wx) + L[y1 * 8 + x1] * wx;
        float up = tv + (bv - tv) * wy;
        tile[cc * 258 + t] = f2b(cur * (1.f + up));
    }
    __syncthreads();
    for (int i = t; i < 16384; i += 256) {
        int px = i >> 6, cc = i & 63;
        xs[((long long)(b * 256 + px)) * 1024 + c0 + cc] = tile[cc * 258 + px];
    }
}

__global__ void k_pool(const ushort_t* __restrict__ f, float* __restrict__ avg, float* __restrict__ mx) {
    int b = blockIdx.x, c = threadIdx.x;
    float s = 0.f, m = -3.4e38f;
    const ushort_t* base = f + (long long)b * 65536 + c;
    for (int px = 0; px < 256; ++px) { float v = b2f(base[px * 256]); s += v; m = fmaxf(m, v); }
    avg[b * 256 + c] = s * (1.f / 256.f);
    mx[b * 256 + c] = m;
}

__global__ void k_cw(const float* __restrict__ avg, const float* __restrict__ mx,
                     const float* __restrict__ aw, const float* __restrict__ mw,
                     float* __restrict__ cw) {
    __shared__ float sa[256], sm[256];
    int b = blockIdx.x, t = threadIdx.x; // 128 threads
    sa[t] = avg[b * 256 + t]; sa[t + 128] = avg[b * 256 + t + 128];
    sm[t] = mx[b * 256 + t];  sm[t + 128] = mx[b * 256 + t + 128];
    __syncthreads();
    float s1 = 0.f, s2 = 0.f;
    const float* a = aw + t * 256; const float* w = mw + t * 256;
    for (int c = 0; c < 256; ++c) { s1 += sa[c] * a[c]; s2 += sm[c] * w[c]; }
    s1 = fmaxf(s1, 0.f); s2 = fmaxf(s2, 0.f);
    cw[b * 128 + t] = sigm(s1 + s2);
}

__global__ void k_qc(const ushort_t* __restrict__ q, const float* __restrict__ cw,
                     ushort_t* __restrict__ qc) {
    int idx = blockIdx.x * 256 + threadIdx.x;
    int m = idx & 127; int b = idx >> 15;
    qc[idx] = f2b(b2f(q[idx]) * cw[(b << 7) + m]);
}

__global__ void k_pscale(const ushort_t* __restrict__ q, const float* __restrict__ dsum,
                         ushort_t* __restrict__ P, ushort_t* __restrict__ Pt) {
    int idx = blockIdx.x * 256 + threadIdx.x; // 2,097,152
    int m = idx & 127; int pix = idx >> 7;
    int b = pix >> 8, j = pix & 255;
    float d = rsqrtf(dsum[pix]);
    ushort_t v = f2b(d * b2f(q[idx]));
    P[idx] = v;
    Pt[((long long)b << 15) + (m << 8) + j] = v;
}

__global__ void k_ft(const ushort_t* __restrict__ f, ushort_t* __restrict__ ft) {
    long long idx = (long long)blockIdx.x * 256 + threadIdx.x; // 64*65536
    int r = (int)(idx & 65535); int b = (int)(idx >> 16);
    int c = r >> 8, j = r & 255;
    ft[idx] = f[((long long)(b * 256 + j)) * 256 + c];
}

// pack stage-s big-GEMM weight: [o<256][tap<10 * 1024]; taps 0..8 = rate(3x3), 9 = conv1x1
__global__ void k_wbig(const float* __restrict__ rate, const float* __restrict__ convw,
                       ushort_t* __restrict__ dst) {
    int gk = blockIdx.x * 256 + threadIdx.x; // 10240
    int o = blockIdx.y;
    int tap = gk >> 10, ci = gk & 1023;
    float v = (tap < 9) ? rate[(long long)o * 9216 + ci * 9 + tap] : convw[(long long)o * 1024 + ci];
    dst[(long long)o * 10240 + gk] = f2b(v);
}

__global__ void k_w3s(const float* __restrict__ w3, ushort_t* __restrict__ dst, int s) {
    int o = blockIdx.x, c = threadIdx.x;
    dst[o * 256 + c] = f2b(w3[o * 768 + s * 256 + c]);
}

__global__ void k_cast(const float* __restrict__ s, ushort_t* __restrict__ d) {
    int i = blockIdx.x * 256 + threadIdx.x; d[i] = f2b(s[i]);
}
__global__ void k_castT256(const float* __restrict__ s, ushort_t* __restrict__ d) {
    int c1 = threadIdx.x, c2 = blockIdx.x;
    d[c2 * 256 + c1] = f2b(s[c1 * 256 + c2]);
}
__global__ void k_bias2(const float* a0, const float* a1, const float* a2,
                        const float* cb, float* dst) {
    int t = threadIdx.x; int s = blockIdx.x;
    const float* a = s == 0 ? a0 : (s == 1 ? a1 : a2);
    dst[s * 256 + t] = a[t] + cb[t];
}
__global__ void k_sentinel(float* o, int n, float v) {
    int i = blockIdx.x * 256 + threadIdx.x; if (i < n) o[i] = v;
}

// ---------------- launch ----------------
extern "C" void kernel_launch(void* const* d_in, const int* in_sizes, int n_in,
                              void* d_out, int out_size, void* d_ws, size_t ws_size,
                              hipStream_t stream) {
    const float* x_cur  = (const float*)d_in[0];
    const float* x_lat  = (const float*)d_in[1];
    const float* conv_w = (const float*)d_in[2];
    const float* conv_b = (const float*)d_in[3];
    const float* conv1_w = (const float*)d_in[4];
    const float* conv1_b = (const float*)d_in[5];
    const float* conv3_w = (const float*)d_in[6];
    const float* conv3_b = (const float*)d_in[7];
    const float* rate_w[3] = {(const float*)d_in[8], (const float*)d_in[10], (const float*)d_in[12]};
    const float* rate_b[3] = {(const float*)d_in[9], (const float*)d_in[11], (const float*)d_in[13]};
    const float* ck_w  = (const float*)d_in[14];
    const float* ck_b  = (const float*)d_in[15];
    const float* avg_w = (const float*)d_in[16];
    const float* max_w = (const float*)d_in[17];
    const float* gcn_w = (const float*)d_in[18];
    float* out = (float*)d_out;

    char* w = (char*)d_ws;
    auto take = [&](size_t bytes) { void* p = (void*)w; w += (bytes + 255) & ~(size_t)255; return p; };
    // ---- shared allocations (all tiers) ----
    ushort_t* xsum = (ushort_t*)take(16384ll * 1024 * 2);   // 33.55MB
    ushort_t* feat = (ushort_t*)take(16384ll * 1024 * 2);   // 33.55MB
    ushort_t* fbuf = (ushort_t*)take(16384ll * 256 * 2);    // 8.39MB
    ushort_t* ftb  = (ushort_t*)take(64ll * 256 * 256 * 2); // 8.39MB (tier C: also ybuf)
    ushort_t* ybuf = ftb;
    ushort_t* qbuf = (ushort_t*)take(16384ll * 128 * 2);    // 4.19MB
    ushort_t* qc   = (ushort_t*)take(16384ll * 128 * 2);    // 4.19MB \ lx aliases
    ushort_t* Pt   = (ushort_t*)take(64ll * 128 * 256 * 2); // 4.19MB /  [qc|Pt]
    ushort_t* lx   = qc;
    ushort_t* Pb   = (ushort_t*)take(16384ll * 128 * 2);    // 4.19MB
    ushort_t* St   = (ushort_t*)take(64ll * 256 * 128 * 2); // 4.19MB
    ushort_t* wbig = (ushort_t*)take(256ll * 10240 * 2);    // 5.24MB
    ushort_t* w1b  = (ushort_t*)take(1024ll * 256 * 2);
    ushort_t* w3b  = (ushort_t*)take(1024ll * 768 * 2);     // full cast (A/B); C uses slices
    ushort_t* ckb  = (ushort_t*)take(128ll * 256 * 2);
    ushort_t* gcnT = (ushort_t*)take(256ll * 256 * 2);
    float*    fbias = (float*)take(3 * 256 * 4);
    float*    avg   = (float*)take(64 * 256 * 4);
    float*    mxp   = (float*)take(64 * 256 * 4);
    float*    cwb   = (float*)take(64 * 128 * 4);
    float*    dsum  = (float*)take(64 * 256 * 4);
    size_t needC = (size_t)(w - (char*)d_ws);
    // ---- tier B extra: cat buffer, single final GEMM ----
    ushort_t* catb = (ushort_t*)take(16384ll * 768 * 2);    // 25.17MB
    size_t needB = (size_t)(w - (char*)d_ws);
    // ---- tier A extra: split-K fp32 partials ----
    float* ftmp = (float*)take(4ll * 16384 * 256 * 4);      // 67.11MB
    size_t needA = (size_t)(w - (char*)d_ws);

    int tier;
    if (needA <= ws_size) tier = 0;        // A: split-K BIG + catb
    else if (needB <= ws_size) tier = 1;   // B: direct BIG + catb
    else if (needC <= ws_size) tier = 2;   // C: round-3 structure
    else {
        float v = 1.0e6f + (float)(ws_size >> 20);
        k_sentinel<<<(out_size + 255) / 256, 256, 0, stream>>>(out, out_size, v);
        return;
    }

    k_upsum<<<dim3(64, 16), 256, 0, stream>>>(x_cur, x_lat, xsum);
    k_cast<<<1024, 256, 0, stream>>>(conv1_w, w1b);
    k_cast<<<128, 256, 0, stream>>>(ck_w, ckb);
    k_castT256<<<256, 256, 0, stream>>>(gcn_w, gcnT);
    k_bias2<<<3, 256, 0, stream>>>(rate_b[0], rate_b[1], rate_b[2], conv_b, fbias);
    if (tier != 2) k_cast<<<3072, 256, 0, stream>>>(conv3_w, w3b);

    for (int s = 0; s < 3; ++s) {
        k_wbig<<<dim3(40, 256), 256, 0, stream>>>(rate_w[s], conv_w, wbig);
        if (tier == 2) k_w3s<<<1024, 256, 0, stream>>>(conv3_w, w3b, s);

        // BIG: f_s = conv3x3(dil=2^s) + rate_b + conv1x1 + conv_b -> fbuf (bf16)
        if (tier == 0) {
            GemmP p{};
            p.A = (s == 0) ? xsum : feat;
            p.B = wbig; p.ldb = 10240;
            p.Ksub = 2560; p.kSplit = 2560; p.dil = 1 << s;
            p.of32 = ftmp; p.oBatch = 16384ll * 256;
            gemm_k<128, 128, 1, EPI_TMP><<<dim3(128, 2, 4), 256, 0, stream>>>(p);
            k_combine<<<4096, 256, 0, stream>>>(ftmp, fbias + s * 256, fbuf);
        } else {
            GemmP p{};
            p.A = (s == 0) ? xsum : feat;
            p.B = wbig; p.ldb = 10240;
            p.Ksub = 10240; p.dil = 1 << s;
            p.bias = fbias + s * 256;
            p.obf = fbuf; p.ldo = 256;
            gemm_k<64, 128, 1, EPI_BIAS><<<dim3(256, 2, 1), 256, 0, stream>>>(p);
        }
        k_pool<<<64, 256, 0, stream>>>(fbuf, avg, mxp);
        k_cw<<<64, 128, 0, stream>>>(avg, mxp, avg_w, max_w, cwb);
        { // q = relu(f @ ck_w^T + ck_b)  [16384][128]
            GemmP p{};
            p.A = fbuf; p.lda = 256; p.B = ckb; p.ldb = 256;
            p.Ksub = 256;
            p.bias = ck_b; p.obf = qbuf; p.ldo = 128;
            gemm_k<128, 128, 0, EPI_RELU><<<dim3(128, 1, 1), 256, 0, stream>>>(p);
        }
        k_qc<<<8192, 256, 0, stream>>>(qbuf, cwb, qc);
        hipMemsetAsync(dsum, 0, 64 * 256 * 4, stream);
        { // dsum[b][i] = sum_j sigmoid( (q*cw)[i,:] . q[j,:] )
            GemmP p{};
            p.A = qc;   p.aBatch = 32768; p.lda = 128;
            p.B = qbuf; p.bBatch = 32768; p.ldb = 128;
            p.Ksub = 128; p.dsum = dsum;
            gemm_k<128, 128, 0, EPI_SIG><<<dim3(2, 2, 64), 256, 0, stream>>>(p);
        }
        k_pscale<<<8192, 256, 0, stream>>>(qbuf, dsum, Pb, Pt);
        k_ft<<<16384, 256, 0, stream>>>(fbuf, ftb);
        { // St[b][c][m] = cw[m] * (P^T X)[m][c]
            GemmP p{};
            p.A = Pt;  p.aBatch = 32768; p.lda = 256;
            p.B = ftb; p.bBatch = 65536; p.ldb = 256;
            p.Ksub = 256; p.cw = cwb;
            p.obf = St; p.oBatch = 32768;
            gemm_k<128, 128, 0, EPI_PTX><<<dim3(1, 2, 64), 256, 0, stream>>>(p);
        }
        { // LX = X - P @ St^T
            GemmP p{};
            p.A = Pb; p.aBatch = 32768; p.lda = 128;
            p.B = St; p.bBatch = 32768; p.ldb = 128;
            p.Ksub = 128;
            p.res = fbuf; p.resBatch = 65536; p.ldres = 256;
            p.obf = lx; p.oBatch = 65536; p.ldo = 256;
            gemm_k<128, 128, 0, EPI_LX><<<dim3(2, 2, 64), 256, 0, stream>>>(p);
        }
        { // Y = X + LX @ gcn_w
            GemmP p{};
            p.A = lx;   p.aBatch = 65536; p.lda = 256;
            p.B = gcnT; p.bBatch = 0;     p.ldb = 256;
            p.Ksub = 256;
            p.res = fbuf; p.resBatch = 65536; p.ldres = 256;
            if (tier != 2) {  // -> catb slice [16384][768]
                p.obf = catb + s * 256; p.oBatch = 256ll * 768; p.ldo = 768;
            } else {          // -> ybuf [16384][256]
                p.obf = ybuf; p.oBatch = 65536; p.ldo = 256;
            }
            gemm_k<128, 128, 0, EPI_Y><<<dim3(2, 2, 64), 256, 0, stream>>>(p);
        }
        if (tier == 2) { // out (+)= ybuf @ w3_slice^T (+ conv3_b at s==0), fp32 NCHW
            GemmP p{};
            p.A = ybuf; p.lda = 256; p.B = w3b; p.ldb = 256;
            p.Ksub = 256; p.bias = conv3_b; p.of32 = out;
            if (s == 0)
                gemm_k<128, 128, 0, EPI_OUT0><<<dim3(128, 8, 1), 256, 0, stream>>>(p);
            else
                gemm_k<128, 128, 0, EPI_OUTA><<<dim3(128, 8, 1), 256, 0, stream>>>(p);
        }
        if (s < 2) { // feature = conv1(f) + conv1_b + x_sum -> feat [16384][1024]
            GemmP p{};
            p.A = fbuf; p.lda = 256; p.B = w1b; p.ldb = 256;
            p.Ksub = 256; p.bias = conv1_b;
            p.res = xsum; p.ldres = 1024;
            p.obf = feat; p.ldo = 1024;
            gemm_k<128, 128, 0, EPI_FEAT><<<dim3(128, 8, 1), 256, 0, stream>>>(p);
        }
    }
    if (tier != 2) { // out = catb @ conv3_w^T + conv3_b, single K=768 GEMM, fp32 NCHW
        GemmP p{};
        p.A = catb; p.lda = 768; p.B = w3b; p.ldb = 768;
        p.Ksub = 768; p.bias = conv3_b; p.of32 = out;
        gemm_k<128, 128, 0, EPI_OUT0><<<dim3(128, 8, 1), 256, 0, stream>>>(p);
    }
}

// Round 5
// 890.229 us; speedup vs baseline: 1.3617x; 1.0405x over previous
//
#include <hip/hip_runtime.h>

typedef unsigned short ushort_t;
typedef unsigned int uint32;
typedef __attribute__((ext_vector_type(8))) unsigned short ushort8;
typedef __attribute__((ext_vector_type(4))) unsigned short ushort4v;
typedef __attribute__((ext_vector_type(8))) __bf16 bf16x8;
typedef __attribute__((ext_vector_type(4))) float f32x4;

__device__ __forceinline__ ushort_t f2b(float f) {
    union { float f; uint32 u; } v; v.f = f;
    uint32 r = v.u + 0x7fffu + ((v.u >> 16) & 1u);
    return (ushort_t)(r >> 16);
}
__device__ __forceinline__ float b2f(ushort_t b) {
    union { uint32 u; float f; } v; v.u = ((uint32)b) << 16;
    return v.f;
}
__device__ __forceinline__ float sigm(float x) { return 1.f / (1.f + __expf(-x)); }

// async global->LDS, 16B per lane. LDS dest = wave-uniform base + lane*16.
__device__ __forceinline__ void gload_lds16(const void* g, void* l) {
    __builtin_amdgcn_global_load_lds(
        (__attribute__((address_space(1))) void*)g,
        (__attribute__((address_space(3))) void*)l, 16, 0, 0);
}

// epilogues
constexpr int EPI_BIAS = 0;  // bf16 (acc+bias) -> obf[row*ldo+col]
constexpr int EPI_RELU = 1;  // bf16 relu(acc+bias) -> obf; also obf2 = relu*cw (fused qc)
constexpr int EPI_FEAT = 2;  // bf16 acc+bias+res[row*ldres+col] -> obf[row*ldo+col]
constexpr int EPI_SIG  = 3;  // rowsum of sigmoid(acc) -> atomicAdd dsum[z*256+row]
constexpr int EPI_PTX  = 4;  // bf16 cw[z*128+row]*acc -> obf[z*oBatch + col*128 + row]
constexpr int EPI_LX   = 5;  // bf16 res - acc -> obf
constexpr int EPI_Y    = 6;  // bf16 res + acc -> obf
constexpr int EPI_OUT0 = 7;  // fp32 acc+bias -> out NCHW (write)
constexpr int EPI_OUTA = 8;  // fp32 out += acc (accumulate) NCHW
constexpr int EPI_TMP  = 9;  // fp32 acc -> of32[z*oBatch + row*256 + col] (split-K partial)

struct GemmP {
    const ushort_t* A; const ushort_t* B;
    long long aBatch, bBatch;
    int lda, ldb;
    int Ksub, kSplit, dil;
    const float* bias;
    const ushort_t* res; long long resBatch; int ldres;
    ushort_t* obf; long long oBatch; int ldo;
    ushort_t* obf2;
    float* of32;
    const float* cw;
    float* dsum;
    const ushort_t* zpage;
};

// ---------------------------------------------------------------------------
// BIG implicit-GEMM (conv3x3-dilated 9 taps + conv1x1 identity tap), m97-style
// global_load_lds staging, split-K. C = A_im2col[16384, 10240] . B[256,10240]^T
// 128x128 tile, BK=64, 4 waves. LDS image: S[r][g] = G[r][g ^ (r&7)] (granule
// = 16B), achieved by PRE-SWIZZLED per-lane global source (lane l fetches
// granule (l&7)^(l>>3) of row base8+(l>>3)); gload_lds writes linearly.
// Read side applies the same XOR -> conflict-free ds_read_b128 (r3-verified).
// OOB taps: per-lane select of a zeroed 16B page (validity uniform per row).
// ---------------------------------------------------------------------------
__global__ __launch_bounds__(256) void gemm_big(GemmP p) {
    __shared__ __align__(16) ushort_t aT[128 * 64];
    __shared__ __align__(16) ushort_t bT[128 * 64];
    const int tid = threadIdx.x;
    const int z = blockIdx.z;
    const int m0 = blockIdx.x * 128, n0 = blockIdx.y * 128;
    const int lane = tid & 63, wid = tid >> 6;
    const int l15 = lane & 15, l16 = lane >> 4;
    const int wr = wid >> 1, wc = wid & 1;
    const int lrow = lane >> 3;           // row within 8-row group
    const int sgran = (lane & 7) ^ lrow;  // pre-swizzled source granule

    int ayy[4], axx[4];
    const ushort_t* aBase[4];
    const ushort_t* bBase[4];
#pragma unroll
    for (int i = 0; i < 4; ++i) {
        int row = wid * 32 + i * 8 + lrow;
        int m = m0 + row;
        int bb = m >> 8;
        ayy[i] = (m >> 4) & 15; axx[i] = m & 15;
        aBase[i] = p.A + (long long)bb * 262144 + sgran * 8;
        bBase[i] = p.B + (long long)(n0 + row) * p.ldb + sgran * 8;
    }

    f32x4 acc[4][4];
#pragma unroll
    for (int i = 0; i < 4; ++i)
#pragma unroll
        for (int j = 0; j < 4; ++j) acc[i][j] = (f32x4){0.f, 0.f, 0.f, 0.f};

    const int gk0 = z * p.kSplit;
    const int iters = p.Ksub >> 6;
    for (int it = 0; it < iters; ++it) {
        const int gk = gk0 + it * 64;
        const int tap = gk >> 10, kin = gk & 1023;
        int dy = 0, dx = 0;
        if (tap < 9) { int ky = tap / 3; dy = (ky - 1) * p.dil; dx = (tap - ky * 3 - 1) * p.dil; }
#pragma unroll
        for (int i = 0; i < 4; ++i) {
            int iy = ayy[i] + dy, ix = axx[i] + dx;
            bool ok = ((unsigned)iy < 16u) && ((unsigned)ix < 16u);
            const ushort_t* ga = ok ? (aBase[i] + (((iy << 4) + ix) << 10) + kin) : p.zpage;
            gload_lds16(ga, &aT[(wid * 32 + i * 8) * 64]);
        }
#pragma unroll
        for (int i = 0; i < 4; ++i)
            gload_lds16(bBase[i] + gk, &bT[(wid * 32 + i * 8) * 64]);
        asm volatile("s_waitcnt vmcnt(0)" ::: "memory");
        __syncthreads();
#pragma unroll
        for (int ks = 0; ks < 2; ++ks) {
            bf16x8 af[4], bfr[4];
#pragma unroll
            for (int mi = 0; mi < 4; ++mi) {
                int rr = wr * 64 + mi * 16 + l15;
                int cc = (ks * 32 + l16 * 8) ^ ((rr & 7) << 3);
                af[mi] = __builtin_bit_cast(bf16x8, *(const ushort8*)&aT[rr * 64 + cc]);
            }
#pragma unroll
            for (int ni = 0; ni < 4; ++ni) {
                int rr = wc * 64 + ni * 16 + l15;
                int cc = (ks * 32 + l16 * 8) ^ ((rr & 7) << 3);
                bfr[ni] = __builtin_bit_cast(bf16x8, *(const ushort8*)&bT[rr * 64 + cc]);
            }
#pragma unroll
            for (int mi = 0; mi < 4; ++mi)
#pragma unroll
                for (int ni = 0; ni < 4; ++ni)
                    acc[mi][ni] = __builtin_amdgcn_mfma_f32_16x16x32_bf16(af[mi], bfr[ni], acc[mi][ni], 0, 0, 0);
        }
        __syncthreads();
    }
    // epilogue: fp32 split-K partial
#pragma unroll
    for (int mi = 0; mi < 4; ++mi)
#pragma unroll
        for (int ni = 0; ni < 4; ++ni) {
            int gcol = n0 + wc * 64 + ni * 16 + l15;
            int growb = m0 + wr * 64 + mi * 16 + l16 * 4;
#pragma unroll
            for (int r = 0; r < 4; ++r)
                p.of32[(long long)z * p.oBatch + (long long)(growb + r) * 256 + gcol] = acc[mi][ni][r];
        }
}

// Generic 4-wave MFMA GEMM: C[M,N] = A[M,K] . B[N,K]^T, bf16 in, fp32 acc.
// (reg-staged; used for all small/mid GEMMs. AMODE==1 im2col kept for tiers B/C.)
template<int BM, int BN, int AMODE, int EPI>
__global__ __launch_bounds__(256) void gemm_k(GemmP p) {
    __shared__ __align__(16) ushort_t aT[BM * 64];
    __shared__ __align__(16) ushort_t bT[BN * 64];
    constexpr int APASS = BM / 32, BPASS = BN / 32;
    constexpr int MFRAG = BM / 32, NFRAG = BN / 32;
    const int tid = threadIdx.x;
    const int z = blockIdx.z;
    const int m0 = blockIdx.x * BM, n0 = blockIdx.y * BN;
    const int lane = tid & 63, wid = tid >> 6;
    const int l15 = lane & 15, l16 = lane >> 4;
    const int wr = wid >> 1, wc = wid & 1;
    const int srow = tid >> 3, scol = (tid & 7) * 8;
    const int swcol = scol ^ ((srow & 7) << 3);

    const ushort_t* aptr[APASS];
    int ayy[APASS], axx[APASS];
    if constexpr (AMODE == 1) {
#pragma unroll
        for (int pi = 0; pi < APASS; ++pi) {
            int m = m0 + pi * 32 + srow;
            int bb = m >> 8;
            ayy[pi] = (m >> 4) & 15; axx[pi] = m & 15;
            aptr[pi] = p.A + (long long)bb * 262144 + scol;
        }
    } else {
#pragma unroll
        for (int pi = 0; pi < APASS; ++pi)
            aptr[pi] = p.A + (long long)z * p.aBatch +
                       (long long)(m0 + pi * 32 + srow) * p.lda + scol;
    }
    const ushort_t* bptr[BPASS];
#pragma unroll
    for (int pi = 0; pi < BPASS; ++pi)
        bptr[pi] = p.B + (long long)z * p.bBatch +
                   (long long)(n0 + pi * 32 + srow) * p.ldb + scol;

    f32x4 acc[MFRAG][NFRAG];
#pragma unroll
    for (int i = 0; i < MFRAG; ++i)
#pragma unroll
        for (int j = 0; j < NFRAG; ++j) acc[i][j] = (f32x4){0.f, 0.f, 0.f, 0.f};

    ushort8 ar[APASS], br[BPASS];
    auto ldg = [&](int gk) {
        if constexpr (AMODE == 1) {
            int tap = gk >> 10, kin = gk & 1023;
            int dy = 0, dx = 0;
            if (tap < 9) { int ky = tap / 3; dy = (ky - 1) * p.dil; dx = (tap - ky * 3 - 1) * p.dil; }
#pragma unroll
            for (int pi = 0; pi < APASS; ++pi) {
                int iy = ayy[pi] + dy, ix = axx[pi] + dx;
                if (((unsigned)iy < 16u) && ((unsigned)ix < 16u))
                    ar[pi] = *(const ushort8*)(aptr[pi] + ((iy << 4) + ix) * 1024 + kin);
                else {
                    ushort8 zz = {};
                    ar[pi] = zz;
                }
            }
        } else {
#pragma unroll
            for (int pi = 0; pi < APASS; ++pi)
                ar[pi] = *(const ushort8*)(aptr[pi] + gk);
        }
#pragma unroll
        for (int pi = 0; pi < BPASS; ++pi)
            br[pi] = *(const ushort8*)(bptr[pi] + gk);
    };

    const int gk0 = z * p.kSplit;
    ldg(gk0);
    const int iters = p.Ksub >> 6;
    for (int it = 0; it < iters; ++it) {
#pragma unroll
        for (int pi = 0; pi < APASS; ++pi)
            *(ushort8*)&aT[(pi * 32 + srow) * 64 + swcol] = ar[pi];
#pragma unroll
        for (int pi = 0; pi < BPASS; ++pi)
            *(ushort8*)&bT[(pi * 32 + srow) * 64 + swcol] = br[pi];
        __syncthreads();
        if (it + 1 < iters) ldg(gk0 + (it + 1) * 64);
#pragma unroll
        for (int ks = 0; ks < 2; ++ks) {
            bf16x8 af[MFRAG], bfr[NFRAG];
#pragma unroll
            for (int mi = 0; mi < MFRAG; ++mi) {
                int rr = wr * (BM / 2) + mi * 16 + l15;
                int cc = (ks * 32 + l16 * 8) ^ ((rr & 7) << 3);
                af[mi] = __builtin_bit_cast(bf16x8, *(const ushort8*)&aT[rr * 64 + cc]);
            }
#pragma unroll
            for (int ni = 0; ni < NFRAG; ++ni) {
                int rr = wc * (BN / 2) + ni * 16 + l15;
                int cc = (ks * 32 + l16 * 8) ^ ((rr & 7) << 3);
                bfr[ni] = __builtin_bit_cast(bf16x8, *(const ushort8*)&bT[rr * 64 + cc]);
            }
#pragma unroll
            for (int mi = 0; mi < MFRAG; ++mi)
#pragma unroll
                for (int ni = 0; ni < NFRAG; ++ni)
                    acc[mi][ni] = __builtin_amdgcn_mfma_f32_16x16x32_bf16(af[mi], bfr[ni], acc[mi][ni], 0, 0, 0);
        }
        __syncthreads();
    }

    // ---------------- epilogue ----------------
#pragma unroll
    for (int mi = 0; mi < MFRAG; ++mi) {
        if constexpr (EPI == EPI_SIG) {
#pragma unroll
            for (int r = 0; r < 4; ++r) {
                float sv = 0.f;
#pragma unroll
                for (int ni = 0; ni < NFRAG; ++ni) sv += sigm(acc[mi][ni][r]);
                sv += __shfl_xor(sv, 1); sv += __shfl_xor(sv, 2);
                sv += __shfl_xor(sv, 4); sv += __shfl_xor(sv, 8);
                if (l15 == 0) {
                    int grow = m0 + wr * (BM / 2) + mi * 16 + l16 * 4 + r;
                    atomicAdd(&p.dsum[z * 256 + grow], sv);
                }
            }
        } else {
#pragma unroll
            for (int ni = 0; ni < NFRAG; ++ni) {
                int gcol = n0 + wc * (BN / 2) + ni * 16 + l15;
                int growb = m0 + wr * (BM / 2) + mi * 16 + l16 * 4;
#pragma unroll
                for (int r = 0; r < 4; ++r) {
                    int grow = growb + r;
                    float v = acc[mi][ni][r];
                    if constexpr (EPI == EPI_BIAS) {
                        v += p.bias[gcol];
                        p.obf[(long long)grow * p.ldo + gcol] = f2b(v);
                    } else if constexpr (EPI == EPI_RELU) {
                        v += p.bias[gcol]; v = fmaxf(v, 0.f);
                        p.obf[(long long)grow * p.ldo + gcol] = f2b(v);
                        p.obf2[(long long)grow * p.ldo + gcol] =
                            f2b(v * p.cw[((grow >> 8) << 7) + gcol]);
                    } else if constexpr (EPI == EPI_FEAT) {
                        v += p.bias[gcol] + b2f(p.res[(long long)grow * p.ldres + gcol]);
                        p.obf[(long long)grow * p.ldo + gcol] = f2b(v);
                    } else if constexpr (EPI == EPI_PTX) {
                        v *= p.cw[z * 128 + grow];
                        p.obf[(long long)z * p.oBatch + (long long)gcol * 128 + grow] = f2b(v);
                    } else if constexpr (EPI == EPI_LX) {
                        v = b2f(p.res[(long long)z * p.resBatch + (long long)grow * p.ldres + gcol]) - v;
                        p.obf[(long long)z * p.oBatch + (long long)grow * p.ldo + gcol] = f2b(v);
                    } else if constexpr (EPI == EPI_Y) {
                        v = b2f(p.res[(long long)z * p.resBatch + (long long)grow * p.ldres + gcol]) + v;
                        p.obf[(long long)z * p.oBatch + (long long)grow * p.ldo + gcol] = f2b(v);
                    } else if constexpr (EPI == EPI_OUT0) {
                        v += p.bias[gcol];
                        int bb = grow >> 8, px = grow & 255;
                        p.of32[((long long)bb * 1024 + gcol) * 256 + px] = v;
                    } else if constexpr (EPI == EPI_OUTA) {
                        int bb = grow >> 8, px = grow & 255;
                        long long o = ((long long)bb * 1024 + gcol) * 256 + px;
                        p.of32[o] = p.of32[o] + v;
                    } else if constexpr (EPI == EPI_TMP) {
                        p.of32[(long long)z * p.oBatch + (long long)grow * 256 + gcol] = v;
                    }
                }
            }
        }
    }
}

// ---------------- small kernels ----------------

// combine 4 split-K fp32 partials + bias -> bf16 fbuf; float4-vectorized
__global__ void k_combine(const float* __restrict__ t, const float* __restrict__ fbias_s,
                          ushort_t* __restrict__ f) {
    int idx = blockIdx.x * 256 + threadIdx.x;  // over 16384*256/4
    const long long N = 16384ll * 256 / 4;
    const float4* t4 = (const float4*)t;
    float4 a = t4[idx], b = t4[idx + N], c = t4[idx + 2 * N], d = t4[idx + 3 * N];
    int cb = (idx * 4) & 255;
    ushort4v o;
    o.x = f2b(a.x + b.x + c.x + d.x + fbias_s[cb]);
    o.y = f2b(a.y + b.y + c.y + d.y + fbias_s[cb + 1]);
    o.z = f2b(a.z + b.z + c.z + d.z + fbias_s[cb + 2]);
    o.w = f2b(a.w + b.w + c.w + d.w + fbias_s[cb + 3]);
    *(ushort4v*)&f[idx * 4] = o;
}

// x_sum = x_cur * (1 + bilinear_up2x_align_corners(x_lat)); bf16 [B*256][1024]
__global__ void k_upsum(const float* __restrict__ xc, const float* __restrict__ xl,
                        ushort_t* __restrict__ xs) {
    __shared__ float lat[64 * 64];
    __shared__ ushort_t tile[64 * 258];
    int b = blockIdx.x, c0 = blockIdx.y * 64;
    int t = threadIdx.x;
    for (int i = t; i < 4096; i += 256)
        lat[i] = xl[((long long)(b * 1024 + c0 + (i >> 6))) * 64 + (i & 63)];
    __syncthreads();
    int y = t >> 4, x = t & 15;
    float fy = y * (7.f / 15.f); int y0 = (int)fy; float wy = fy - y0; int y1 = y0 + 1 > 7 ? 7 : y0 + 1;
    float fx = x * (7.f / 15.f); int x0 = (int)fx; float wx = fx - x0; int x1 = x0 + 1 > 7 ? 7 : x0 + 1;
    for (int cc = 0; cc < 64; ++cc) {
        float cur = xc[((long long)(b * 1024 + c0 + cc)) * 256 + t];
        const float* L = &lat[cc * 64];
        float tv = L[y0 * 8 + x0] * (1.f - wx) + L[y0 * 8 + x1] * wx;
        float bv = L[y1 * 8 + x0] * (1.f - wx) + L[y1 * 8 + x1] * wx;
        float up = tv + (bv - tv) * wy;
        tile[cc * 258 + t] = f2b(cur * (1.f + up));
    }
    __syncthreads();
    for (int i = t; i < 16384; i += 256) {
        int px = i >> 6, cc = i & 63;
        xs[((long long)(b * 256 + px)) * 1024 + c0 + cc] = tile[cc * 258 + px];
    }
}

__global__ void k_pool(const ushort_t* __restrict__ f, float* __restrict__ avg, float* __restrict__ mx) {
    int b = blockIdx.x, c = threadIdx.x;
    float s = 0.f, m = -3.4e38f;
    const ushort_t* base = f + (long long)b * 65536 + c;
    for (int px = 0; px < 256; ++px) { float v = b2f(base[px * 256]); s += v; m = fmaxf(m, v); }
    avg[b * 256 + c] = s * (1.f / 256.f);
    mx[b * 256 + c] = m;
}

__global__ void k_cw(const float* __restrict__ avg, const float* __restrict__ mx,
                     const float* __restrict__ aw, const float* __restrict__ mw,
                     float* __restrict__ cw) {
    __shared__ float sa[256], sm[256];
    int b = blockIdx.x, t = threadIdx.x; // 128 threads
    sa[t] = avg[b * 256 + t]; sa[t + 128] = avg[b * 256 + t + 128];
    sm[t] = mx[b * 256 + t];  sm[t + 128] = mx[b * 256 + t + 128];
    __syncthreads();
    float s1 = 0.f, s2 = 0.f;
    const float* a = aw + t * 256; const float* w = mw + t * 256;
    for (int c = 0; c < 256; ++c) { s1 += sa[c] * a[c]; s2 += sm[c] * w[c]; }
    s1 = fmaxf(s1, 0.f); s2 = fmaxf(s2, 0.f);
    cw[b * 128 + t] = sigm(s1 + s2);
}

__global__ void k_pscale(const ushort_t* __restrict__ q, const float* __restrict__ dsum,
                         ushort_t* __restrict__ P, ushort_t* __restrict__ Pt) {
    int idx = blockIdx.x * 256 + threadIdx.x; // 2,097,152
    int m = idx & 127; int pix = idx >> 7;
    int b = pix >> 8, j = pix & 255;
    float d = rsqrtf(dsum[pix]);
    ushort_t v = f2b(d * b2f(q[idx]));
    P[idx] = v;
    Pt[((long long)b << 15) + (m << 8) + j] = v;
}

// ft[b][c][j] = f[b][j][c], LDS-tiled 64x64 transpose (coalesced both sides)
__global__ void k_ft(const ushort_t* __restrict__ f, ushort_t* __restrict__ ft) {
    __shared__ ushort_t t[64][65];
    int b = blockIdx.z, j0 = blockIdx.x * 64, c0 = blockIdx.y * 64;
    int c = threadIdx.x & 63, r = threadIdx.x >> 6;  // 4 rows per pass
#pragma unroll
    for (int k = 0; k < 64; k += 4)
        t[r + k][c] = f[((long long)(b * 256 + j0 + r + k)) * 256 + c0 + c];
    __syncthreads();
#pragma unroll
    for (int k = 0; k < 64; k += 4)
        ft[((long long)(b * 256 + c0 + r + k)) * 256 + j0 + c] = t[c][r + k];
}

// pack stage-s big-GEMM weight: [o<256][tap<10 * 1024]; taps 0..8 = rate(3x3), 9 = conv1x1
__global__ void k_wbig(const float* __restrict__ rate, const float* __restrict__ convw,
                       ushort_t* __restrict__ dst) {
    int gk = blockIdx.x * 256 + threadIdx.x; // 10240
    int o = blockIdx.y;
    int tap = gk >> 10, ci = gk & 1023;
    float v = (tap < 9) ? rate[(long long)o * 9216 + ci * 9 + tap] : convw[(long long)o * 1024 + ci];
    dst[(long long)o * 10240 + gk] = f2b(v);
}

__global__ void k_w3s(const float* __restrict__ w3, ushort_t* __restrict__ dst, int s) {
    int o = blockIdx.x, c = threadIdx.x;
    dst[o * 256 + c] = f2b(w3[o * 768 + s * 256 + c]);
}

__global__ void k_cast(const float* __restrict__ s, ushort_t* __restrict__ d) {
    int i = blockIdx.x * 256 + threadIdx.x; d[i] = f2b(s[i]);
}
__global__ void k_castT256(const float* __restrict__ s, ushort_t* __restrict__ d) {
    int c1 = threadIdx.x, c2 = blockIdx.x;
    d[c2 * 256 + c1] = f2b(s[c1 * 256 + c2]);
}
__global__ void k_bias2(const float* a0, const float* a1, const float* a2,
                        const float* cb, float* dst) {
    int t = threadIdx.x; int s = blockIdx.x;
    const float* a = s == 0 ? a0 : (s == 1 ? a1 : a2);
    dst[s * 256 + t] = a[t] + cb[t];
}
__global__ void k_sentinel(float* o, int n, float v) {
    int i = blockIdx.x * 256 + threadIdx.x; if (i < n) o[i] = v;
}

// ---------------- launch ----------------
extern "C" void kernel_launch(void* const* d_in, const int* in_sizes, int n_in,
                              void* d_out, int out_size, void* d_ws, size_t ws_size,
                              hipStream_t stream) {
    const float* x_cur  = (const float*)d_in[0];
    const float* x_lat  = (const float*)d_in[1];
    const float* conv_w = (const float*)d_in[2];
    const float* conv_b = (const float*)d_in[3];
    const float* conv1_w = (const float*)d_in[4];
    const float* conv1_b = (const float*)d_in[5];
    const float* conv3_w = (const float*)d_in[6];
    const float* conv3_b = (const float*)d_in[7];
    const float* rate_w[3] = {(const float*)d_in[8], (const float*)d_in[10], (const float*)d_in[12]};
    const float* rate_b[3] = {(const float*)d_in[9], (const float*)d_in[11], (const float*)d_in[13]};
    const float* ck_w  = (const float*)d_in[14];
    const float* ck_b  = (const float*)d_in[15];
    const float* avg_w = (const float*)d_in[16];
    const float* max_w = (const float*)d_in[17];
    const float* gcn_w = (const float*)d_in[18];
    float* out = (float*)d_out;

    char* w = (char*)d_ws;
    auto take = [&](size_t bytes) { void* p = (void*)w; w += (bytes + 255) & ~(size_t)255; return p; };
    // ---- shared allocations (all tiers) ----
    ushort_t* xsum = (ushort_t*)take(16384ll * 1024 * 2);   // 33.55MB
    ushort_t* feat = (ushort_t*)take(16384ll * 1024 * 2);   // 33.55MB
    ushort_t* fbuf = (ushort_t*)take(16384ll * 256 * 2);    // 8.39MB
    ushort_t* ftb  = (ushort_t*)take(64ll * 256 * 256 * 2); // 8.39MB (tier C: also ybuf)
    ushort_t* ybuf = ftb;
    ushort_t* qbuf = (ushort_t*)take(16384ll * 128 * 2);    // 4.19MB
    ushort_t* qc   = (ushort_t*)take(16384ll * 128 * 2);    // 4.19MB \ lx aliases
    ushort_t* Pt   = (ushort_t*)take(64ll * 128 * 256 * 2); // 4.19MB /  [qc|Pt]
    ushort_t* lx   = qc;
    ushort_t* Pb   = (ushort_t*)take(16384ll * 128 * 2);    // 4.19MB
    ushort_t* St   = (ushort_t*)take(64ll * 256 * 128 * 2); // 4.19MB
    ushort_t* wbig = (ushort_t*)take(256ll * 10240 * 2);    // 5.24MB
    ushort_t* w1b  = (ushort_t*)take(1024ll * 256 * 2);
    ushort_t* w3b  = (ushort_t*)take(1024ll * 768 * 2);
    ushort_t* ckb  = (ushort_t*)take(128ll * 256 * 2);
    ushort_t* gcnT = (ushort_t*)take(256ll * 256 * 2);
    ushort_t* zpage = (ushort_t*)take(256);
    float*    fbias = (float*)take(3 * 256 * 4);
    float*    avg   = (float*)take(64 * 256 * 4);
    float*    mxp   = (float*)take(64 * 256 * 4);
    float*    cwb   = (float*)take(64 * 128 * 4);
    float*    dsum  = (float*)take(64 * 256 * 4);
    size_t needC = (size_t)(w - (char*)d_ws);
    // ---- tier B extra: cat buffer, single final GEMM ----
    ushort_t* catb = (ushort_t*)take(16384ll * 768 * 2);    // 25.17MB
    size_t needB = (size_t)(w - (char*)d_ws);
    // ---- tier A extra: split-K fp32 partials ----
    float* ftmp = (float*)take(4ll * 16384 * 256 * 4);      // 67.11MB
    size_t needA = (size_t)(w - (char*)d_ws);

    int tier;
    if (needA <= ws_size) tier = 0;        // A: split-K BIG (gload_lds) + catb
    else if (needB <= ws_size) tier = 1;   // B: direct BIG + catb
    else if (needC <= ws_size) tier = 2;   // C: round-3 structure
    else {
        float v = 1.0e6f + (float)(ws_size >> 20);
        k_sentinel<<<(out_size + 255) / 256, 256, 0, stream>>>(out, out_size, v);
        return;
    }

    hipMemsetAsync(zpage, 0, 256, stream);
    k_upsum<<<dim3(64, 16), 256, 0, stream>>>(x_cur, x_lat, xsum);
    k_cast<<<1024, 256, 0, stream>>>(conv1_w, w1b);
    k_cast<<<128, 256, 0, stream>>>(ck_w, ckb);
    k_castT256<<<256, 256, 0, stream>>>(gcn_w, gcnT);
    k_bias2<<<3, 256, 0, stream>>>(rate_b[0], rate_b[1], rate_b[2], conv_b, fbias);
    if (tier != 2) k_cast<<<3072, 256, 0, stream>>>(conv3_w, w3b);

    for (int s = 0; s < 3; ++s) {
        k_wbig<<<dim3(40, 256), 256, 0, stream>>>(rate_w[s], conv_w, wbig);
        if (tier == 2) k_w3s<<<1024, 256, 0, stream>>>(conv3_w, w3b, s);

        // BIG: f_s = conv3x3(dil=2^s) + rate_b + conv1x1 + conv_b -> fbuf (bf16)
        if (tier == 0) {
            GemmP p{};
            p.A = (s == 0) ? xsum : feat;
            p.B = wbig; p.ldb = 10240;
            p.Ksub = 2560; p.kSplit = 2560; p.dil = 1 << s;
            p.of32 = ftmp; p.oBatch = 16384ll * 256;
            p.zpage = zpage;
            gemm_big<<<dim3(128, 2, 4), 256, 0, stream>>>(p);
            k_combine<<<4096, 256, 0, stream>>>(ftmp, fbias + s * 256, fbuf);
        } else {
            GemmP p{};
            p.A = (s == 0) ? xsum : feat;
            p.B = wbig; p.ldb = 10240;
            p.Ksub = 10240; p.dil = 1 << s;
            p.bias = fbias + s * 256;
            p.obf = fbuf; p.ldo = 256;
            gemm_k<64, 128, 1, EPI_BIAS><<<dim3(256, 2, 1), 256, 0, stream>>>(p);
        }
        k_pool<<<64, 256, 0, stream>>>(fbuf, avg, mxp);
        k_cw<<<64, 128, 0, stream>>>(avg, mxp, avg_w, max_w, cwb);
        { // q = relu(f @ ck_w^T + ck_b); fused qc = q * cw
            GemmP p{};
            p.A = fbuf; p.lda = 256; p.B = ckb; p.ldb = 256;
            p.Ksub = 256;
            p.bias = ck_b; p.obf = qbuf; p.obf2 = qc; p.cw = cwb; p.ldo = 128;
            gemm_k<128, 128, 0, EPI_RELU><<<dim3(128, 1, 1), 256, 0, stream>>>(p);
        }
        hipMemsetAsync(dsum, 0, 64 * 256 * 4, stream);
        { // dsum[b][i] = sum_j sigmoid( (q*cw)[i,:] . q[j,:] )
            GemmP p{};
            p.A = qc;   p.aBatch = 32768; p.lda = 128;
            p.B = qbuf; p.bBatch = 32768; p.ldb = 128;
            p.Ksub = 128; p.dsum = dsum;
            gemm_k<128, 128, 0, EPI_SIG><<<dim3(2, 2, 64), 256, 0, stream>>>(p);
        }
        k_pscale<<<8192, 256, 0, stream>>>(qbuf, dsum, Pb, Pt);
        k_ft<<<dim3(4, 4, 64), 256, 0, stream>>>(fbuf, ftb);
        { // St[b][c][m] = cw[m] * (P^T X)[m][c]
            GemmP p{};
            p.A = Pt;  p.aBatch = 32768; p.lda = 256;
            p.B = ftb; p.bBatch = 65536; p.ldb = 256;
            p.Ksub = 256; p.cw = cwb;
            p.obf = St; p.oBatch = 32768;
            gemm_k<128, 128, 0, EPI_PTX><<<dim3(1, 2, 64), 256, 0, stream>>>(p);
        }
        { // LX = X - P @ St^T
            GemmP p{};
            p.A = Pb; p.aBatch = 32768; p.lda = 128;
            p.B = St; p.bBatch = 32768; p.ldb = 128;
            p.Ksub = 128;
            p.res = fbuf; p.resBatch = 65536; p.ldres = 256;
            p.obf = lx; p.oBatch = 65536; p.ldo = 256;
            gemm_k<128, 128, 0, EPI_LX><<<dim3(2, 2, 64), 256, 0, stream>>>(p);
        }
        { // Y = X + LX @ gcn_w
            GemmP p{};
            p.A = lx;   p.aBatch = 65536; p.lda = 256;
            p.B = gcnT; p.bBatch = 0;     p.ldb = 256;
            p.Ksub = 256;
            p.res = fbuf; p.resBatch = 65536; p.ldres = 256;
            if (tier != 2) {  // -> catb slice [16384][768]
                p.obf = catb + s * 256; p.oBatch = 256ll * 768; p.ldo = 768;
            } else {          // -> ybuf [16384][256]
                p.obf = ybuf; p.oBatch = 65536; p.ldo = 256;
            }
            gemm_k<128, 128, 0, EPI_Y><<<dim3(2, 2, 64), 256, 0, stream>>>(p);
        }
        if (tier == 2) { // out (+)= ybuf @ w3_slice^T (+ conv3_b at s==0), fp32 NCHW
            GemmP p{};
            p.A = ybuf; p.lda = 256; p.B = w3b; p.ldb = 256;
            p.Ksub = 256; p.bias = conv3_b; p.of32 = out;
            if (s == 0)
                gemm_k<128, 128, 0, EPI_OUT0><<<dim3(128, 8, 1), 256, 0, stream>>>(p);
            else
                gemm_k<128, 128, 0, EPI_OUTA><<<dim3(128, 8, 1), 256, 0, stream>>>(p);
        }
        if (s < 2) { // feature = conv1(f) + conv1_b + x_sum -> feat [16384][1024]
            GemmP p{};
            p.A = fbuf; p.lda = 256; p.B = w1b; p.ldb = 256;
            p.Ksub = 256; p.bias = conv1_b;
            p.res = xsum; p.ldres = 1024;
            p.obf = feat; p.ldo = 1024;
            gemm_k<128, 128, 0, EPI_FEAT><<<dim3(128, 8, 1), 256, 0, stream>>>(p);
        }
    }
    if (tier != 2) { // out = catb @ conv3_w^T + conv3_b, single K=768 GEMM, fp32 NCHW
        GemmP p{};
        p.A = catb; p.lda = 768; p.B = w3b; p.ldb = 768;
        p.Ksub = 768; p.bias = conv3_b; p.of32 = out;
        gemm_k<128, 128, 0, EPI_OUT0><<<dim3(128, 8, 1), 256, 0, stream>>>(p);
    }
}

// Round 6
// 825.906 us; speedup vs baseline: 1.4677x; 1.0779x over previous
//
#include <hip/hip_runtime.h>

typedef unsigned short ushort_t;
typedef unsigned int uint32;
typedef __attribute__((ext_vector_type(8))) unsigned short ushort8;
typedef __attribute__((ext_vector_type(8))) __bf16 bf16x8;
typedef __attribute__((ext_vector_type(4))) float f32x4;

__device__ __forceinline__ ushort_t f2b(float f) {
    union { float f; uint32 u; } v; v.f = f;
    uint32 r = v.u + 0x7fffu + ((v.u >> 16) & 1u);
    return (ushort_t)(r >> 16);
}
__device__ __forceinline__ float b2f(ushort_t b) {
    union { uint32 u; float f; } v; v.u = ((uint32)b) << 16;
    return v.f;
}
__device__ __forceinline__ float sigm(float x) { return 1.f / (1.f + __expf(-x)); }

__device__ __forceinline__ void gload_lds16(const void* g, void* l) {
    __builtin_amdgcn_global_load_lds(
        (__attribute__((address_space(1))) void*)g,
        (__attribute__((address_space(3))) void*)l, 16, 0, 0);
}

// epilogues
constexpr int EPI_RELU = 1;  // bf16 relu(acc+bias) -> obf; obf2 = relu*cw (fused qc)
constexpr int EPI_FEAT = 2;  // bf16 acc+bias+res -> obf
constexpr int EPI_SIG  = 3;  // rowsum sigmoid(acc) -> dsum4[(by*2+wc)][z*256+row], no atomics
constexpr int EPI_ST   = 4;  // bf16 cw[z*128+row]*acc -> obf[z*oB + row*ldo + col] (coalesced)
constexpr int EPI_NEG  = 5;  // bf16 -acc -> obf[z*oB + row*ldo + col]
constexpr int EPI_Y    = 6;  // bf16 res + acc -> obf (catb slice)
constexpr int EPI_OUTT = 7;  // fp32 acc+bias[row]; row=outchan, col=pixel -> NCHW coalesced

struct GemmP {
    const ushort_t* A; const ushort_t* B;
    const ushort_t* A2; const ushort_t* B2;     // AMODE==2 second source (K >= 256)
    long long aBatch, bBatch, a2Batch, b2Batch;
    int lda, ldb, lda2, ldb2;
    int Ksub, kSplit, dil;
    const float* bias;
    const ushort_t* res; long long resBatch; int ldres;
    ushort_t* obf; long long oBatch; int ldo;
    ushort_t* obf2;
    float* of32;
    const float* cw;
    float* dsum;
    const ushort_t* zpage;
};

// ---------------------------------------------------------------------------
// BIG implicit-GEMM (9 dilated conv taps + conv1x1 identity tap), m97-style
// global_load_lds staging, split-K=4, 128x128 tile, BK=64.
// LDS image S[r][g] = G[r][g ^ (r&7)] via pre-swizzled per-lane global source
// (lane l fetches granule (l&7)^(l>>3)); read side applies the same XOR.
// OOB taps -> zeroed 16B page. Partials stored bf16 (sigma~0.7 -> err ~3e-3).
// ---------------------------------------------------------------------------
__global__ __launch_bounds__(256) void gemm_big(GemmP p) {
    __shared__ __align__(16) ushort_t aT[128 * 64];
    __shared__ __align__(16) ushort_t bT[128 * 64];
    const int tid = threadIdx.x;
    const int z = blockIdx.z;
    const int m0 = blockIdx.x * 128, n0 = blockIdx.y * 128;
    const int lane = tid & 63, wid = tid >> 6;
    const int l15 = lane & 15, l16 = lane >> 4;
    const int wr = wid >> 1, wc = wid & 1;
    const int lrow = lane >> 3;
    const int sgran = (lane & 7) ^ lrow;

    int ayy[4], axx[4];
    const ushort_t* aBase[4];
    const ushort_t* bBase[4];
#pragma unroll
    for (int i = 0; i < 4; ++i) {
        int row = wid * 32 + i * 8 + lrow;
        int m = m0 + row;
        int bb = m >> 8;
        ayy[i] = (m >> 4) & 15; axx[i] = m & 15;
        aBase[i] = p.A + (long long)bb * 262144 + sgran * 8;
        bBase[i] = p.B + (long long)(n0 + row) * p.ldb + sgran * 8;
    }

    f32x4 acc[4][4];
#pragma unroll
    for (int i = 0; i < 4; ++i)
#pragma unroll
        for (int j = 0; j < 4; ++j) acc[i][j] = (f32x4){0.f, 0.f, 0.f, 0.f};

    const int gk0 = z * p.kSplit;
    const int iters = p.Ksub >> 6;
    for (int it = 0; it < iters; ++it) {
        const int gk = gk0 + it * 64;
        const int tap = gk >> 10, kin = gk & 1023;
        int dy = 0, dx = 0;
        if (tap < 9) { int ky = tap / 3; dy = (ky - 1) * p.dil; dx = (tap - ky * 3 - 1) * p.dil; }
#pragma unroll
        for (int i = 0; i < 4; ++i) {
            int iy = ayy[i] + dy, ix = axx[i] + dx;
            bool ok = ((unsigned)iy < 16u) && ((unsigned)ix < 16u);
            const ushort_t* ga = ok ? (aBase[i] + (((iy << 4) + ix) << 10) + kin) : p.zpage;
            gload_lds16(ga, &aT[(wid * 32 + i * 8) * 64]);
        }
#pragma unroll
        for (int i = 0; i < 4; ++i)
            gload_lds16(bBase[i] + gk, &bT[(wid * 32 + i * 8) * 64]);
        asm volatile("s_waitcnt vmcnt(0)" ::: "memory");
        __syncthreads();
#pragma unroll
        for (int ks = 0; ks < 2; ++ks) {
            bf16x8 af[4], bfr[4];
#pragma unroll
            for (int mi = 0; mi < 4; ++mi) {
                int rr = wr * 64 + mi * 16 + l15;
                int cc = (ks * 32 + l16 * 8) ^ ((rr & 7) << 3);
                af[mi] = __builtin_bit_cast(bf16x8, *(const ushort8*)&aT[rr * 64 + cc]);
            }
#pragma unroll
            for (int ni = 0; ni < 4; ++ni) {
                int rr = wc * 64 + ni * 16 + l15;
                int cc = (ks * 32 + l16 * 8) ^ ((rr & 7) << 3);
                bfr[ni] = __builtin_bit_cast(bf16x8, *(const ushort8*)&bT[rr * 64 + cc]);
            }
#pragma unroll
            for (int mi = 0; mi < 4; ++mi)
#pragma unroll
                for (int ni = 0; ni < 4; ++ni)
                    acc[mi][ni] = __builtin_amdgcn_mfma_f32_16x16x32_bf16(af[mi], bfr[ni], acc[mi][ni], 0, 0, 0);
        }
        __syncthreads();
    }
    // epilogue: bf16 split-K partial, coalesced
#pragma unroll
    for (int mi = 0; mi < 4; ++mi)
#pragma unroll
        for (int ni = 0; ni < 4; ++ni) {
            int gcol = n0 + wc * 64 + ni * 16 + l15;
            int growb = m0 + wr * 64 + mi * 16 + l16 * 4;
#pragma unroll
            for (int r = 0; r < 4; ++r)
                p.obf[(long long)z * p.oBatch + (long long)(growb + r) * 256 + gcol] =
                    f2b(acc[mi][ni][r]);
        }
}

// Generic 4-wave MFMA GEMM: C = A.B^T, bf16 in, fp32 acc. AMODE==0: single
// source; AMODE==2: dual source (gk<256 from A/B, gk>=256 from A2/B2 — used
// for Y = X + X@G - P@H as one K=384 pass; H pre-negated).
template<int BM, int BN, int AMODE, int EPI>
__global__ __launch_bounds__(256) void gemm_k(GemmP p) {
    __shared__ __align__(16) ushort_t aT[BM * 64];
    __shared__ __align__(16) ushort_t bT[BN * 64];
    constexpr int APASS = BM / 32, BPASS = BN / 32;
    constexpr int MFRAG = BM / 32, NFRAG = BN / 32;
    const int tid = threadIdx.x;
    const int z = blockIdx.z;
    const int m0 = blockIdx.x * BM, n0 = blockIdx.y * BN;
    const int lane = tid & 63, wid = tid >> 6;
    const int l15 = lane & 15, l16 = lane >> 4;
    const int wr = wid >> 1, wc = wid & 1;
    const int srow = tid >> 3, scol = (tid & 7) * 8;
    const int swcol = scol ^ ((srow & 7) << 3);

    const ushort_t* aptr[APASS];
    const ushort_t* bptr[BPASS];
    const ushort_t* aptr2[APASS];
    const ushort_t* bptr2[BPASS];
#pragma unroll
    for (int pi = 0; pi < APASS; ++pi)
        aptr[pi] = p.A + (long long)z * p.aBatch +
                   (long long)(m0 + pi * 32 + srow) * p.lda + scol;
#pragma unroll
    for (int pi = 0; pi < BPASS; ++pi)
        bptr[pi] = p.B + (long long)z * p.bBatch +
                   (long long)(n0 + pi * 32 + srow) * p.ldb + scol;
    if constexpr (AMODE == 2) {
#pragma unroll
        for (int pi = 0; pi < APASS; ++pi)
            aptr2[pi] = p.A2 + (long long)z * p.a2Batch +
                        (long long)(m0 + pi * 32 + srow) * p.lda2 + scol;
#pragma unroll
        for (int pi = 0; pi < BPASS; ++pi)
            bptr2[pi] = p.B2 + (long long)z * p.b2Batch +
                        (long long)(n0 + pi * 32 + srow) * p.ldb2 + scol;
    }

    f32x4 acc[MFRAG][NFRAG];
#pragma unroll
    for (int i = 0; i < MFRAG; ++i)
#pragma unroll
        for (int j = 0; j < NFRAG; ++j) acc[i][j] = (f32x4){0.f, 0.f, 0.f, 0.f};

    ushort8 ar[APASS], br[BPASS];
    auto ldg = [&](int gk) {
        if (AMODE == 2 && gk >= 256) {
            int g2 = gk - 256;
#pragma unroll
            for (int pi = 0; pi < APASS; ++pi) ar[pi] = *(const ushort8*)(aptr2[pi] + g2);
#pragma unroll
            for (int pi = 0; pi < BPASS; ++pi) br[pi] = *(const ushort8*)(bptr2[pi] + g2);
        } else {
#pragma unroll
            for (int pi = 0; pi < APASS; ++pi) ar[pi] = *(const ushort8*)(aptr[pi] + gk);
#pragma unroll
            for (int pi = 0; pi < BPASS; ++pi) br[pi] = *(const ushort8*)(bptr[pi] + gk);
        }
    };

    const int gk0 = z * p.kSplit;
    ldg(gk0);
    const int iters = p.Ksub >> 6;
    for (int it = 0; it < iters; ++it) {
#pragma unroll
        for (int pi = 0; pi < APASS; ++pi)
            *(ushort8*)&aT[(pi * 32 + srow) * 64 + swcol] = ar[pi];
#pragma unroll
        for (int pi = 0; pi < BPASS; ++pi)
            *(ushort8*)&bT[(pi * 32 + srow) * 64 + swcol] = br[pi];
        __syncthreads();
        if (it + 1 < iters) ldg(gk0 + (it + 1) * 64);
#pragma unroll
        for (int ks = 0; ks < 2; ++ks) {
            bf16x8 af[MFRAG], bfr[NFRAG];
#pragma unroll
            for (int mi = 0; mi < MFRAG; ++mi) {
                int rr = wr * (BM / 2) + mi * 16 + l15;
                int cc = (ks * 32 + l16 * 8) ^ ((rr & 7) << 3);
                af[mi] = __builtin_bit_cast(bf16x8, *(const ushort8*)&aT[rr * 64 + cc]);
            }
#pragma unroll
            for (int ni = 0; ni < NFRAG; ++ni) {
                int rr = wc * (BN / 2) + ni * 16 + l15;
                int cc = (ks * 32 + l16 * 8) ^ ((rr & 7) << 3);
                bfr[ni] = __builtin_bit_cast(bf16x8, *(const ushort8*)&bT[rr * 64 + cc]);
            }
#pragma unroll
            for (int mi = 0; mi < MFRAG; ++mi)
#pragma unroll
                for (int ni = 0; ni < NFRAG; ++ni)
                    acc[mi][ni] = __builtin_amdgcn_mfma_f32_16x16x32_bf16(af[mi], bfr[ni], acc[mi][ni], 0, 0, 0);
        }
        __syncthreads();
    }

    // ---------------- epilogue ----------------
#pragma unroll
    for (int mi = 0; mi < MFRAG; ++mi) {
        if constexpr (EPI == EPI_SIG) {
#pragma unroll
            for (int r = 0; r < 4; ++r) {
                float sv = 0.f;
#pragma unroll
                for (int ni = 0; ni < NFRAG; ++ni) sv += sigm(acc[mi][ni][r]);
                sv += __shfl_xor(sv, 1); sv += __shfl_xor(sv, 2);
                sv += __shfl_xor(sv, 4); sv += __shfl_xor(sv, 8);
                if (l15 == 0) {
                    int grow = m0 + wr * (BM / 2) + mi * 16 + l16 * 4 + r;
                    int q4 = blockIdx.y * 2 + wc;  // disjoint slot -> deterministic
                    p.dsum[q4 * 16384 + z * 256 + grow] = sv;
                }
            }
        } else {
#pragma unroll
            for (int ni = 0; ni < NFRAG; ++ni) {
                int gcol = n0 + wc * (BN / 2) + ni * 16 + l15;
                int growb = m0 + wr * (BM / 2) + mi * 16 + l16 * 4;
#pragma unroll
                for (int r = 0; r < 4; ++r) {
                    int grow = growb + r;
                    float v = acc[mi][ni][r];
                    if constexpr (EPI == EPI_RELU) {
                        v += p.bias[gcol]; v = fmaxf(v, 0.f);
                        p.obf[(long long)grow * p.ldo + gcol] = f2b(v);
                        p.obf2[(long long)grow * p.ldo + gcol] =
                            f2b(v * p.cw[((grow >> 8) << 7) + gcol]);
                    } else if constexpr (EPI == EPI_FEAT) {
                        v += p.bias[gcol] + b2f(p.res[(long long)grow * p.ldres + gcol]);
                        p.obf[(long long)grow * p.ldo + gcol] = f2b(v);
                    } else if constexpr (EPI == EPI_ST) {
                        v *= p.cw[z * 128 + grow];
                        p.obf[(long long)z * p.oBatch + (long long)grow * p.ldo + gcol] = f2b(v);
                    } else if constexpr (EPI == EPI_NEG) {
                        p.obf[(long long)z * p.oBatch + (long long)grow * p.ldo + gcol] = f2b(-v);
                    } else if constexpr (EPI == EPI_Y) {
                        v = b2f(p.res[(long long)z * p.resBatch + (long long)grow * p.ldres + gcol]) + v;
                        p.obf[(long long)z * p.oBatch + (long long)grow * p.ldo + gcol] = f2b(v);
                    } else if constexpr (EPI == EPI_OUTT) {
                        v += p.bias[grow];               // row = out-channel
                        int bb = gcol >> 8, px = gcol & 255;
                        p.of32[((long long)bb * 1024 + grow) * 256 + px] = v;  // coalesced over px
                    }
                }
            }
        }
    }
}

// ---------------- small kernels ----------------

// combine 4 bf16 split-K partials + bias -> bf16 fbuf
__global__ void k_combine(const ushort_t* __restrict__ t, const float* __restrict__ fbias_s,
                          ushort_t* __restrict__ f) {
    int idx = blockIdx.x * 256 + threadIdx.x;  // x8 elements
    const long long N = 16384ll * 256;
    ushort8 a = *(const ushort8*)(t + (long long)idx * 8);
    ushort8 b = *(const ushort8*)(t + N + (long long)idx * 8);
    ushort8 c = *(const ushort8*)(t + 2 * N + (long long)idx * 8);
    ushort8 d = *(const ushort8*)(t + 3 * N + (long long)idx * 8);
    int cb = (idx * 8) & 255;
    ushort8 o;
#pragma unroll
    for (int k = 0; k < 8; ++k)
        o[k] = f2b(b2f(a[k]) + b2f(b[k]) + b2f(c[k]) + b2f(d[k]) + fbias_s[cb + k]);
    *(ushort8*)&f[(long long)idx * 8] = o;
}

// x_sum = x_cur * (1 + bilinear_up2x_align_corners(x_lat)); bf16 [B*256][1024]
__global__ void k_upsum(const float* __restrict__ xc, const float* __restrict__ xl,
                        ushort_t* __restrict__ xs) {
    __shared__ float lat[64 * 64];
    __shared__ ushort_t tile[64 * 258];
    int b = blockIdx.x, c0 = blockIdx.y * 64;
    int t = threadIdx.x;
    for (int i = t; i < 4096; i += 256)
        lat[i] = xl[((long long)(b * 1024 + c0 + (i >> 6))) * 64 + (i & 63)];
    __syncthreads();
    int y = t >> 4, x = t & 15;
    float fy = y * (7.f / 15.f); int y0 = (int)fy; float wy = fy - y0; int y1 = y0 + 1 > 7 ? 7 : y0 + 1;
    float fx = x * (7.f / 15.f); int x0 = (int)fx; float wx = fx - x0; int x1 = x0 + 1 > 7 ? 7 : x0 + 1;
    for (int cc = 0; cc < 64; ++cc) {
        float cur = xc[((long long)(b * 1024 + c0 + cc)) * 256 + t];
        const float* L = &lat[cc * 64];
        float tv = L[y0 * 8 + x0] * (1.f - wx) + L[y0 * 8 + x1] * wx;
        float bv = L[y1 * 8 + x0] * (1.f - wx) + L[y1 * 8 + x1] * wx;
        float up = tv + (bv - tv) * wy;
        tile[cc * 258 + t] = f2b(cur * (1.f + up));
    }
    __syncthreads();
    for (int i = t; i < 16384; i += 256) {
        int px = i >> 6, cc = i & 63;
        xs[((long long)(b * 256 + px)) * 1024 + c0 + cc] = tile[cc * 258 + px];
    }
}

// fused avg/max pool + channel-weight MLP: cw[b][m] = sigm(relu(avg@awT)+relu(mx@mwT))
__global__ void k_poolcw(const ushort_t* __restrict__ f,
                         const float* __restrict__ aw, const float* __restrict__ mw,
                         float* __restrict__ cw) {
    __shared__ float sa[256], sm[256];
    int b = blockIdx.x, t = threadIdx.x;
    float s = 0.f, m = -3.4e38f;
    const ushort_t* base = f + (long long)b * 65536 + t;
    for (int px = 0; px < 256; ++px) { float v = b2f(base[px * 256]); s += v; m = fmaxf(m, v); }
    sa[t] = s * (1.f / 256.f);
    sm[t] = m;
    __syncthreads();
    if (t < 128) {
        float s1 = 0.f, s2 = 0.f;
        const float* a = aw + t * 256; const float* w = mw + t * 256;
        for (int c = 0; c < 256; ++c) { s1 += sa[c] * a[c]; s2 += sm[c] * w[c]; }
        s1 = fmaxf(s1, 0.f); s2 = fmaxf(s2, 0.f);
        cw[b * 128 + t] = sigm(s1 + s2);
    }
}

// P scale + LDS-tiled transposed Pt (both writes coalesced)
__global__ void k_pscale(const ushort_t* __restrict__ q, const float* __restrict__ dsum4,
                         ushort_t* __restrict__ P, ushort_t* __restrict__ Pt) {
    __shared__ ushort_t t[128][130];
    __shared__ float dd[128];
    int jh = blockIdx.x, b = blockIdx.y;
    int j0 = jh * 128;
    int tid = threadIdx.x;
    if (tid < 128) {
        int pix = b * 256 + j0 + tid;
        float s = dsum4[pix] + dsum4[16384 + pix] + dsum4[32768 + pix] + dsum4[49152 + pix];
        dd[tid] = rsqrtf(s);
    }
    __syncthreads();
    int jr = tid >> 7, m = tid & 127;
    for (int i = 0; i < 64; ++i) {
        int j = i * 2 + jr;
        long long qi = ((long long)(b * 256 + j0 + j)) * 128 + m;
        ushort_t v = f2b(dd[j] * b2f(q[qi]));
        P[qi] = v;
        t[j][m] = v;
    }
    __syncthreads();
    for (int i = 0; i < 64; ++i) {
        int mm = i * 2 + jr;
        Pt[((long long)b << 15) + (mm << 8) + j0 + m] = t[m][mm];
    }
}

// ft[b][c][j] = f[b][j][c], LDS-tiled 64x64 transpose
__global__ void k_ft(const ushort_t* __restrict__ f, ushort_t* __restrict__ ft) {
    __shared__ ushort_t t[64][65];
    int b = blockIdx.z, j0 = blockIdx.x * 64, c0 = blockIdx.y * 64;
    int c = threadIdx.x & 63, r = threadIdx.x >> 6;
#pragma unroll
    for (int k = 0; k < 64; k += 4)
        t[r + k][c] = f[((long long)(b * 256 + j0 + r + k)) * 256 + c0 + c];
    __syncthreads();
#pragma unroll
    for (int k = 0; k < 64; k += 4)
        ft[((long long)(b * 256 + c0 + r + k)) * 256 + j0 + c] = t[c][r + k];
}

// pack BIG weight via LDS (coalesced read+write): [o][tap*1024+ci]
__global__ void k_wbig2(const float* __restrict__ rate, const float* __restrict__ convw,
                        ushort_t* __restrict__ dst) {
    __shared__ float lw[10240];
    int o = blockIdx.x, tid = threadIdx.x;
    for (int i = tid; i < 9216; i += 256) lw[i] = rate[(long long)o * 9216 + i];
    for (int i = tid; i < 1024; i += 256) lw[9216 + i] = convw[(long long)o * 1024 + i];
    __syncthreads();
    for (int i = tid; i < 10240; i += 256) {
        int tap = i >> 10, ci = i & 1023;
        float v = (tap < 9) ? lw[ci * 9 + tap] : lw[9216 + ci];
        dst[(long long)o * 10240 + i] = f2b(v);
    }
}

__global__ void k_cast(const float* __restrict__ s, ushort_t* __restrict__ d) {
    int i = blockIdx.x * 256 + threadIdx.x; d[i] = f2b(s[i]);
}
__global__ void k_castT256(const float* __restrict__ s, ushort_t* __restrict__ d) {
    int c1 = threadIdx.x, c2 = blockIdx.x;
    d[c2 * 256 + c1] = f2b(s[c1 * 256 + c2]);
}
__global__ void k_bias2(const float* a0, const float* a1, const float* a2,
                        const float* cb, float* dst) {
    int t = threadIdx.x; int s = blockIdx.x;
    const float* a = s == 0 ? a0 : (s == 1 ? a1 : a2);
    dst[s * 256 + t] = a[t] + cb[t];
}
__global__ void k_sentinel(float* o, int n, float v) {
    int i = blockIdx.x * 256 + threadIdx.x; if (i < n) o[i] = v;
}

// ---------------- launch ----------------
extern "C" void kernel_launch(void* const* d_in, const int* in_sizes, int n_in,
                              void* d_out, int out_size, void* d_ws, size_t ws_size,
                              hipStream_t stream) {
    const float* x_cur  = (const float*)d_in[0];
    const float* x_lat  = (const float*)d_in[1];
    const float* conv_w = (const float*)d_in[2];
    const float* conv_b = (const float*)d_in[3];
    const float* conv1_w = (const float*)d_in[4];
    const float* conv1_b = (const float*)d_in[5];
    const float* conv3_w = (const float*)d_in[6];
    const float* conv3_b = (const float*)d_in[7];
    const float* rate_w[3] = {(const float*)d_in[8], (const float*)d_in[10], (const float*)d_in[12]};
    const float* rate_b[3] = {(const float*)d_in[9], (const float*)d_in[11], (const float*)d_in[13]};
    const float* ck_w  = (const float*)d_in[14];
    const float* ck_b  = (const float*)d_in[15];
    const float* avg_w = (const float*)d_in[16];
    const float* max_w = (const float*)d_in[17];
    const float* gcn_w = (const float*)d_in[18];
    float* out = (float*)d_out;

    char* w = (char*)d_ws;
    auto take = [&](size_t bytes) { void* p = (void*)w; w += (bytes + 255) & ~(size_t)255; return p; };
    ushort_t* xsum = (ushort_t*)take(16384ll * 1024 * 2);    // 33.55MB
    ushort_t* feat = (ushort_t*)take(16384ll * 1024 * 2);    // 33.55MB
    ushort_t* fbuf = (ushort_t*)take(16384ll * 256 * 2);     // 8.39MB
    ushort_t* ftb  = (ushort_t*)take(64ll * 256 * 256 * 2);  // 8.39MB
    ushort_t* qbuf = (ushort_t*)take(16384ll * 128 * 2);     // 4.19MB
    ushort_t* qc   = (ushort_t*)take(16384ll * 128 * 2);     // 4.19MB
    ushort_t* Pt   = (ushort_t*)take(64ll * 128 * 256 * 2);  // 4.19MB
    ushort_t* Pb   = (ushort_t*)take(16384ll * 128 * 2);     // 4.19MB
    ushort_t* St2  = (ushort_t*)take(64ll * 128 * 256 * 2);  // 4.19MB  [b][m][c]
    ushort_t* Htn  = (ushort_t*)take(64ll * 256 * 128 * 2);  // 4.19MB  [b][c][m] = -H^T
    ushort_t* wbig = (ushort_t*)take(256ll * 10240 * 2);     // 5.24MB
    ushort_t* w1b  = (ushort_t*)take(1024ll * 256 * 2);
    ushort_t* w3b  = (ushort_t*)take(1024ll * 768 * 2);
    ushort_t* ckb  = (ushort_t*)take(128ll * 256 * 2);
    ushort_t* gcnT = (ushort_t*)take(256ll * 256 * 2);
    ushort_t* zpage = (ushort_t*)take(256);
    float*    fbias = (float*)take(3 * 256 * 4);
    float*    cwb   = (float*)take(64 * 128 * 4);
    float*    dsum4 = (float*)take(4ll * 64 * 256 * 4);      // 4 disjoint partial slots
    ushort_t* catb = (ushort_t*)take(16384ll * 768 * 2);     // 25.17MB
    ushort_t* ftmp = (ushort_t*)take(4ll * 16384 * 256 * 2); // 33.55MB bf16 partials
    size_t need = (size_t)(w - (char*)d_ws);                 // ~176MB (r5 proved >=204MB)

    if (need > ws_size) {
        float v = 1.0e6f + (float)(ws_size >> 20);
        k_sentinel<<<(out_size + 255) / 256, 256, 0, stream>>>(out, out_size, v);
        return;
    }

    hipMemsetAsync(zpage, 0, 256, stream);
    k_upsum<<<dim3(64, 16), 256, 0, stream>>>(x_cur, x_lat, xsum);
    k_cast<<<1024, 256, 0, stream>>>(conv1_w, w1b);
    k_cast<<<3072, 256, 0, stream>>>(conv3_w, w3b);
    k_cast<<<128, 256, 0, stream>>>(ck_w, ckb);
    k_castT256<<<256, 256, 0, stream>>>(gcn_w, gcnT);
    k_bias2<<<3, 256, 0, stream>>>(rate_b[0], rate_b[1], rate_b[2], conv_b, fbias);

    for (int s = 0; s < 3; ++s) {
        k_wbig2<<<256, 256, 0, stream>>>(rate_w[s], conv_w, wbig);

        { // BIG: split-K=4, bf16 partials
            GemmP p{};
            p.A = (s == 0) ? xsum : feat;
            p.B = wbig; p.ldb = 10240;
            p.Ksub = 2560; p.kSplit = 2560; p.dil = 1 << s;
            p.obf = ftmp; p.oBatch = 16384ll * 256;
            p.zpage = zpage;
            gemm_big<<<dim3(128, 2, 4), 256, 0, stream>>>(p);
        }
        k_combine<<<2048, 256, 0, stream>>>(ftmp, fbias + s * 256, fbuf);
        k_poolcw<<<64, 256, 0, stream>>>(fbuf, avg_w, max_w, cwb);
        { // q = relu(f @ ck_w^T + ck_b); fused qc = q * cw
            GemmP p{};
            p.A = fbuf; p.lda = 256; p.B = ckb; p.ldb = 256;
            p.Ksub = 256;
            p.bias = ck_b; p.obf = qbuf; p.obf2 = qc; p.cw = cwb; p.ldo = 128;
            gemm_k<128, 128, 0, EPI_RELU><<<dim3(128, 1, 1), 256, 0, stream>>>(p);
        }
        { // dsum4[q4][b][i] = partial row-sums of sigmoid(qc_i . q_j) — no atomics
            GemmP p{};
            p.A = qc;   p.aBatch = 32768; p.lda = 128;
            p.B = qbuf; p.bBatch = 32768; p.ldb = 128;
            p.Ksub = 128; p.dsum = dsum4;
            gemm_k<128, 128, 0, EPI_SIG><<<dim3(2, 2, 64), 256, 0, stream>>>(p);
        }
        k_pscale<<<dim3(2, 64), 256, 0, stream>>>(qbuf, dsum4, Pb, Pt);
        k_ft<<<dim3(4, 4, 64), 256, 0, stream>>>(fbuf, ftb);
        { // St2[b][m][c] = cw[m] * sum_j Pt[m][j] ft[c][j]   (coalesced write)
            GemmP p{};
            p.A = Pt;  p.aBatch = 32768; p.lda = 256;
            p.B = ftb; p.bBatch = 65536; p.ldb = 256;
            p.Ksub = 256; p.cw = cwb;
            p.obf = St2; p.oBatch = 32768; p.ldo = 256;
            gemm_k<128, 128, 0, EPI_ST><<<dim3(1, 2, 64), 256, 0, stream>>>(p);
        }
        { // Htn[b][c][m] = - sum_c' gcnT[c][c'] St2[m][c']   ( = -(St2@G)^T )
            GemmP p{};
            p.A = gcnT; p.aBatch = 0;     p.lda = 256;
            p.B = St2;  p.bBatch = 32768; p.ldb = 256;
            p.Ksub = 256;
            p.obf = Htn; p.oBatch = 32768; p.ldo = 128;
            gemm_k<128, 128, 0, EPI_NEG><<<dim3(2, 1, 64), 256, 0, stream>>>(p);
        }
        { // Y = X + X@G - P@H : one K=384 dual-source GEMM -> catb slice
            GemmP p{};
            p.A = fbuf; p.aBatch = 65536; p.lda = 256;
            p.B = gcnT; p.bBatch = 0;     p.ldb = 256;
            p.A2 = Pb;  p.a2Batch = 32768; p.lda2 = 128;
            p.B2 = Htn; p.b2Batch = 32768; p.ldb2 = 128;
            p.Ksub = 384;
            p.res = fbuf; p.resBatch = 65536; p.ldres = 256;
            p.obf = catb + s * 256; p.oBatch = 256ll * 768; p.ldo = 768;
            gemm_k<128, 128, 2, EPI_Y><<<dim3(2, 2, 64), 256, 0, stream>>>(p);
        }
        if (s < 2) { // feature = conv1(f) + conv1_b + x_sum -> feat
            GemmP p{};
            p.A = fbuf; p.lda = 256; p.B = w1b; p.ldb = 256;
            p.Ksub = 256; p.bias = conv1_b;
            p.res = xsum; p.ldres = 1024;
            p.obf = feat; p.ldo = 1024;
            gemm_k<128, 128, 0, EPI_FEAT><<<dim3(128, 8, 1), 256, 0, stream>>>(p);
        }
    }
    { // out[bb][o][px] = sum_k w3[o][k] cat[px][k] + conv3_b[o]  (coalesced px writes)
        GemmP p{};
        p.A = w3b;  p.lda = 768;
        p.B = catb; p.ldb = 768;
        p.Ksub = 768; p.bias = conv3_b; p.of32 = out;
        gemm_k<128, 128, 0, EPI_OUTT><<<dim3(8, 128, 1), 256, 0, stream>>>(p);
    }
}

// Round 7
// 762.103 us; speedup vs baseline: 1.5906x; 1.0837x over previous
//
#include <hip/hip_runtime.h>

typedef unsigned short ushort_t;
typedef unsigned int uint32;
typedef __attribute__((ext_vector_type(8))) unsigned short ushort8;
typedef __attribute__((ext_vector_type(8))) __bf16 bf16x8;
typedef __attribute__((ext_vector_type(4))) float f32x4;

__device__ __forceinline__ ushort_t f2b(float f) {
    union { float f; uint32 u; } v; v.f = f;
    uint32 r = v.u + 0x7fffu + ((v.u >> 16) & 1u);
    return (ushort_t)(r >> 16);
}
__device__ __forceinline__ float b2f(ushort_t b) {
    union { uint32 u; float f; } v; v.u = ((uint32)b) << 16;
    return v.f;
}
__device__ __forceinline__ float sigm(float x) { return 1.f / (1.f + __expf(-x)); }

__device__ __forceinline__ void gload_lds16(const void* g, void* l) {
    __builtin_amdgcn_global_load_lds(
        (__attribute__((address_space(1))) void*)g,
        (__attribute__((address_space(3))) void*)l, 16, 0, 0);
}

// epilogues
constexpr int EPI_RELU  = 1;  // bf16 relu(acc+bias) -> obf; obf2 = relu*cw (fused qc)
constexpr int EPI_FEAT  = 2;  // bf16 acc+bias+res -> obf
constexpr int EPI_SIG   = 3;  // rowsum sigmoid(acc) -> dsum4[(by*2+wc)][z*256+row]
constexpr int EPI_XG    = 4;  // bf16 acc -> obf[z*oB + row*ldo + col]  (XGt)
constexpr int EPI_NEGCW = 5;  // bf16 -acc*cw[z*128+col] -> obf[z*oB + row*ldo + col] (Htn)
constexpr int EPI_Y     = 6;  // bf16 res + acc -> obf (catb slice)
constexpr int EPI_OUTT  = 7;  // fp32 acc+bias[row]; row=outchan, col=pixel -> NCHW coalesced

struct GemmP {
    const ushort_t* A; const ushort_t* B;
    const ushort_t* A2; const ushort_t* B2;     // AMODE==2 second source (gk >= 256)
    long long aBatch, bBatch, a2Batch, b2Batch;
    int lda, ldb, lda2, ldb2;
    int Ksub, kSplit, dil;
    const float* bias;
    const ushort_t* res; long long resBatch; int ldres;
    ushort_t* obf; long long oBatch; int ldo;
    ushort_t* obf2;
    float* of32;
    const float* cw;
    float* dsum;
    const ushort_t* zpage;
};

// ---------------------------------------------------------------------------
// BIG implicit-GEMM (9 dilated conv taps + conv1x1 identity tap), m97-style
// global_load_lds staging, split-K=5 (grid 1280 = 5 blocks/CU = LDS cap),
// 128x128 tile, BK=64. LDS image S[r][g] = G[r][g ^ (r&7)] via pre-swizzled
// per-lane global source; read side applies the same XOR (conflict-free,
// verified r3: 4.7e7 -> 0). OOB taps -> zeroed 16B page. bf16 partials.
// ---------------------------------------------------------------------------
__global__ __launch_bounds__(256) void gemm_big(GemmP p) {
    __shared__ __align__(16) ushort_t aT[128 * 64];
    __shared__ __align__(16) ushort_t bT[128 * 64];
    const int tid = threadIdx.x;
    const int z = blockIdx.z;
    const int m0 = blockIdx.x * 128, n0 = blockIdx.y * 128;
    const int lane = tid & 63, wid = tid >> 6;
    const int l15 = lane & 15, l16 = lane >> 4;
    const int wr = wid >> 1, wc = wid & 1;
    const int lrow = lane >> 3;
    const int sgran = (lane & 7) ^ lrow;

    int ayy[4], axx[4];
    const ushort_t* aBase[4];
    const ushort_t* bBase[4];
#pragma unroll
    for (int i = 0; i < 4; ++i) {
        int row = wid * 32 + i * 8 + lrow;
        int m = m0 + row;
        int bb = m >> 8;
        ayy[i] = (m >> 4) & 15; axx[i] = m & 15;
        aBase[i] = p.A + (long long)bb * 262144 + sgran * 8;
        bBase[i] = p.B + (long long)(n0 + row) * p.ldb + sgran * 8;
    }

    f32x4 acc[4][4];
#pragma unroll
    for (int i = 0; i < 4; ++i)
#pragma unroll
        for (int j = 0; j < 4; ++j) acc[i][j] = (f32x4){0.f, 0.f, 0.f, 0.f};

    const int gk0 = z * p.kSplit;
    const int iters = p.Ksub >> 6;
    for (int it = 0; it < iters; ++it) {
        const int gk = gk0 + it * 64;
        const int tap = gk >> 10, kin = gk & 1023;
        int dy = 0, dx = 0;
        if (tap < 9) { int ky = tap / 3; dy = (ky - 1) * p.dil; dx = (tap - ky * 3 - 1) * p.dil; }
#pragma unroll
        for (int i = 0; i < 4; ++i) {
            int iy = ayy[i] + dy, ix = axx[i] + dx;
            bool ok = ((unsigned)iy < 16u) && ((unsigned)ix < 16u);
            const ushort_t* ga = ok ? (aBase[i] + (((iy << 4) + ix) << 10) + kin) : p.zpage;
            gload_lds16(ga, &aT[(wid * 32 + i * 8) * 64]);
        }
#pragma unroll
        for (int i = 0; i < 4; ++i)
            gload_lds16(bBase[i] + gk, &bT[(wid * 32 + i * 8) * 64]);
        asm volatile("s_waitcnt vmcnt(0)" ::: "memory");
        __syncthreads();
#pragma unroll
        for (int ks = 0; ks < 2; ++ks) {
            bf16x8 af[4], bfr[4];
#pragma unroll
            for (int mi = 0; mi < 4; ++mi) {
                int rr = wr * 64 + mi * 16 + l15;
                int cc = (ks * 32 + l16 * 8) ^ ((rr & 7) << 3);
                af[mi] = __builtin_bit_cast(bf16x8, *(const ushort8*)&aT[rr * 64 + cc]);
            }
#pragma unroll
            for (int ni = 0; ni < 4; ++ni) {
                int rr = wc * 64 + ni * 16 + l15;
                int cc = (ks * 32 + l16 * 8) ^ ((rr & 7) << 3);
                bfr[ni] = __builtin_bit_cast(bf16x8, *(const ushort8*)&bT[rr * 64 + cc]);
            }
#pragma unroll
            for (int mi = 0; mi < 4; ++mi)
#pragma unroll
                for (int ni = 0; ni < 4; ++ni)
                    acc[mi][ni] = __builtin_amdgcn_mfma_f32_16x16x32_bf16(af[mi], bfr[ni], acc[mi][ni], 0, 0, 0);
        }
        __syncthreads();
    }
#pragma unroll
    for (int mi = 0; mi < 4; ++mi)
#pragma unroll
        for (int ni = 0; ni < 4; ++ni) {
            int gcol = n0 + wc * 64 + ni * 16 + l15;
            int growb = m0 + wr * 64 + mi * 16 + l16 * 4;
#pragma unroll
            for (int r = 0; r < 4; ++r)
                p.obf[(long long)z * p.oBatch + (long long)(growb + r) * 256 + gcol] =
                    f2b(acc[mi][ni][r]);
        }
}

// Generic 4-wave MFMA GEMM: C = A.B^T, bf16 in, fp32 acc. AMODE==0: single
// source; AMODE==2: dual source (gk<256 from A/B, gk>=256 from A2/B2 — used
// for Y = X + X@G - P@H as one K=384 pass; Htn pre-negated & cw-scaled).
template<int BM, int BN, int AMODE, int EPI>
__global__ __launch_bounds__(256) void gemm_k(GemmP p) {
    __shared__ __align__(16) ushort_t aT[BM * 64];
    __shared__ __align__(16) ushort_t bT[BN * 64];
    constexpr int APASS = BM / 32, BPASS = BN / 32;
    constexpr int MFRAG = BM / 32, NFRAG = BN / 32;
    const int tid = threadIdx.x;
    const int z = blockIdx.z;
    const int m0 = blockIdx.x * BM, n0 = blockIdx.y * BN;
    const int lane = tid & 63, wid = tid >> 6;
    const int l15 = lane & 15, l16 = lane >> 4;
    const int wr = wid >> 1, wc = wid & 1;
    const int srow = tid >> 3, scol = (tid & 7) * 8;
    const int swcol = scol ^ ((srow & 7) << 3);

    const ushort_t* aptr[APASS];
    const ushort_t* bptr[BPASS];
    const ushort_t* aptr2[APASS];
    const ushort_t* bptr2[BPASS];
#pragma unroll
    for (int pi = 0; pi < APASS; ++pi)
        aptr[pi] = p.A + (long long)z * p.aBatch +
                   (long long)(m0 + pi * 32 + srow) * p.lda + scol;
#pragma unroll
    for (int pi = 0; pi < BPASS; ++pi)
        bptr[pi] = p.B + (long long)z * p.bBatch +
                   (long long)(n0 + pi * 32 + srow) * p.ldb + scol;
    if constexpr (AMODE == 2) {
#pragma unroll
        for (int pi = 0; pi < APASS; ++pi)
            aptr2[pi] = p.A2 + (long long)z * p.a2Batch +
                        (long long)(m0 + pi * 32 + srow) * p.lda2 + scol;
#pragma unroll
        for (int pi = 0; pi < BPASS; ++pi)
            bptr2[pi] = p.B2 + (long long)z * p.b2Batch +
                        (long long)(n0 + pi * 32 + srow) * p.ldb2 + scol;
    }

    f32x4 acc[MFRAG][NFRAG];
#pragma unroll
    for (int i = 0; i < MFRAG; ++i)
#pragma unroll
        for (int j = 0; j < NFRAG; ++j) acc[i][j] = (f32x4){0.f, 0.f, 0.f, 0.f};

    ushort8 ar[APASS], br[BPASS];
    auto ldg = [&](int gk) {
        if (AMODE == 2 && gk >= 256) {
            int g2 = gk - 256;
#pragma unroll
            for (int pi = 0; pi < APASS; ++pi) ar[pi] = *(const ushort8*)(aptr2[pi] + g2);
#pragma unroll
            for (int pi = 0; pi < BPASS; ++pi) br[pi] = *(const ushort8*)(bptr2[pi] + g2);
        } else {
#pragma unroll
            for (int pi = 0; pi < APASS; ++pi) ar[pi] = *(const ushort8*)(aptr[pi] + gk);
#pragma unroll
            for (int pi = 0; pi < BPASS; ++pi) br[pi] = *(const ushort8*)(bptr[pi] + gk);
        }
    };

    const int gk0 = z * p.kSplit;
    ldg(gk0);
    const int iters = p.Ksub >> 6;
    for (int it = 0; it < iters; ++it) {
#pragma unroll
        for (int pi = 0; pi < APASS; ++pi)
            *(ushort8*)&aT[(pi * 32 + srow) * 64 + swcol] = ar[pi];
#pragma unroll
        for (int pi = 0; pi < BPASS; ++pi)
            *(ushort8*)&bT[(pi * 32 + srow) * 64 + swcol] = br[pi];
        __syncthreads();
        if (it + 1 < iters) ldg(gk0 + (it + 1) * 64);
#pragma unroll
        for (int ks = 0; ks < 2; ++ks) {
            bf16x8 af[MFRAG], bfr[NFRAG];
#pragma unroll
            for (int mi = 0; mi < MFRAG; ++mi) {
                int rr = wr * (BM / 2) + mi * 16 + l15;
                int cc = (ks * 32 + l16 * 8) ^ ((rr & 7) << 3);
                af[mi] = __builtin_bit_cast(bf16x8, *(const ushort8*)&aT[rr * 64 + cc]);
            }
#pragma unroll
            for (int ni = 0; ni < NFRAG; ++ni) {
                int rr = wc * (BN / 2) + ni * 16 + l15;
                int cc = (ks * 32 + l16 * 8) ^ ((rr & 7) << 3);
                bfr[ni] = __builtin_bit_cast(bf16x8, *(const ushort8*)&bT[rr * 64 + cc]);
            }
#pragma unroll
            for (int mi = 0; mi < MFRAG; ++mi)
#pragma unroll
                for (int ni = 0; ni < NFRAG; ++ni)
                    acc[mi][ni] = __builtin_amdgcn_mfma_f32_16x16x32_bf16(af[mi], bfr[ni], acc[mi][ni], 0, 0, 0);
        }
        __syncthreads();
    }

    // ---------------- epilogue ----------------
#pragma unroll
    for (int mi = 0; mi < MFRAG; ++mi) {
        if constexpr (EPI == EPI_SIG) {
#pragma unroll
            for (int r = 0; r < 4; ++r) {
                float sv = 0.f;
#pragma unroll
                for (int ni = 0; ni < NFRAG; ++ni) sv += sigm(acc[mi][ni][r]);
                sv += __shfl_xor(sv, 1); sv += __shfl_xor(sv, 2);
                sv += __shfl_xor(sv, 4); sv += __shfl_xor(sv, 8);
                if (l15 == 0) {
                    int grow = m0 + wr * (BM / 2) + mi * 16 + l16 * 4 + r;
                    int q4 = blockIdx.y * 2 + wc;  // disjoint slot -> deterministic
                    p.dsum[q4 * 16384 + z * 256 + grow] = sv;
                }
            }
        } else {
#pragma unroll
            for (int ni = 0; ni < NFRAG; ++ni) {
                int gcol = n0 + wc * (BN / 2) + ni * 16 + l15;
                int growb = m0 + wr * (BM / 2) + mi * 16 + l16 * 4;
#pragma unroll
                for (int r = 0; r < 4; ++r) {
                    int grow = growb + r;
                    float v = acc[mi][ni][r];
                    if constexpr (EPI == EPI_RELU) {
                        v += p.bias[gcol]; v = fmaxf(v, 0.f);
                        p.obf[(long long)grow * p.ldo + gcol] = f2b(v);
                        p.obf2[(long long)grow * p.ldo + gcol] =
                            f2b(v * p.cw[((grow >> 8) << 7) + gcol]);
                    } else if constexpr (EPI == EPI_FEAT) {
                        v += p.bias[gcol] + b2f(p.res[(long long)grow * p.ldres + gcol]);
                        p.obf[(long long)grow * p.ldo + gcol] = f2b(v);
                    } else if constexpr (EPI == EPI_XG) {
                        p.obf[(long long)z * p.oBatch + (long long)grow * p.ldo + gcol] = f2b(v);
                    } else if constexpr (EPI == EPI_NEGCW) {
                        v *= -p.cw[z * 128 + gcol];
                        p.obf[(long long)z * p.oBatch + (long long)grow * p.ldo + gcol] = f2b(v);
                    } else if constexpr (EPI == EPI_Y) {
                        v = b2f(p.res[(long long)z * p.resBatch + (long long)grow * p.ldres + gcol]) + v;
                        p.obf[(long long)z * p.oBatch + (long long)grow * p.ldo + gcol] = f2b(v);
                    } else if constexpr (EPI == EPI_OUTT) {
                        v += p.bias[grow];               // row = out-channel
                        int bb = gcol >> 8, px = gcol & 255;
                        p.of32[((long long)bb * 1024 + grow) * 256 + px] = v;  // coalesced over px
                    }
                }
            }
        }
    }
}

// ---------------- small kernels ----------------

// combine 5 bf16 split-K partials + bias -> bf16 fbuf
__global__ void k_combine(const ushort_t* __restrict__ t, const float* __restrict__ fbias_s,
                          ushort_t* __restrict__ f) {
    int idx = blockIdx.x * 256 + threadIdx.x;  // x8 elements
    const long long N = 16384ll * 256;
    ushort8 a0 = *(const ushort8*)(t + (long long)idx * 8);
    ushort8 a1 = *(const ushort8*)(t + N + (long long)idx * 8);
    ushort8 a2 = *(const ushort8*)(t + 2 * N + (long long)idx * 8);
    ushort8 a3 = *(const ushort8*)(t + 3 * N + (long long)idx * 8);
    ushort8 a4 = *(const ushort8*)(t + 4 * N + (long long)idx * 8);
    int cb = (idx * 8) & 255;
    ushort8 o;
#pragma unroll
    for (int k = 0; k < 8; ++k)
        o[k] = f2b(b2f(a0[k]) + b2f(a1[k]) + b2f(a2[k]) + b2f(a3[k]) + b2f(a4[k]) + fbias_s[cb + k]);
    *(ushort8*)&f[(long long)idx * 8] = o;
}

// x_sum = x_cur * (1 + bilinear_up2x_align_corners(x_lat)); bf16 [B*256][1024]
__global__ void k_upsum(const float* __restrict__ xc, const float* __restrict__ xl,
                        ushort_t* __restrict__ xs) {
    __shared__ float lat[64 * 64];
    __shared__ ushort_t tile[64 * 258];
    int b = blockIdx.x, c0 = blockIdx.y * 64;
    int t = threadIdx.x;
    for (int i = t; i < 4096; i += 256)
        lat[i] = xl[((long long)(b * 1024 + c0 + (i >> 6))) * 64 + (i & 63)];
    __syncthreads();
    int y = t >> 4, x = t & 15;
    float fy = y * (7.f / 15.f); int y0 = (int)fy; float wy = fy - y0; int y1 = y0 + 1 > 7 ? 7 : y0 + 1;
    float fx = x * (7.f / 15.f); int x0 = (int)fx; float wx = fx - x0; int x1 = x0 + 1 > 7 ? 7 : x0 + 1;
    for (int cc = 0; cc < 64; ++cc) {
        float cur = xc[((long long)(b * 1024 + c0 + cc)) * 256 + t];
        const float* L = &lat[cc * 64];
        float tv = L[y0 * 8 + x0] * (1.f - wx) + L[y0 * 8 + x1] * wx;
        float bv = L[y1 * 8 + x0] * (1.f - wx) + L[y1 * 8 + x1] * wx;
        float up = tv + (bv - tv) * wy;
        tile[cc * 258 + t] = f2b(cur * (1.f + up));
    }
    __syncthreads();
    for (int i = t; i < 16384; i += 256) {
        int px = i >> 6, cc = i & 63;
        xs[((long long)(b * 256 + px)) * 1024 + c0 + cc] = tile[cc * 258 + px];
    }
}

// fused avg/max pool + channel-weight MLP
__global__ void k_poolcw(const ushort_t* __restrict__ f,
                         const float* __restrict__ aw, const float* __restrict__ mw,
                         float* __restrict__ cw) {
    __shared__ float sa[256], sm[256];
    int b = blockIdx.x, t = threadIdx.x;
    float s = 0.f, m = -3.4e38f;
    const ushort_t* base = f + (long long)b * 65536 + t;
    for (int px = 0; px < 256; ++px) { float v = b2f(base[px * 256]); s += v; m = fmaxf(m, v); }
    sa[t] = s * (1.f / 256.f);
    sm[t] = m;
    __syncthreads();
    if (t < 128) {
        float s1 = 0.f, s2 = 0.f;
        const float* a = aw + t * 256; const float* w = mw + t * 256;
        for (int c = 0; c < 256; ++c) { s1 += sa[c] * a[c]; s2 += sm[c] * w[c]; }
        s1 = fmaxf(s1, 0.f); s2 = fmaxf(s2, 0.f);
        cw[b * 128 + t] = sigm(s1 + s2);
    }
}

// P scale + LDS-tiled transposed Pt (both writes coalesced)
__global__ void k_pscale(const ushort_t* __restrict__ q, const float* __restrict__ dsum4,
                         ushort_t* __restrict__ P, ushort_t* __restrict__ Pt) {
    __shared__ ushort_t t[128][130];
    __shared__ float dd[128];
    int jh = blockIdx.x, b = blockIdx.y;
    int j0 = jh * 128;
    int tid = threadIdx.x;
    if (tid < 128) {
        int pix = b * 256 + j0 + tid;
        float s = dsum4[pix] + dsum4[16384 + pix] + dsum4[32768 + pix] + dsum4[49152 + pix];
        dd[tid] = rsqrtf(s);
    }
    __syncthreads();
    int jr = tid >> 7, m = tid & 127;
    for (int i = 0; i < 64; ++i) {
        int j = i * 2 + jr;
        long long qi = ((long long)(b * 256 + j0 + j)) * 128 + m;
        ushort_t v = f2b(dd[j] * b2f(q[qi]));
        P[qi] = v;
        t[j][m] = v;
    }
    __syncthreads();
    for (int i = 0; i < 64; ++i) {
        int mm = i * 2 + jr;
        Pt[((long long)b << 15) + (mm << 8) + j0 + m] = t[m][mm];
    }
}

// One-shot weight/bias packing: blocks [0,768) pack wbig for 3 stages via
// LDS; blocks >= 768 grid-stride flat regions (w1b, w3b, ckb, gcnT, fbias,
// zpage).
__global__ void k_packall(const float* r0, const float* r1, const float* r2,
                          const float* convw, const float* c1w, const float* c3w,
                          const float* ckw, const float* gcnw,
                          const float* rb0, const float* rb1, const float* rb2,
                          const float* cb,
                          ushort_t* wbig3, ushort_t* w1b, ushort_t* w3b,
                          ushort_t* ckb, ushort_t* gcnT, float* fbias,
                          ushort_t* zpage) {
    int blk = blockIdx.x, tid = threadIdx.x;
    if (blk < 768) {
        __shared__ float lw[10240];
        int s = blk >> 8, o = blk & 255;
        const float* rate = s == 0 ? r0 : (s == 1 ? r1 : r2);
        for (int i = tid; i < 9216; i += 256) lw[i] = rate[(long long)o * 9216 + i];
        for (int i = tid; i < 1024; i += 256) lw[9216 + i] = convw[(long long)o * 1024 + i];
        __syncthreads();
        ushort_t* dst = wbig3 + (long long)blk * 10240;
        for (int i = tid; i < 10240; i += 256) {
            int tap = i >> 10, ci = i & 1023;
            float v = (tap < 9) ? lw[ci * 9 + tap] : lw[9216 + i - 9216 + ci - ci];  // placeholder
            v = (tap < 9) ? lw[ci * 9 + tap] : lw[9216 + ci];
            dst[i] = f2b(v);
        }
        return;
    }
    // flat regions
    const int R1 = 262144, R2 = R1 + 786432, R3 = R2 + 32768, R4 = R3 + 65536;
    const int R5 = R4 + 768, R6 = R5 + 128;  // fbias(768), zpage(128 ushorts)
    int base = (blk - 768) * 2048 + tid * 8;
#pragma unroll
    for (int k = 0; k < 8; ++k) {
        int i = base + k;
        if (i >= R6) return;
        if (i < R1) w1b[i] = f2b(c1w[i]);
        else if (i < R2) w3b[i - R1] = f2b(c3w[i - R1]);
        else if (i < R3) ckb[i - R2] = f2b(ckw[i - R2]);
        else if (i < R4) {
            int ii = i - R3; int c2 = ii >> 8, c1 = ii & 255;
            gcnT[ii] = f2b(gcnw[c1 * 256 + c2]);
        } else if (i < R5) {
            int ii = i - R4; int s = ii >> 8, t = ii & 255;
            const float* rb = s == 0 ? rb0 : (s == 1 ? rb1 : rb2);
            fbias[ii] = rb[t] + cb[t];
        } else {
            zpage[i - R5] = 0;
        }
    }
}

__global__ void k_sentinel(float* o, int n, float v) {
    int i = blockIdx.x * 256 + threadIdx.x; if (i < n) o[i] = v;
}

// ---------------- launch ----------------
extern "C" void kernel_launch(void* const* d_in, const int* in_sizes, int n_in,
                              void* d_out, int out_size, void* d_ws, size_t ws_size,
                              hipStream_t stream) {
    const float* x_cur  = (const float*)d_in[0];
    const float* x_lat  = (const float*)d_in[1];
    const float* conv_w = (const float*)d_in[2];
    const float* conv_b = (const float*)d_in[3];
    const float* conv1_w = (const float*)d_in[4];
    const float* conv1_b = (const float*)d_in[5];
    const float* conv3_w = (const float*)d_in[6];
    const float* conv3_b = (const float*)d_in[7];
    const float* rate_w[3] = {(const float*)d_in[8], (const float*)d_in[10], (const float*)d_in[12]};
    const float* rate_b[3] = {(const float*)d_in[9], (const float*)d_in[11], (const float*)d_in[13]};
    const float* ck_w  = (const float*)d_in[14];
    const float* ck_b  = (const float*)d_in[15];
    const float* avg_w = (const float*)d_in[16];
    const float* max_w = (const float*)d_in[17];
    const float* gcn_w = (const float*)d_in[18];
    float* out = (float*)d_out;

    char* w = (char*)d_ws;
    auto take = [&](size_t bytes) { void* p = (void*)w; w += (bytes + 255) & ~(size_t)255; return p; };
    ushort_t* xsum  = (ushort_t*)take(16384ll * 1024 * 2);    // 33.55MB
    ushort_t* feat  = (ushort_t*)take(16384ll * 1024 * 2);    // 33.55MB
    ushort_t* fbuf  = (ushort_t*)take(16384ll * 256 * 2);     // 8.39MB
    ushort_t* xgt   = (ushort_t*)take(64ll * 256 * 256 * 2);  // 8.39MB  (X@G)^T per batch
    ushort_t* qbuf  = (ushort_t*)take(16384ll * 128 * 2);     // 4.19MB
    ushort_t* qc    = (ushort_t*)take(16384ll * 128 * 2);     // 4.19MB
    ushort_t* Pt    = (ushort_t*)take(64ll * 128 * 256 * 2);  // 4.19MB
    ushort_t* Pb    = (ushort_t*)take(16384ll * 128 * 2);     // 4.19MB
    ushort_t* Htn   = (ushort_t*)take(64ll * 256 * 128 * 2);  // 4.19MB  [b][c][m]
    ushort_t* wbig3 = (ushort_t*)take(3ll * 256 * 10240 * 2); // 15.73MB
    ushort_t* w1b   = (ushort_t*)take(1024ll * 256 * 2);
    ushort_t* w3b   = (ushort_t*)take(1024ll * 768 * 2);
    ushort_t* ckb   = (ushort_t*)take(128ll * 256 * 2);
    ushort_t* gcnT  = (ushort_t*)take(256ll * 256 * 2);
    ushort_t* zpage = (ushort_t*)take(256);
    float*    fbias = (float*)take(3 * 256 * 4);
    float*    cwb   = (float*)take(64 * 128 * 4);
    float*    dsum4 = (float*)take(4ll * 64 * 256 * 4);
    ushort_t* catb  = (ushort_t*)take(16384ll * 768 * 2);     // 25.17MB
    ushort_t* ftmp  = (ushort_t*)take(5ll * 16384 * 256 * 2); // 41.94MB (5 splits)
    size_t need = (size_t)(w - (char*)d_ws);                  // ~190MB (<=204 proven r4/r5)

    if (need > ws_size) {
        float v = 1.0e6f + (float)(ws_size >> 20);
        k_sentinel<<<(out_size + 255) / 256, 256, 0, stream>>>(out, out_size, v);
        return;
    }

    k_packall<<<768 + 561, 256, 0, stream>>>(
        rate_w[0], rate_w[1], rate_w[2], conv_w, conv1_w, conv3_w, ck_w, gcn_w,
        rate_b[0], rate_b[1], rate_b[2], conv_b,
        wbig3, w1b, w3b, ckb, gcnT, fbias, zpage);
    k_upsum<<<dim3(64, 16), 256, 0, stream>>>(x_cur, x_lat, xsum);

    for (int s = 0; s < 3; ++s) {
        { // BIG: split-K=5, bf16 partials
            GemmP p{};
            p.A = (s == 0) ? xsum : feat;
            p.B = wbig3 + (long long)s * 256 * 10240; p.ldb = 10240;
            p.Ksub = 2048; p.kSplit = 2048; p.dil = 1 << s;
            p.obf = ftmp; p.oBatch = 16384ll * 256;
            p.zpage = zpage;
            gemm_big<<<dim3(128, 2, 5), 256, 0, stream>>>(p);
        }
        k_combine<<<2048, 256, 0, stream>>>(ftmp, fbias + s * 256, fbuf);
        k_poolcw<<<64, 256, 0, stream>>>(fbuf, avg_w, max_w, cwb);
        { // q = relu(f @ ck_w^T + ck_b); fused qc = q * cw
            GemmP p{};
            p.A = fbuf; p.lda = 256; p.B = ckb; p.ldb = 256;
            p.Ksub = 256;
            p.bias = ck_b; p.obf = qbuf; p.obf2 = qc; p.cw = cwb; p.ldo = 128;
            gemm_k<128, 128, 0, EPI_RELU><<<dim3(128, 1, 1), 256, 0, stream>>>(p);
        }
        { // dsum4 partial row-sums of sigmoid(qc_i . q_j) — no atomics
            GemmP p{};
            p.A = qc;   p.aBatch = 32768; p.lda = 128;
            p.B = qbuf; p.bBatch = 32768; p.ldb = 128;
            p.Ksub = 128; p.dsum = dsum4;
            gemm_k<128, 128, 0, EPI_SIG><<<dim3(2, 2, 64), 256, 0, stream>>>(p);
        }
        k_pscale<<<dim3(2, 64), 256, 0, stream>>>(qbuf, dsum4, Pb, Pt);
        { // XGt[b][c][j] = sum_c' gcnT[c][c'] fbuf_b[j][c']  (= (X@G)^T, no transpose kernel)
            GemmP p{};
            p.A = gcnT; p.aBatch = 0;     p.lda = 256;
            p.B = fbuf; p.bBatch = 65536; p.ldb = 256;
            p.Ksub = 256;
            p.obf = xgt; p.oBatch = 65536; p.ldo = 256;
            gemm_k<128, 128, 0, EPI_XG><<<dim3(2, 2, 64), 256, 0, stream>>>(p);
        }
        { // Htn[b][c][m] = -cw[m] * sum_j XGt[c][j] Pt[m][j]   (= -(St@G)^T)
            GemmP p{};
            p.A = xgt; p.aBatch = 65536; p.lda = 256;
            p.B = Pt;  p.bBatch = 32768; p.ldb = 256;
            p.Ksub = 256; p.cw = cwb;
            p.obf = Htn; p.oBatch = 32768; p.ldo = 128;
            gemm_k<128, 128, 0, EPI_NEGCW><<<dim3(2, 1, 64), 256, 0, stream>>>(p);
        }
        { // Y = X + X@G - P@H : one K=384 dual-source GEMM -> catb slice
            GemmP p{};
            p.A = fbuf; p.aBatch = 65536; p.lda = 256;
            p.B = gcnT; p.bBatch = 0;     p.ldb = 256;
            p.A2 = Pb;  p.a2Batch = 32768; p.lda2 = 128;
            p.B2 = Htn; p.b2Batch = 32768; p.ldb2 = 128;
            p.Ksub = 384;
            p.res = fbuf; p.resBatch = 65536; p.ldres = 256;
            p.obf = catb + s * 256; p.oBatch = 256ll * 768; p.ldo = 768;
            gemm_k<128, 128, 2, EPI_Y><<<dim3(2, 2, 64), 256, 0, stream>>>(p);
        }
        if (s < 2) { // feature = conv1(f) + conv1_b + x_sum -> feat
            GemmP p{};
            p.A = fbuf; p.lda = 256; p.B = w1b; p.ldb = 256;
            p.Ksub = 256; p.bias = conv1_b;
            p.res = xsum; p.ldres = 1024;
            p.obf = feat; p.ldo = 1024;
            gemm_k<128, 128, 0, EPI_FEAT><<<dim3(128, 8, 1), 256, 0, stream>>>(p);
        }
    }
    { // out[bb][o][px] = sum_k w3[o][k] cat[px][k] + conv3_b[o]  (coalesced px writes)
        GemmP p{};
        p.A = w3b;  p.lda = 768;
        p.B = catb; p.ldb = 768;
        p.Ksub = 768; p.bias = conv3_b; p.of32 = out;
        gemm_k<128, 128, 0, EPI_OUTT><<<dim3(8, 128, 1), 256, 0, stream>>>(p);
    }
}

// Round 8
// 696.075 us; speedup vs baseline: 1.7415x; 1.0949x over previous
//
#include <hip/hip_runtime.h>

typedef unsigned short ushort_t;
typedef unsigned int uint32;
typedef __attribute__((ext_vector_type(8))) unsigned short ushort8;
typedef __attribute__((ext_vector_type(8))) __bf16 bf16x8;
typedef __attribute__((ext_vector_type(4))) float f32x4;

__device__ __forceinline__ ushort_t f2b(float f) {
    union { float f; uint32 u; } v; v.f = f;
    uint32 r = v.u + 0x7fffu + ((v.u >> 16) & 1u);
    return (ushort_t)(r >> 16);
}
__device__ __forceinline__ float b2f(ushort_t b) {
    union { uint32 u; float f; } v; v.u = ((uint32)b) << 16;
    return v.f;
}
__device__ __forceinline__ float sigm(float x) { return 1.f / (1.f + __expf(-x)); }

__device__ __forceinline__ void gload_lds16(const void* g, void* l) {
    __builtin_amdgcn_global_load_lds(
        (__attribute__((address_space(1))) void*)g,
        (__attribute__((address_space(3))) void*)l, 16, 0, 0);
}

// epilogues
constexpr int EPI_RELU  = 1;  // bf16 relu(acc+bias) -> obf
constexpr int EPI_FEAT  = 2;  // bf16 acc+bias+res -> obf
constexpr int EPI_SIG   = 3;  // rowsum sigmoid(acc) -> dsum[(by*2+wc)][z*256+row]
constexpr int EPI_XG    = 4;  // bf16 acc -> obf[z*oB + row*ldo + col]  (XGt)
constexpr int EPI_NEGCW = 5;  // bf16 -acc*cw[z*128+col] -> obf (Htn)
constexpr int EPI_Y     = 6;  // bf16 res + acc -> obf (catb slice)
constexpr int EPI_OUTT  = 7;  // fp32 acc+bias[row]; row=outchan, col=pixel -> NCHW coalesced

struct GemmP {
    const ushort_t* A; const ushort_t* B;
    const ushort_t* A2; const ushort_t* B2;     // AMODE==2 second source (gk >= 256)
    long long aBatch, bBatch, a2Batch, b2Batch;
    int lda, ldb, lda2, ldb2;
    int Ksub, kSplit, dil;
    const float* bias;
    const ushort_t* res; long long resBatch; int ldres;
    ushort_t* obf; long long oBatch; int ldo;
    float* of32;
    const float* cw;
    float* dsum;
    const ushort_t* zpage;
};

// ---------------------------------------------------------------------------
// BIG implicit-GEMM (9 dilated conv taps + conv1x1 identity tap), m97-style
// global_load_lds staging, split-K=5 (grid 1280 = 5 blocks/CU = LDS cap),
// 128x128 tile, BK=64. LDS image S[r][g] = G[r][g ^ (r&7)] via pre-swizzled
// per-lane global source; read side applies the same XOR (conflict-free,
// verified r3: 4.7e7 -> 0). OOB taps -> zeroed 16B page. bf16 partials.
// ---------------------------------------------------------------------------
__global__ __launch_bounds__(256) void gemm_big(GemmP p) {
    __shared__ __align__(16) ushort_t aT[128 * 64];
    __shared__ __align__(16) ushort_t bT[128 * 64];
    const int tid = threadIdx.x;
    const int z = blockIdx.z;
    const int m0 = blockIdx.x * 128, n0 = blockIdx.y * 128;
    const int lane = tid & 63, wid = tid >> 6;
    const int l15 = lane & 15, l16 = lane >> 4;
    const int wr = wid >> 1, wc = wid & 1;
    const int lrow = lane >> 3;
    const int sgran = (lane & 7) ^ lrow;

    int ayy[4], axx[4];
    const ushort_t* aBase[4];
    const ushort_t* bBase[4];
#pragma unroll
    for (int i = 0; i < 4; ++i) {
        int row = wid * 32 + i * 8 + lrow;
        int m = m0 + row;
        int bb = m >> 8;
        ayy[i] = (m >> 4) & 15; axx[i] = m & 15;
        aBase[i] = p.A + (long long)bb * 262144 + sgran * 8;
        bBase[i] = p.B + (long long)(n0 + row) * p.ldb + sgran * 8;
    }

    f32x4 acc[4][4];
#pragma unroll
    for (int i = 0; i < 4; ++i)
#pragma unroll
        for (int j = 0; j < 4; ++j) acc[i][j] = (f32x4){0.f, 0.f, 0.f, 0.f};

    const int gk0 = z * p.kSplit;
    const int iters = p.Ksub >> 6;
    for (int it = 0; it < iters; ++it) {
        const int gk = gk0 + it * 64;
        const int tap = gk >> 10, kin = gk & 1023;
        int dy = 0, dx = 0;
        if (tap < 9) { int ky = tap / 3; dy = (ky - 1) * p.dil; dx = (tap - ky * 3 - 1) * p.dil; }
#pragma unroll
        for (int i = 0; i < 4; ++i) {
            int iy = ayy[i] + dy, ix = axx[i] + dx;
            bool ok = ((unsigned)iy < 16u) && ((unsigned)ix < 16u);
            const ushort_t* ga = ok ? (aBase[i] + (((iy << 4) + ix) << 10) + kin) : p.zpage;
            gload_lds16(ga, &aT[(wid * 32 + i * 8) * 64]);
        }
#pragma unroll
        for (int i = 0; i < 4; ++i)
            gload_lds16(bBase[i] + gk, &bT[(wid * 32 + i * 8) * 64]);
        asm volatile("s_waitcnt vmcnt(0)" ::: "memory");
        __syncthreads();
#pragma unroll
        for (int ks = 0; ks < 2; ++ks) {
            bf16x8 af[4], bfr[4];
#pragma unroll
            for (int mi = 0; mi < 4; ++mi) {
                int rr = wr * 64 + mi * 16 + l15;
                int cc = (ks * 32 + l16 * 8) ^ ((rr & 7) << 3);
                af[mi] = __builtin_bit_cast(bf16x8, *(const ushort8*)&aT[rr * 64 + cc]);
            }
#pragma unroll
            for (int ni = 0; ni < 4; ++ni) {
                int rr = wc * 64 + ni * 16 + l15;
                int cc = (ks * 32 + l16 * 8) ^ ((rr & 7) << 3);
                bfr[ni] = __builtin_bit_cast(bf16x8, *(const ushort8*)&bT[rr * 64 + cc]);
            }
#pragma unroll
            for (int mi = 0; mi < 4; ++mi)
#pragma unroll
                for (int ni = 0; ni < 4; ++ni)
                    acc[mi][ni] = __builtin_amdgcn_mfma_f32_16x16x32_bf16(af[mi], bfr[ni], acc[mi][ni], 0, 0, 0);
        }
        __syncthreads();
    }
#pragma unroll
    for (int mi = 0; mi < 4; ++mi)
#pragma unroll
        for (int ni = 0; ni < 4; ++ni) {
            int gcol = n0 + wc * 64 + ni * 16 + l15;
            int growb = m0 + wr * 64 + mi * 16 + l16 * 4;
#pragma unroll
            for (int r = 0; r < 4; ++r)
                p.obf[(long long)z * p.oBatch + (long long)(growb + r) * 256 + gcol] =
                    f2b(acc[mi][ni][r]);
        }
}

// Generic 4-wave MFMA GEMM: C = A.B^T, bf16 in, fp32 acc.
// AMODE==0: single source. AMODE==2: dual source (gk<256 from A/B, gk>=256
// from A2/B2 — Y = X + X@G - P@H as one K=384 pass, Htn pre-negated/scaled).
// AMODE==3: A's K-elements scaled by cw[z*128 + k] at load (SIG without a
// separate qc buffer).
template<int BM, int BN, int AMODE, int EPI>
__global__ __launch_bounds__(256) void gemm_k(GemmP p) {
    __shared__ __align__(16) ushort_t aT[BM * 64];
    __shared__ __align__(16) ushort_t bT[BN * 64];
    constexpr int APASS = BM / 32, BPASS = BN / 32;
    constexpr int MFRAG = BM / 32, NFRAG = BN / 32;
    const int tid = threadIdx.x;
    const int z = blockIdx.z;
    const int m0 = blockIdx.x * BM, n0 = blockIdx.y * BN;
    const int lane = tid & 63, wid = tid >> 6;
    const int l15 = lane & 15, l16 = lane >> 4;
    const int wr = wid >> 1, wc = wid & 1;
    const int srow = tid >> 3, scol = (tid & 7) * 8;
    const int swcol = scol ^ ((srow & 7) << 3);

    const ushort_t* aptr[APASS];
    const ushort_t* bptr[BPASS];
    const ushort_t* aptr2[APASS];
    const ushort_t* bptr2[BPASS];
#pragma unroll
    for (int pi = 0; pi < APASS; ++pi)
        aptr[pi] = p.A + (long long)z * p.aBatch +
                   (long long)(m0 + pi * 32 + srow) * p.lda + scol;
#pragma unroll
    for (int pi = 0; pi < BPASS; ++pi)
        bptr[pi] = p.B + (long long)z * p.bBatch +
                   (long long)(n0 + pi * 32 + srow) * p.ldb + scol;
    if constexpr (AMODE == 2) {
#pragma unroll
        for (int pi = 0; pi < APASS; ++pi)
            aptr2[pi] = p.A2 + (long long)z * p.a2Batch +
                        (long long)(m0 + pi * 32 + srow) * p.lda2 + scol;
#pragma unroll
        for (int pi = 0; pi < BPASS; ++pi)
            bptr2[pi] = p.B2 + (long long)z * p.b2Batch +
                        (long long)(n0 + pi * 32 + srow) * p.ldb2 + scol;
    }

    f32x4 acc[MFRAG][NFRAG];
#pragma unroll
    for (int i = 0; i < MFRAG; ++i)
#pragma unroll
        for (int j = 0; j < NFRAG; ++j) acc[i][j] = (f32x4){0.f, 0.f, 0.f, 0.f};

    ushort8 ar[APASS], br[BPASS];
    auto ldg = [&](int gk) {
        if (AMODE == 2 && gk >= 256) {
            int g2 = gk - 256;
#pragma unroll
            for (int pi = 0; pi < APASS; ++pi) ar[pi] = *(const ushort8*)(aptr2[pi] + g2);
#pragma unroll
            for (int pi = 0; pi < BPASS; ++pi) br[pi] = *(const ushort8*)(bptr2[pi] + g2);
        } else if constexpr (AMODE == 3) {
#pragma unroll
            for (int pi = 0; pi < APASS; ++pi) {
                ushort8 t8 = *(const ushort8*)(aptr[pi] + gk);
#pragma unroll
                for (int k = 0; k < 8; ++k)
                    t8[k] = f2b(b2f(t8[k]) * p.cw[(z << 7) + gk + scol + k]);
                ar[pi] = t8;
            }
#pragma unroll
            for (int pi = 0; pi < BPASS; ++pi) br[pi] = *(const ushort8*)(bptr[pi] + gk);
        } else {
#pragma unroll
            for (int pi = 0; pi < APASS; ++pi) ar[pi] = *(const ushort8*)(aptr[pi] + gk);
#pragma unroll
            for (int pi = 0; pi < BPASS; ++pi) br[pi] = *(const ushort8*)(bptr[pi] + gk);
        }
    };

    const int gk0 = z * p.kSplit;
    ldg(gk0);
    const int iters = p.Ksub >> 6;
    for (int it = 0; it < iters; ++it) {
#pragma unroll
        for (int pi = 0; pi < APASS; ++pi)
            *(ushort8*)&aT[(pi * 32 + srow) * 64 + swcol] = ar[pi];
#pragma unroll
        for (int pi = 0; pi < BPASS; ++pi)
            *(ushort8*)&bT[(pi * 32 + srow) * 64 + swcol] = br[pi];
        __syncthreads();
        if (it + 1 < iters) ldg(gk0 + (it + 1) * 64);
#pragma unroll
        for (int ks = 0; ks < 2; ++ks) {
            bf16x8 af[MFRAG], bfr[NFRAG];
#pragma unroll
            for (int mi = 0; mi < MFRAG; ++mi) {
                int rr = wr * (BM / 2) + mi * 16 + l15;
                int cc = (ks * 32 + l16 * 8) ^ ((rr & 7) << 3);
                af[mi] = __builtin_bit_cast(bf16x8, *(const ushort8*)&aT[rr * 64 + cc]);
            }
#pragma unroll
            for (int ni = 0; ni < NFRAG; ++ni) {
                int rr = wc * (BN / 2) + ni * 16 + l15;
                int cc = (ks * 32 + l16 * 8) ^ ((rr & 7) << 3);
                bfr[ni] = __builtin_bit_cast(bf16x8, *(const ushort8*)&bT[rr * 64 + cc]);
            }
#pragma unroll
            for (int mi = 0; mi < MFRAG; ++mi)
#pragma unroll
                for (int ni = 0; ni < NFRAG; ++ni)
                    acc[mi][ni] = __builtin_amdgcn_mfma_f32_16x16x32_bf16(af[mi], bfr[ni], acc[mi][ni], 0, 0, 0);
        }
        __syncthreads();
    }

    // ---------------- epilogue ----------------
#pragma unroll
    for (int mi = 0; mi < MFRAG; ++mi) {
        if constexpr (EPI == EPI_SIG) {
#pragma unroll
            for (int r = 0; r < 4; ++r) {
                float sv = 0.f;
#pragma unroll
                for (int ni = 0; ni < NFRAG; ++ni) sv += sigm(acc[mi][ni][r]);
                sv += __shfl_xor(sv, 1); sv += __shfl_xor(sv, 2);
                sv += __shfl_xor(sv, 4); sv += __shfl_xor(sv, 8);
                if (l15 == 0) {
                    int grow = m0 + wr * (BM / 2) + mi * 16 + l16 * 4 + r;
                    int q8 = blockIdx.y * 2 + wc;  // disjoint slot -> deterministic
                    p.dsum[q8 * 16384 + z * 256 + grow] = sv;
                }
            }
        } else {
#pragma unroll
            for (int ni = 0; ni < NFRAG; ++ni) {
                int gcol = n0 + wc * (BN / 2) + ni * 16 + l15;
                int growb = m0 + wr * (BM / 2) + mi * 16 + l16 * 4;
#pragma unroll
                for (int r = 0; r < 4; ++r) {
                    int grow = growb + r;
                    float v = acc[mi][ni][r];
                    if constexpr (EPI == EPI_RELU) {
                        v += p.bias[gcol]; v = fmaxf(v, 0.f);
                        p.obf[(long long)grow * p.ldo + gcol] = f2b(v);
                    } else if constexpr (EPI == EPI_FEAT) {
                        v += p.bias[gcol] + b2f(p.res[(long long)grow * p.ldres + gcol]);
                        p.obf[(long long)grow * p.ldo + gcol] = f2b(v);
                    } else if constexpr (EPI == EPI_XG) {
                        p.obf[(long long)z * p.oBatch + (long long)grow * p.ldo + gcol] = f2b(v);
                    } else if constexpr (EPI == EPI_NEGCW) {
                        v *= -p.cw[z * 128 + gcol];
                        p.obf[(long long)z * p.oBatch + (long long)grow * p.ldo + gcol] = f2b(v);
                    } else if constexpr (EPI == EPI_Y) {
                        v = b2f(p.res[(long long)z * p.resBatch + (long long)grow * p.ldres + gcol]) + v;
                        p.obf[(long long)z * p.oBatch + (long long)grow * p.ldo + gcol] = f2b(v);
                    } else if constexpr (EPI == EPI_OUTT) {
                        v += p.bias[grow];               // row = out-channel
                        int bb = gcol >> 8, px = gcol & 255;
                        p.of32[((long long)bb * 1024 + grow) * 256 + px] = v;  // coalesced over px
                    }
                }
            }
        }
    }
}

// ---------------- small kernels ----------------

// combine 5 bf16 split-K partials + bias -> bf16 fbuf
__global__ void k_combine(const ushort_t* __restrict__ t, const float* __restrict__ fbias_s,
                          ushort_t* __restrict__ f) {
    int idx = blockIdx.x * 256 + threadIdx.x;  // x8 elements
    const long long N = 16384ll * 256;
    ushort8 a0 = *(const ushort8*)(t + (long long)idx * 8);
    ushort8 a1 = *(const ushort8*)(t + N + (long long)idx * 8);
    ushort8 a2 = *(const ushort8*)(t + 2 * N + (long long)idx * 8);
    ushort8 a3 = *(const ushort8*)(t + 3 * N + (long long)idx * 8);
    ushort8 a4 = *(const ushort8*)(t + 4 * N + (long long)idx * 8);
    int cb = (idx * 8) & 255;
    ushort8 o;
#pragma unroll
    for (int k = 0; k < 8; ++k)
        o[k] = f2b(b2f(a0[k]) + b2f(a1[k]) + b2f(a2[k]) + b2f(a3[k]) + b2f(a4[k]) + fbias_s[cb + k]);
    *(ushort8*)&f[(long long)idx * 8] = o;
}

// x_sum = x_cur * (1 + bilinear_up2x_align_corners(x_lat)); bf16 [B*256][1024]
__global__ void k_upsum(const float* __restrict__ xc, const float* __restrict__ xl,
                        ushort_t* __restrict__ xs) {
    __shared__ float lat[64 * 64];
    __shared__ ushort_t tile[64 * 258];
    int b = blockIdx.x, c0 = blockIdx.y * 64;
    int t = threadIdx.x;
    for (int i = t; i < 4096; i += 256)
        lat[i] = xl[((long long)(b * 1024 + c0 + (i >> 6))) * 64 + (i & 63)];
    __syncthreads();
    int y = t >> 4, x = t & 15;
    float fy = y * (7.f / 15.f); int y0 = (int)fy; float wy = fy - y0; int y1 = y0 + 1 > 7 ? 7 : y0 + 1;
    float fx = x * (7.f / 15.f); int x0 = (int)fx; float wx = fx - x0; int x1 = x0 + 1 > 7 ? 7 : x0 + 1;
    for (int cc = 0; cc < 64; ++cc) {
        float cur = xc[((long long)(b * 1024 + c0 + cc)) * 256 + t];
        const float* L = &lat[cc * 64];
        float tv = L[y0 * 8 + x0] * (1.f - wx) + L[y0 * 8 + x1] * wx;
        float bv = L[y1 * 8 + x0] * (1.f - wx) + L[y1 * 8 + x1] * wx;
        float up = tv + (bv - tv) * wy;
        tile[cc * 258 + t] = f2b(cur * (1.f + up));
    }
    __syncthreads();
    for (int i = t; i < 16384; i += 256) {
        int px = i >> 6, cc = i & 63;
        xs[((long long)(b * 256 + px)) * 1024 + c0 + cc] = tile[cc * 258 + px];
    }
}

// fused avg/max pool + channel-weight MLP
__global__ void k_poolcw(const ushort_t* __restrict__ f,
                         const float* __restrict__ aw, const float* __restrict__ mw,
                         float* __restrict__ cw) {
    __shared__ float sa[256], sm[256];
    int b = blockIdx.x, t = threadIdx.x;
    float s = 0.f, m = -3.4e38f;
    const ushort_t* base = f + (long long)b * 65536 + t;
    for (int px = 0; px < 256; ++px) { float v = b2f(base[px * 256]); s += v; m = fmaxf(m, v); }
    sa[t] = s * (1.f / 256.f);
    sm[t] = m;
    __syncthreads();
    if (t < 128) {
        float s1 = 0.f, s2 = 0.f;
        const float* a = aw + t * 256; const float* w = mw + t * 256;
        for (int c = 0; c < 256; ++c) { s1 += sa[c] * a[c]; s2 += sm[c] * w[c]; }
        s1 = fmaxf(s1, 0.f); s2 = fmaxf(s2, 0.f);
        cw[b * 128 + t] = sigm(s1 + s2);
    }
}

// P scale + LDS-tiled transposed Pt (both writes coalesced); sums 8 slots
__global__ void k_pscale(const ushort_t* __restrict__ q, const float* __restrict__ dsum8,
                         ushort_t* __restrict__ P, ushort_t* __restrict__ Pt) {
    __shared__ ushort_t t[128][130];
    __shared__ float dd[128];
    int jh = blockIdx.x, b = blockIdx.y;
    int j0 = jh * 128;
    int tid = threadIdx.x;
    if (tid < 128) {
        int pix = b * 256 + j0 + tid;
        float s = 0.f;
#pragma unroll
        for (int qs = 0; qs < 8; ++qs) s += dsum8[qs * 16384 + pix];
        dd[tid] = rsqrtf(s);
    }
    __syncthreads();
    int jr = tid >> 7, m = tid & 127;
    for (int i = 0; i < 64; ++i) {
        int j = i * 2 + jr;
        long long qi = ((long long)(b * 256 + j0 + j)) * 128 + m;
        ushort_t v = f2b(dd[j] * b2f(q[qi]));
        P[qi] = v;
        t[j][m] = v;
    }
    __syncthreads();
    for (int i = 0; i < 64; ++i) {
        int mm = i * 2 + jr;
        Pt[((long long)b << 15) + (mm << 8) + j0 + m] = t[m][mm];
    }
}

// One-shot weight/bias packing: blocks [0,768) pack wbig for 3 stages via
// LDS; blocks >= 768 grid-stride flat regions.
__global__ void k_packall(const float* r0, const float* r1, const float* r2,
                          const float* convw, const float* c1w, const float* c3w,
                          const float* ckw, const float* gcnw,
                          const float* rb0, const float* rb1, const float* rb2,
                          const float* cb,
                          ushort_t* wbig3, ushort_t* w1b, ushort_t* w3b,
                          ushort_t* ckb, ushort_t* gcnT, float* fbias,
                          ushort_t* zpage) {
    int blk = blockIdx.x, tid = threadIdx.x;
    if (blk < 768) {
        __shared__ float lw[10240];
        int s = blk >> 8, o = blk & 255;
        const float* rate = s == 0 ? r0 : (s == 1 ? r1 : r2);
        for (int i = tid; i < 9216; i += 256) lw[i] = rate[(long long)o * 9216 + i];
        for (int i = tid; i < 1024; i += 256) lw[9216 + i] = convw[(long long)o * 1024 + i];
        __syncthreads();
        ushort_t* dst = wbig3 + (long long)blk * 10240;
        for (int i = tid; i < 10240; i += 256) {
            int tap = i >> 10, ci = i & 1023;
            float v = (tap < 9) ? lw[ci * 9 + tap] : lw[9216 + ci];
            dst[i] = f2b(v);
        }
        return;
    }
    const int R1 = 262144, R2 = R1 + 786432, R3 = R2 + 32768, R4 = R3 + 65536;
    const int R5 = R4 + 768, R6 = R5 + 128;
    int base = (blk - 768) * 2048 + tid * 8;
#pragma unroll
    for (int k = 0; k < 8; ++k) {
        int i = base + k;
        if (i >= R6) return;
        if (i < R1) w1b[i] = f2b(c1w[i]);
        else if (i < R2) w3b[i - R1] = f2b(c3w[i - R1]);
        else if (i < R3) ckb[i - R2] = f2b(ckw[i - R2]);
        else if (i < R4) {
            int ii = i - R3; int c2 = ii >> 8, c1 = ii & 255;
            gcnT[ii] = f2b(gcnw[c1 * 256 + c2]);
        } else if (i < R5) {
            int ii = i - R4; int s = ii >> 8, t = ii & 255;
            const float* rb = s == 0 ? rb0 : (s == 1 ? rb1 : rb2);
            fbias[ii] = rb[t] + cb[t];
        } else {
            zpage[i - R5] = 0;
        }
    }
}

__global__ void k_sentinel(float* o, int n, float v) {
    int i = blockIdx.x * 256 + threadIdx.x; if (i < n) o[i] = v;
}

// ---------------- launch ----------------
extern "C" void kernel_launch(void* const* d_in, const int* in_sizes, int n_in,
                              void* d_out, int out_size, void* d_ws, size_t ws_size,
                              hipStream_t stream) {
    const float* x_cur  = (const float*)d_in[0];
    const float* x_lat  = (const float*)d_in[1];
    const float* conv_w = (const float*)d_in[2];
    const float* conv_b = (const float*)d_in[3];
    const float* conv1_w = (const float*)d_in[4];
    const float* conv1_b = (const float*)d_in[5];
    const float* conv3_w = (const float*)d_in[6];
    const float* conv3_b = (const float*)d_in[7];
    const float* rate_w[3] = {(const float*)d_in[8], (const float*)d_in[10], (const float*)d_in[12]};
    const float* rate_b[3] = {(const float*)d_in[9], (const float*)d_in[11], (const float*)d_in[13]};
    const float* ck_w  = (const float*)d_in[14];
    const float* ck_b  = (const float*)d_in[15];
    const float* avg_w = (const float*)d_in[16];
    const float* max_w = (const float*)d_in[17];
    const float* gcn_w = (const float*)d_in[18];
    float* out = (float*)d_out;

    char* w = (char*)d_ws;
    auto take = [&](size_t bytes) { void* p = (void*)w; w += (bytes + 255) & ~(size_t)255; return p; };
    ushort_t* xsum  = (ushort_t*)take(16384ll * 1024 * 2);    // 33.55MB
    ushort_t* feat  = (ushort_t*)take(16384ll * 1024 * 2);    // 33.55MB
    ushort_t* fbuf  = (ushort_t*)take(16384ll * 256 * 2);     // 8.39MB
    ushort_t* xgt   = (ushort_t*)take(64ll * 256 * 256 * 2);  // 8.39MB
    ushort_t* qbuf  = (ushort_t*)take(16384ll * 128 * 2);     // 4.19MB
    ushort_t* Pt    = (ushort_t*)take(64ll * 128 * 256 * 2);  // 4.19MB
    ushort_t* Pb    = (ushort_t*)take(16384ll * 128 * 2);     // 4.19MB
    ushort_t* Htn   = (ushort_t*)take(64ll * 256 * 128 * 2);  // 4.19MB
    ushort_t* wbig3 = (ushort_t*)take(3ll * 256 * 10240 * 2); // 15.73MB
    ushort_t* w1b   = (ushort_t*)take(1024ll * 256 * 2);
    ushort_t* w3b   = (ushort_t*)take(1024ll * 768 * 2);
    ushort_t* ckb   = (ushort_t*)take(128ll * 256 * 2);
    ushort_t* gcnT  = (ushort_t*)take(256ll * 256 * 2);
    ushort_t* zpage = (ushort_t*)take(256);
    float*    fbias = (float*)take(3 * 256 * 4);
    float*    cwb   = (float*)take(64 * 128 * 4);
    float*    dsum8 = (float*)take(8ll * 64 * 256 * 4);       // 8 disjoint partial slots
    ushort_t* catb  = (ushort_t*)take(16384ll * 768 * 2);     // 25.17MB
    ushort_t* ftmp  = (ushort_t*)take(5ll * 16384 * 256 * 2); // 41.94MB
    size_t need = (size_t)(w - (char*)d_ws);                  // ~186MB

    if (need > ws_size) {
        float v = 1.0e6f + (float)(ws_size >> 20);
        k_sentinel<<<(out_size + 255) / 256, 256, 0, stream>>>(out, out_size, v);
        return;
    }

    k_packall<<<768 + 561, 256, 0, stream>>>(
        rate_w[0], rate_w[1], rate_w[2], conv_w, conv1_w, conv3_w, ck_w, gcn_w,
        rate_b[0], rate_b[1], rate_b[2], conv_b,
        wbig3, w1b, w3b, ckb, gcnT, fbias, zpage);
    k_upsum<<<dim3(64, 16), 256, 0, stream>>>(x_cur, x_lat, xsum);

    for (int s = 0; s < 3; ++s) {
        { // BIG: split-K=5, bf16 partials
            GemmP p{};
            p.A = (s == 0) ? xsum : feat;
            p.B = wbig3 + (long long)s * 256 * 10240; p.ldb = 10240;
            p.Ksub = 2048; p.kSplit = 2048; p.dil = 1 << s;
            p.obf = ftmp; p.oBatch = 16384ll * 256;
            p.zpage = zpage;
            gemm_big<<<dim3(128, 2, 5), 256, 0, stream>>>(p);
        }
        k_combine<<<2048, 256, 0, stream>>>(ftmp, fbias + s * 256, fbuf);
        k_poolcw<<<64, 256, 0, stream>>>(fbuf, avg_w, max_w, cwb);
        { // q = relu(f @ ck_w^T + ck_b)  [16384][128], 64x64 tiles
            GemmP p{};
            p.A = fbuf; p.lda = 256; p.B = ckb; p.ldb = 256;
            p.Ksub = 256;
            p.bias = ck_b; p.obf = qbuf; p.ldo = 128;
            gemm_k<64, 64, 0, EPI_RELU><<<dim3(256, 2, 1), 256, 0, stream>>>(p);
        }
        { // dsum8 partial row-sums of sigmoid((q*cw)_i . q_j); cw folded into A-load
            GemmP p{};
            p.A = qbuf; p.aBatch = 32768; p.lda = 128;
            p.B = qbuf; p.bBatch = 32768; p.ldb = 128;
            p.Ksub = 128; p.dsum = dsum8; p.cw = cwb;
            gemm_k<64, 64, 3, EPI_SIG><<<dim3(4, 4, 64), 256, 0, stream>>>(p);
        }
        k_pscale<<<dim3(2, 64), 256, 0, stream>>>(qbuf, dsum8, Pb, Pt);
        { // XGt[b][c][j] = sum_c' gcnT[c][c'] fbuf_b[j][c']
            GemmP p{};
            p.A = gcnT; p.aBatch = 0;     p.lda = 256;
            p.B = fbuf; p.bBatch = 65536; p.ldb = 256;
            p.Ksub = 256;
            p.obf = xgt; p.oBatch = 65536; p.ldo = 256;
            gemm_k<64, 64, 0, EPI_XG><<<dim3(4, 4, 64), 256, 0, stream>>>(p);
        }
        { // Htn[b][c][m] = -cw[m] * sum_j XGt[c][j] Pt[m][j]
            GemmP p{};
            p.A = xgt; p.aBatch = 65536; p.lda = 256;
            p.B = Pt;  p.bBatch = 32768; p.ldb = 256;
            p.Ksub = 256; p.cw = cwb;
            p.obf = Htn; p.oBatch = 32768; p.ldo = 128;
            gemm_k<64, 64, 0, EPI_NEGCW><<<dim3(4, 2, 64), 256, 0, stream>>>(p);
        }
        { // Y = X + X@G - P@H : K=384 dual-source -> catb slice
            GemmP p{};
            p.A = fbuf; p.aBatch = 65536; p.lda = 256;
            p.B = gcnT; p.bBatch = 0;     p.ldb = 256;
            p.A2 = Pb;  p.a2Batch = 32768; p.lda2 = 128;
            p.B2 = Htn; p.b2Batch = 32768; p.ldb2 = 128;
            p.Ksub = 384;
            p.res = fbuf; p.resBatch = 65536; p.ldres = 256;
            p.obf = catb + s * 256; p.oBatch = 256ll * 768; p.ldo = 768;
            gemm_k<64, 64, 2, EPI_Y><<<dim3(4, 4, 64), 256, 0, stream>>>(p);
        }
        if (s < 2) { // feature = conv1(f) + conv1_b + x_sum -> feat
            GemmP p{};
            p.A = fbuf; p.lda = 256; p.B = w1b; p.ldb = 256;
            p.Ksub = 256; p.bias = conv1_b;
            p.res = xsum; p.ldres = 1024;
            p.obf = feat; p.ldo = 1024;
            gemm_k<64, 64, 0, EPI_FEAT><<<dim3(256, 16, 1), 256, 0, stream>>>(p);
        }
    }
    { // out[bb][o][px] = sum_k w3[o][k] cat[px][k] + conv3_b[o]
        GemmP p{};
        p.A = w3b;  p.lda = 768;
        p.B = catb; p.ldb = 768;
        p.Ksub = 768; p.bias = conv3_b; p.of32 = out;
        gemm_k<128, 128, 0, EPI_OUTT><<<dim3(8, 128, 1), 256, 0, stream>>>(p);
    }
}